// Round 7
// baseline (564.913 us; speedup 1.0000x reference)
//
#include <hip/hip_runtime.h>
#include <math.h>

// ---------------- problem sizes ----------------
#define NEV    32      // n_events
#define NS     65536   // n_samples
#define NFFT   131072  // 2*NS
#define ENVS   128
#define ENVF   8192
#define FSAMP2 512
#define NEXP2  4
#define FLEN   8704    // filtered support (8192 + 512 - 1 -> padded to 8704)
#define GD     5622750u   // 22050*255 (phase denominator)
#define GDH    2811375u   // GD/2

// ---------------- workspace layout (float offsets) ----------------
enum : size_t {
  O_ENV_SMALL = 0,         // 32*128
  O_NFIL      = 4096,      // 32*4*512
  O_IMP       = 69632,     // 32*8192
  O_ND        = 331776,    // 32*4*128
  O_WSM       = 348160,    // 32*8*128
  O_DSM       = 380928,    // 32*128
  O_SCAL      = 385024,    // 32*4  (m0, m1, amp^2)
  O_RHO       = 385152,    // 32*16
  O_P1        = 385664,    // 256*1024
  O_P2        = 647808,    // 256*1024
  O_FILT      = 909952,    // 32*8704
  O_DRES      = 1188480,   // 32*65536
  O_CONV      = 3285632,   // 32*65536
  O_ROOMS     = 5382784,   // 32*65536 (fallback path only)
  O_SWE       = 7479936,   // 32*64
  O_SWN       = 7482048,   // 32*4*64
  O_SWD       = 7490304,   // 32*64
  O_SWND      = 7492416,   // 32*32
  O_X         = 7742080,   // 8,388,608 floats: Xf | Xd  (16 pair-slices each)
  O_Y         = 16130688,  // 8,388,608 floats: Xr | Uc
  O_END       = 24519296,  // *4 bytes = 98,077,184
};

typedef float f32x4 __attribute__((ext_vector_type(4)));
typedef short bf16x8 __attribute__((ext_vector_type(8)));

union U8 { uint4 q; bf16x8 v; unsigned short u[8]; };

__device__ __forceinline__ int imin(int a, int b){ return a < b ? a : b; }

__device__ __forceinline__ float wsum(float v){
  #pragma unroll
  for (int o = 32; o > 0; o >>= 1) v += __shfl_xor(v, o);
  return v;
}
__device__ __forceinline__ float wmax(float v){
  #pragma unroll
  for (int o = 32; o > 0; o >>= 1) v = fmaxf(v, __shfl_xor(v, o));
  return v;
}

__device__ __forceinline__ unsigned short f2bf(float f){
  unsigned u = __float_as_uint(f);
  unsigned r = (u + 0x7fffu + ((u >> 16) & 1u)) >> 16;
  return (unsigned short)r;
}

// e^{-2*pi*i*frac} via HW trig (input in revolutions)
__device__ __forceinline__ float2 twid(float frac){
  float c, s;
  asm("v_cos_f32 %0, %1" : "=v"(c) : "v"(frac));
  asm("v_sin_f32 %0, %1" : "=v"(s) : "v"(frac));
  return make_float2(c, -s);
}

// ---------------- JAX threefry2x32, partitionable 32-bit path ----------------
__device__ __forceinline__ unsigned tf_rotl(unsigned x, int d){ return (x << d) | (x >> (32 - d)); }

__device__ unsigned threefry_bits(unsigned chi, unsigned clo){
  const unsigned k0 = 0u, k1 = 42u, k2 = 0x1BD11BDAu ^ 0u ^ 42u;
  unsigned x0 = chi + k0;
  unsigned x1 = clo + k1;
  x0 += x1; x1 = tf_rotl(x1,13); x1 ^= x0;
  x0 += x1; x1 = tf_rotl(x1,15); x1 ^= x0;
  x0 += x1; x1 = tf_rotl(x1,26); x1 ^= x0;
  x0 += x1; x1 = tf_rotl(x1, 6); x1 ^= x0;
  x0 += k1; x1 += k2 + 1u;
  x0 += x1; x1 = tf_rotl(x1,17); x1 ^= x0;
  x0 += x1; x1 = tf_rotl(x1,29); x1 ^= x0;
  x0 += x1; x1 = tf_rotl(x1,16); x1 ^= x0;
  x0 += x1; x1 = tf_rotl(x1,24); x1 ^= x0;
  x0 += k2; x1 += k0 + 2u;
  x0 += x1; x1 = tf_rotl(x1,13); x1 ^= x0;
  x0 += x1; x1 = tf_rotl(x1,15); x1 ^= x0;
  x0 += x1; x1 = tf_rotl(x1,26); x1 ^= x0;
  x0 += x1; x1 = tf_rotl(x1, 6); x1 ^= x0;
  x0 += k0; x1 += k1 + 3u;
  x0 += x1; x1 = tf_rotl(x1,17); x1 ^= x0;
  x0 += x1; x1 = tf_rotl(x1,29); x1 ^= x0;
  x0 += x1; x1 = tf_rotl(x1,16); x1 ^= x0;
  x0 += x1; x1 = tf_rotl(x1,24); x1 ^= x0;
  x0 += k1; x1 += k2 + 4u;
  x0 += x1; x1 = tf_rotl(x1,13); x1 ^= x0;
  x0 += x1; x1 = tf_rotl(x1,15); x1 ^= x0;
  x0 += x1; x1 = tf_rotl(x1,26); x1 ^= x0;
  x0 += x1; x1 = tf_rotl(x1, 6); x1 ^= x0;
  x0 += k2; x1 += k0 + 5u;
  return x0 ^ x1;
}

// ---------------- weights: softmaxes + decay/mix/room ----------------
__global__ __launch_bounds__(64) void weights_kernel(
    const float* __restrict__ noise_sel, const float* __restrict__ env_sel,
    const float* __restrict__ dec_sel,   const float* __restrict__ def_sel,
    const float* __restrict__ ndef_sel,  const float* __restrict__ mix_sel,
    const float* __restrict__ room_sel,  const float* __restrict__ amp,
    const float* __restrict__ d_items,
    float* __restrict__ swE, float* __restrict__ swN,
    float* __restrict__ swD, float* __restrict__ swND,
    float* __restrict__ d_small, float* __restrict__ scal,
    float* __restrict__ rho)
{
  const int e = blockIdx.x;
  const int l = threadIdx.x;

  {
    float x = env_sel[e*64 + l];
    float mx = wmax(x);
    float ex = expf(x - mx);
    float sm = wsum(ex);
    swE[e*64 + l] = ex / sm;
  }
  #pragma unroll
  for (int x4 = 0; x4 < NEXP2; x4++){
    float v = noise_sel[(e*NEXP2 + x4)*64 + l];
    float mxv = wmax(v);
    float exv = expf(v - mxv);
    float smv = wsum(exv);
    swN[(e*NEXP2 + x4)*64 + l] = exv / smv;
  }
  {
    float x = def_sel[e*64 + l];
    float mx = wmax(x);
    float ex = expf(x - mx);
    float sm = wsum(ex);
    swD[e*64 + l] = ex / sm;
  }
  {
    float x = (l < 32) ? ndef_sel[e*32 + l] : -1e30f;
    float mx = wmax(x);
    float ex = (l < 32) ? expf(x - mx) : 0.f;
    float sm = wsum(ex);
    if (l < 32) swND[e*32 + l] = ex / sm;
  }
  {
    float x = dec_sel[e*64 + l];
    float mx = wmax(x);
    float ex = expf(x - mx);
    float sm = wsum(ex);
    float wgt = ex / sm;
    float di = d_items[l];
    float dp = 0.5f + 0.5f*(1.0f/(1.0f + expf(-di)));
    float d0 = wsum(wgt*dp);
    float ld = logf(d0 + 1e-12f);
    #pragma unroll
    for (int c = 0; c < 2; c++){
      int f = l + 64*c;
      d_small[e*128 + f] = expf((float)(f+1)*ld);
    }
  }
  if (l == 0){
    float a = mix_sel[e*2 + 0], b = mix_sel[e*2 + 1];
    float mm = fmaxf(a, b);
    float ea = expf(a - mm), eb = expf(b - mm);
    float ss = ea + eb;
    scal[e*4 + 0] = ea/ss;
    scal[e*4 + 1] = eb/ss;
    float am = amp[e];
    scal[e*4 + 2] = am*am;
  }
  {
    float x = (l < 16) ? room_sel[e*16 + l] : -1e30f;
    float mx = wmax(x);
    float ex = (l < 16) ? expf(x - mx) : 0.f;
    float sm = wsum(ex);
    if (l < 16) rho[e*16 + l] = ex/sm;
  }
}

// ---------------- output-parallel small lookups ----------------
__global__ __launch_bounds__(128) void envs_kernel(
    const float* __restrict__ swE, const float* __restrict__ e_items,
    float* __restrict__ env_small)
{
  const int e = blockIdx.x, j = threadIdx.x;
  __shared__ float sw[64];
  if (j < 64) sw[j] = swE[e*64 + j];
  __syncthreads();
  float acc = 0.f;
  #pragma unroll 8
  for (int k = 0; k < 64; k++){ float it = e_items[k*ENVS + j]; acc += sw[k]*(it*it); }
  env_small[e*ENVS + j] = acc;
}

__global__ __launch_bounds__(256) void nfil_kernel(
    const float* __restrict__ swN, const float* __restrict__ n_items,
    float* __restrict__ nfil)
{
  const int b = blockIdx.x;
  const int tid = threadIdx.x;
  __shared__ float sw[64];
  if (tid < 64) sw[tid] = swN[b*64 + tid];
  __syncthreads();
  #pragma unroll
  for (int c = 0; c < 2; c++){
    int tau = tid + 256*c;
    float acc = 0.f;
    #pragma unroll 8
    for (int f = 0; f < 64; f++) acc += sw[f]*n_items[f*FSAMP2 + tau];
    float ham = 0.54f - 0.46f*cosf((6.2831853071795864769f * (float)tau) / 511.0f);
    nfil[b*FSAMP2 + tau] = acc*ham;
  }
}

__global__ __launch_bounds__(128) void warp_kernel(
    const float* __restrict__ swD, const float* __restrict__ warp_items,
    float* __restrict__ w_small)
{
  const int e = blockIdx.x, f = threadIdx.x;
  __shared__ float sw[64];
  if (f < 64) sw[f] = swD[e*64 + f];
  __syncthreads();
  float acc[8] = {0,0,0,0,0,0,0,0};
  for (int k = 0; k < 64; k++){
    float wk = sw[k];
    const float* row = warp_items + (size_t)k*1024 + f;
    #pragma unroll
    for (int i = 0; i < 8; i++) acc[i] += wk*row[i*128];
  }
  float mx = -1e30f;
  #pragma unroll
  for (int i = 0; i < 8; i++) mx = fmaxf(mx, acc[i]);
  float ev[8]; float s = 0.f;
  #pragma unroll
  for (int i = 0; i < 8; i++){ ev[i] = expf(acc[i] - mx); s += ev[i]; }
  #pragma unroll
  for (int i = 0; i < 8; i++) w_small[(e*8 + i)*128 + f] = ev[i]/s;
}

__global__ __launch_bounds__(128) void nwarp_kernel(
    const float* __restrict__ swND, const float* __restrict__ nwarp_items,
    float* __restrict__ nd_small)
{
  const int e = blockIdx.x, f = threadIdx.x;
  __shared__ float sw[32];
  if (f < 32) sw[f] = swND[e*32 + f];
  __syncthreads();
  float acc[4] = {0,0,0,0};
  for (int k = 0; k < 32; k++){
    float wk = sw[k];
    const float* row = nwarp_items + (size_t)k*512 + f;
    #pragma unroll
    for (int x = 0; x < 4; x++) acc[x] += wk*row[x*128];
  }
  float mx = -1e30f;
  #pragma unroll
  for (int x = 0; x < 4; x++) mx = fmaxf(mx, acc[x]);
  float ev[4]; float s = 0.f;
  #pragma unroll
  for (int x = 0; x < 4; x++){ ev[x] = expf(acc[x] - mx); s += ev[x]; }
  #pragma unroll
  for (int x = 0; x < 4; x++) nd_small[(e*4 + x)*128 + f] = ev[x]/s;
}

// ---------------- legacy prep (fallback path only) ----------------
__global__ __launch_bounds__(64) void prep_kernel(
    const float* __restrict__ noise_sel, const float* __restrict__ env_sel,
    const float* __restrict__ dec_sel,   const float* __restrict__ def_sel,
    const float* __restrict__ ndef_sel,  const float* __restrict__ mix_sel,
    const float* __restrict__ room_sel,  const float* __restrict__ amp,
    const float* __restrict__ n_items,   const float* __restrict__ e_items,
    const float* __restrict__ d_items,   const float* __restrict__ warp_items,
    const float* __restrict__ nwarp_items,
    float* __restrict__ env_small, float* __restrict__ nfil,
    float* __restrict__ nd_small,  float* __restrict__ w_small,
    float* __restrict__ d_small,   float* __restrict__ scal,
    float* __restrict__ rho)
{
  const int e = blockIdx.x;
  const int l = threadIdx.x;
  __shared__ float sw[64];
  __shared__ float buf[1024];

  {
    float x = env_sel[e*64 + l];
    float mx = wmax(x);
    float ex = expf(x - mx);
    float sm = wsum(ex);
    sw[l] = ex / sm;
  }
  __syncthreads();
  #pragma unroll
  for (int c = 0; c < 2; c++){
    int j = l + 64*c;
    float acc = 0.f;
    for (int k = 0; k < 64; k++){ float it = e_items[k*ENVS + j]; acc += sw[k]*(it*it); }
    env_small[e*ENVS + j] = acc;
  }
  __syncthreads();

  for (int x = 0; x < NEXP2; x++){
    float v = noise_sel[(e*NEXP2 + x)*64 + l];
    float mxv = wmax(v);
    float exv = expf(v - mxv);
    float smv = wsum(exv);
    sw[l] = exv / smv;
    __syncthreads();
    for (int c = 0; c < 8; c++){
      int tau = l + 64*c;
      float acc = 0.f;
      for (int f = 0; f < 64; f++) acc += sw[f]*n_items[f*FSAMP2 + tau];
      float ham = 0.54f - 0.46f*cosf((6.2831853071795864769f * (float)tau) / 511.0f);
      nfil[(e*NEXP2 + x)*FSAMP2 + tau] = acc*ham;
    }
    __syncthreads();
  }

  {
    float x = def_sel[e*64 + l];
    float mx = wmax(x);
    float ex = expf(x - mx);
    float sm = wsum(ex);
    sw[l] = ex / sm;
  }
  __syncthreads();
  for (int c = 0; c < 16; c++){
    int idx = l + 64*c;
    float acc = 0.f;
    for (int k = 0; k < 64; k++) acc += sw[k]*warp_items[k*1024 + idx];
    buf[idx] = acc;
  }
  __syncthreads();
  #pragma unroll
  for (int c = 0; c < 2; c++){
    int f = l + 64*c;
    float mx = -1e30f;
    for (int i = 0; i < 8; i++) mx = fmaxf(mx, buf[i*128 + f]);
    float ev[8]; float s = 0.f;
    for (int i = 0; i < 8; i++){ ev[i] = expf(buf[i*128 + f] - mx); s += ev[i]; }
    for (int i = 0; i < 8; i++) w_small[(e*8 + i)*128 + f] = ev[i]/s;
  }
  __syncthreads();

  {
    float x = (l < 32) ? ndef_sel[e*32 + l] : -1e30f;
    float mx = wmax(x);
    float ex = (l < 32) ? expf(x - mx) : 0.f;
    float sm = wsum(ex);
    sw[l] = (l < 32) ? ex/sm : 0.f;
  }
  __syncthreads();
  for (int c = 0; c < 8; c++){
    int idx = l + 64*c;
    float acc = 0.f;
    for (int k = 0; k < 32; k++) acc += sw[k]*nwarp_items[k*512 + idx];
    buf[idx] = acc;
  }
  __syncthreads();
  #pragma unroll
  for (int c = 0; c < 2; c++){
    int j = l + 64*c;
    float mx = -1e30f;
    for (int x = 0; x < 4; x++) mx = fmaxf(mx, buf[x*128 + j]);
    float ev[4]; float s = 0.f;
    for (int x = 0; x < 4; x++){ ev[x] = expf(buf[x*128 + j] - mx); s += ev[x]; }
    for (int x = 0; x < 4; x++) nd_small[(e*4 + x)*128 + j] = ev[x]/s;
  }
  __syncthreads();

  {
    float x = dec_sel[e*64 + l];
    float mx = wmax(x);
    float ex = expf(x - mx);
    float sm = wsum(ex);
    float wgt = ex / sm;
    float di = d_items[l];
    float dp = 0.5f + 0.5f*(1.0f/(1.0f + expf(-di)));
    float d0 = wsum(wgt*dp);
    float ld = logf(d0 + 1e-12f);
    #pragma unroll
    for (int c = 0; c < 2; c++){
      int f = l + 64*c;
      d_small[e*128 + f] = expf((float)(f+1)*ld);
    }
  }
  if (l == 0){
    float a = mix_sel[e*2 + 0], b = mix_sel[e*2 + 1];
    float mm = fmaxf(a, b);
    float ea = expf(a - mm), eb = expf(b - mm);
    float ss = ea + eb;
    scal[e*4 + 0] = ea/ss;
    scal[e*4 + 1] = eb/ss;
    float am = amp[e];
    scal[e*4 + 2] = am*am;
  }
  {
    float x = (l < 16) ? room_sel[e*16 + l] : -1e30f;
    float mx = wmax(x);
    float ex = (l < 16) ? expf(x - mx) : 0.f;
    float sm = wsum(ex);
    if (l < 16) rho[e*16 + l] = ex/sm;
  }
}

// ---------------- P1 = softmax(res_sel) ----------------
__global__ __launch_bounds__(256) void p1_softmax_kernel(
    const float* __restrict__ res_sel, float* __restrict__ P1)
{
  const int m = blockIdx.x;
  const int tid = threadIdx.x;
  __shared__ float red[4], red2[4];
  const float* row = res_sel + (size_t)m*1024;
  float4 v = ((const float4*)row)[tid];
  float mx = fmaxf(fmaxf(v.x, v.y), fmaxf(v.z, v.w));
  #pragma unroll
  for (int o = 32; o > 0; o >>= 1) mx = fmaxf(mx, __shfl_xor(mx, o));
  if ((tid & 63) == 0) red[tid >> 6] = mx;
  __syncthreads();
  mx = fmaxf(fmaxf(red[0], red[1]), fmaxf(red[2], red[3]));
  float e0 = expf(v.x - mx), e1 = expf(v.y - mx), e2 = expf(v.z - mx), e3 = expf(v.w - mx);
  float s = e0 + e1 + e2 + e3;
  #pragma unroll
  for (int o = 32; o > 0; o >>= 1) s += __shfl_xor(s, o);
  if ((tid & 63) == 0) red2[tid >> 6] = s;
  __syncthreads();
  s = red2[0] + red2[1] + red2[2] + red2[3];
  float inv = 1.0f/s;
  ((float4*)(P1 + (size_t)m*1024))[tid] = make_float4(e0*inv, e1*inv, e2*inv, e3*inv);
}

// ---------------- P2 = P1 @ r_items ----------------
__global__ __launch_bounds__(256) void p2_kernel(
    const float* __restrict__ P1, const float* __restrict__ r_items,
    float* __restrict__ P2)
{
  __shared__ __align__(16) float sp1[8][1024];
  const int bx = blockIdx.x;
  const int mg = blockIdx.y;
  const int tid = threadIdx.x;
  for (int idx = tid; idx < 2048; idx += 256)
    ((float4*)&sp1[0][0])[idx] = ((const float4*)(P1 + (size_t)mg*8*1024))[idx];
  __syncthreads();
  const int n = bx*256 + tid;
  float acc[8] = {0,0,0,0,0,0,0,0};
  for (int k = 0; k < 1024; k++){
    float wv = r_items[(size_t)k*1024 + n];
    #pragma unroll
    for (int r = 0; r < 8; r++) acc[r] += sp1[r][k]*wv;
  }
  #pragma unroll
  for (int r = 0; r < 8; r++) P2[(size_t)(mg*8 + r)*1024 + n] = acc[r];
}

// ---------------- split A = P2 into bf16 hi (fragment order) ----------------
__global__ __launch_bounds__(256) void split_a_kernel(
    const float* __restrict__ P2, unsigned short* __restrict__ Ahi)
{
  const int row = blockIdx.x;
  for (int k = threadIdx.x; k < 1024; k += 256){
    float f = P2[(size_t)row*1024 + k];
    Ahi[(size_t)(k >> 3)*2048 + row*8 + (k & 7)] = f2bf(f);
  }
}

// ---------------- impulses = interp(env_small,8192) * uniform_noise ----------------
__global__ __launch_bounds__(256) void env_noise_kernel(
    const float* __restrict__ env_small, float* __restrict__ impulses)
{
  const int flat = blockIdx.x*256 + threadIdx.x;
  const int e = flat >> 13, i = flat & 8191;
  unsigned bits = threefry_bits(0u, (unsigned)flat);
  float u01 = __uint_as_float((bits >> 9) | 0x3f800000u) - 1.0f;
  float nz  = fmaxf(-1.0f, u01*2.0f - 1.0f);
  float pos = (float)i * (127.0f/8191.0f);
  int lo = (int)floorf(pos);
  int hi = imin(lo + 1, 127);
  float w = pos - (float)lo;
  const float* es = env_small + e*ENVS;
  float v = es[lo]*(1.0f - w) + es[hi]*w;
  impulses[flat] = v*nz;
}

// ---------------- filtered: 512-tap FIR + nd combine ----------------
__global__ __launch_bounds__(256) void filt_kernel(
    const float* __restrict__ nfil, const float* __restrict__ impulses,
    const float* __restrict__ nd_small, float* __restrict__ filtered)
{
  __shared__ float nf[4*512];
  __shared__ float imp[768];
  const int e = blockIdx.y, t0 = blockIdx.x*256, tid = threadIdx.x;
  for (int idx = tid; idx < 2048; idx += 256) nf[idx] = nfil[e*2048 + idx];
  for (int idx = tid; idx < 768; idx += 256){
    int g = t0 - 512 + idx;
    imp[idx] = (g >= 0 && g < ENVF) ? impulses[e*ENVF + g] : 0.f;
  }
  __syncthreads();
  const int t = t0 + tid;
  float s0 = 0.f, s1 = 0.f, s2 = 0.f, s3 = 0.f;
  for (int tau = 0; tau < 512; tau++){
    float iv = imp[512 + tid - tau];
    s0 += nf[0*512 + tau]*iv;
    s1 += nf[1*512 + tau]*iv;
    s2 += nf[2*512 + tau]*iv;
    s3 += nf[3*512 + tau]*iv;
  }
  float pos = (float)t * (127.0f/65535.0f);
  int lo = (int)floorf(pos);
  int hi = imin(lo + 1, 127);
  float w = pos - (float)lo;
  const float* nds = nd_small + e*512;
  float acc = 0.f;
  acc += s0*(nds[0*128 + lo]*(1.0f - w) + nds[0*128 + hi]*w);
  acc += s1*(nds[1*128 + lo]*(1.0f - w) + nds[1*128 + hi]*w);
  acc += s2*(nds[2*128 + lo]*(1.0f - w) + nds[2*128 + hi]*w);
  acc += s3*(nds[3*128 + lo]*(1.0f - w) + nds[3*128 + hi]*w);
  filtered[e*FLEN + t] = acc;
}

// ---------------- rooms (fallback path only) ----------------
__global__ __launch_bounds__(256) void rooms_kernel(
    const float* __restrict__ verbs, const float* __restrict__ rho,
    float* __restrict__ rooms)
{
  const int t = blockIdx.x*256 + threadIdx.x;
  const int e = blockIdx.y;
  float acc = 0.f;
  #pragma unroll
  for (int v = 0; v < 16; v++) acc += rho[e*16 + v]*verbs[(size_t)v*NS + t];
  rooms[(size_t)e*NS + t] = acc;
}

// ---------------- rare-path waveform: exact f64 replication of numpy ----------------
__device__ __noinline__ float slow_wave(int wf, int n, int i){
  const double stp = 3980.0 / 255.0;
  double fi = (i == 255) ? 4000.0 : __dadd_rn(__dmul_rn((double)i, stp), 20.0);
  double tn = (double)n / 22050.0;
  double ph = __dmul_rn(fi, tn);
  double fr = ph - trunc(ph);
  if (wf == 1) return (float)(2.0*fr - 1.0);
  if (wf == 3){ double sw = 2.0*fr - 1.0; return (float)(2.0*fabs(sw) - 1.0); }
  if (fr == 0.0 || fr == 0.5){
    if (ph == 0.0) return 0.0f;
    double sv = sin(__dmul_rn(6.283185307179586, ph));
    return (sv > 0.0) ? 1.0f : ((sv < 0.0) ? -1.0f : 0.0f);
  }
  return (fr < 0.5) ? 1.0f : -1.0f;
}

// generate 8 wave values (rows i0..i0+7, column n), split to bf16 hi (and lo if LO)
template<bool LO>
__device__ __forceinline__ void gen8(int wf, int n, int i0,
                                     unsigned m_in, unsigned stepn,
                                     U8& bh, U8& bl)
{
  unsigned m = m_in;
  #pragma unroll
  for (int j = 0; j < 8; j++){
    float fr = (float)m * (1.0f/5622750.0f);
    float val;
    bool rare;
    if (wf == 0){
      asm("v_sin_f32 %0, %1" : "=v"(val) : "v"(fr));
      rare = false;
    } else if (wf == 1){
      val = fmaf(fr, 2.0f, -1.0f);
      rare = (m == 0u);
    } else if (wf == 2){
      val = (m < GDH) ? 1.0f : -1.0f;
      rare = (m == 0u) || (m == GDH);
    } else {
      val = fmaf(fabsf(fmaf(fr, 2.0f, -1.0f)), 2.0f, -1.0f);
      rare = (m == 0u);
    }
    if (rare) val = slow_wave(wf, n, i0 + j);
    unsigned ub = __float_as_uint(val);
    bh.u[j] = (unsigned short)(ub >> 16);
    if (LO){
      unsigned th = ub & 0xFFFF0000u;
      float lres = val - __uint_as_float(th);
      bl.u[j] = (unsigned short)(__float_as_uint(lres) >> 16);
    }
    m += stepn;
    if (m >= GD) m -= GD;
  }
}

// ---------------- MFMA GEMM: BN=128, LDS-staged A, integer wave-gen ----------
// square-wave quarter (wf==2): bl == 0 exactly -> skip lo MFMAs + lo gen.
__global__ __launch_bounds__(256, 2) void gemm_dres_gen2_kernel(
    const unsigned short* __restrict__ Ahi,
    const float* __restrict__ w_small, const float* __restrict__ d_small,
    float* __restrict__ dres)
{
  __shared__ __align__(16) unsigned short Abuf[2][8192];   // 2 x 16 KB

  const int tid = threadIdx.x;
  const int l = tid & 63, w = tid >> 6;
  const int g = l >> 4, c = l & 15;
  const int n0 = blockIdx.x * 128;
  const int nA = n0 + w*32 + c;
  const int nB = nA + 16;

  f32x4 accA[16], accB[16];
  #pragma unroll
  for (int m = 0; m < 16; m++){
    accA[m] = (f32x4){0.f,0.f,0.f,0.f};
    accB[m] = (f32x4){0.f,0.f,0.f,0.f};
  }

  const unsigned stepA = (3980u*(unsigned)nA) % GD;
  const unsigned stepB = (3980u*(unsigned)nB) % GD;
  const unsigned s32A = (32u*stepA) % GD;
  const unsigned s32B = (32u*stepB) % GD;
  const unsigned K0g = 3980u*(unsigned)(g*8) + 5100u;
  const unsigned m0A = (unsigned)(((unsigned long long)(unsigned)nA * K0g) % GD);
  const unsigned m0B = (unsigned)(((unsigned long long)(unsigned)nB * K0g) % GD);
  unsigned msegA = m0A, msegB = m0B;

  typedef const __attribute__((address_space(1))) void GV;
  typedef __attribute__((address_space(3))) void LV;

  #pragma unroll
  for (int q = 0; q < 4; q++){
    const unsigned short* src = Ahi + (size_t)q*2048 + (size_t)w*512 + (size_t)l*8;
    __builtin_amdgcn_global_load_lds((GV*)src, (LV*)&Abuf[0][q*2048 + w*512], 16, 0, 0);
  }
  __syncthreads();

  for (int k0 = 0; k0 < 1024; k0 += 32){
    const int cur = (k0 >> 5) & 1, nxt = cur ^ 1;
    const int wf = k0 >> 8;
    if ((k0 & 255) == 0){ msegA = m0A; msegB = m0B; }

    if (k0 + 32 < 1024){
      const size_t slice = (size_t)((k0 + 32) >> 5) * 8192;
      #pragma unroll
      for (int q = 0; q < 4; q++){
        const unsigned short* src = Ahi + slice + (size_t)q*2048 + (size_t)w*512 + (size_t)l*8;
        __builtin_amdgcn_global_load_lds((GV*)src, (LV*)&Abuf[nxt][q*2048 + w*512], 16, 0, 0);
      }
    }

    const int i0 = (k0 & 255) + g*8;
    if (wf != 2){
      U8 bhA, blA, bhB, blB;
      gen8<true>(wf, nA, i0, msegA, stepA, bhA, blA);
      gen8<true>(wf, nB, i0, msegB, stepB, bhB, blB);
      #pragma unroll
      for (int m = 0; m < 16; m++){
        U8 ah;
        ah.q = *(const uint4*)&Abuf[cur][g*2048 + (m*16 + c)*8];
        accA[m] = __builtin_amdgcn_mfma_f32_16x16x32_bf16(ah.v, bhA.v, accA[m], 0, 0, 0);
        accA[m] = __builtin_amdgcn_mfma_f32_16x16x32_bf16(ah.v, blA.v, accA[m], 0, 0, 0);
        accB[m] = __builtin_amdgcn_mfma_f32_16x16x32_bf16(ah.v, bhB.v, accB[m], 0, 0, 0);
        accB[m] = __builtin_amdgcn_mfma_f32_16x16x32_bf16(ah.v, blB.v, accB[m], 0, 0, 0);
      }
    } else {
      U8 bhA, bhB, dummy;
      gen8<false>(2, nA, i0, msegA, stepA, bhA, dummy);
      gen8<false>(2, nB, i0, msegB, stepB, bhB, dummy);
      #pragma unroll
      for (int m = 0; m < 16; m++){
        U8 ah;
        ah.q = *(const uint4*)&Abuf[cur][g*2048 + (m*16 + c)*8];
        accA[m] = __builtin_amdgcn_mfma_f32_16x16x32_bf16(ah.v, bhA.v, accA[m], 0, 0, 0);
        accB[m] = __builtin_amdgcn_mfma_f32_16x16x32_bf16(ah.v, bhB.v, accB[m], 0, 0, 0);
      }
    }
    msegA += s32A; if (msegA >= GD) msegA -= GD;
    msegB += s32B; if (msegB >= GD) msegB -= GD;
    __syncthreads();
  }

  #pragma unroll
  for (int nt = 0; nt < 2; nt++){
    const int t = (nt == 0) ? nA : nB;
    const f32x4* acc = (nt == 0) ? accA : accB;
    float pos = (float)t * (127.0f/65535.0f);
    int lo = (int)floorf(pos);
    int hi = imin(lo + 1, 127);
    float fr = pos - (float)lo;
    #pragma unroll
    for (int m = 0; m < 16; m++){
      int e = 2*m + (g >> 1);
      float s = 0.f;
      #pragma unroll
      for (int jj = 0; jj < 4; jj++){
        int i = (g & 1)*4 + jj;
        const float* wr = w_small + (size_t)(e*8 + i)*128;
        float wi = wr[lo]*(1.0f - fr) + wr[hi]*fr;
        s += wi * acc[m][jj];
      }
      s += __shfl_xor(s, 16);
      if ((g & 1) == 0){
        float de = d_small[e*128 + lo]*(1.0f - fr) + d_small[e*128 + hi]*fr;
        dres[(size_t)e*NS + t] = de * s;
      }
    }
  }
}

// ---------------- fallback f32 GEMM ----------------
__global__ __launch_bounds__(256) void gemm_dres_kernel(
    const float* __restrict__ P2, const float* __restrict__ waves,
    const float* __restrict__ w_small, const float* __restrict__ d_small,
    float* __restrict__ dres)
{
  __shared__ __align__(16) float At[32][256];
  __shared__ __align__(16) float Bt[32][64];
  const int tid = threadIdx.x;
  const int tx = tid & 15, ty = tid >> 4;
  const int n0 = blockIdx.x * 64;
  float acc[16][4];
  #pragma unroll
  for (int a = 0; a < 16; a++)
    #pragma unroll
    for (int b = 0; b < 4; b++) acc[a][b] = 0.f;

  for (int k0 = 0; k0 < 1024; k0 += 32){
    {
      const float4* src = (const float4*)(P2 + (size_t)tid*1024 + k0);
      #pragma unroll
      for (int q = 0; q < 8; q++){
        float4 v = src[q];
        At[q*4 + 0][tid] = v.x; At[q*4 + 1][tid] = v.y;
        At[q*4 + 2][tid] = v.z; At[q*4 + 3][tid] = v.w;
      }
    }
    {
      int c  = tid & 15;
      int kr = tid >> 4;
      *(float4*)&Bt[kr][c*4]      = *((const float4*)(waves + (size_t)(k0 + kr)*NS + n0) + c);
      *(float4*)&Bt[kr + 16][c*4] = *((const float4*)(waves + (size_t)(k0 + kr + 16)*NS + n0) + c);
    }
    __syncthreads();
    #pragma unroll 4
    for (int k = 0; k < 32; k++){
      float a[16];
      *(float4*)&a[0]  = *(const float4*)&At[k][ty*16 + 0];
      *(float4*)&a[4]  = *(const float4*)&At[k][ty*16 + 4];
      *(float4*)&a[8]  = *(const float4*)&At[k][ty*16 + 8];
      *(float4*)&a[12] = *(const float4*)&At[k][ty*16 + 12];
      float4 b = *(const float4*)&Bt[k][tx*4];
      #pragma unroll
      for (int mi = 0; mi < 16; mi++){
        acc[mi][0] += a[mi]*b.x;
        acc[mi][1] += a[mi]*b.y;
        acc[mi][2] += a[mi]*b.z;
        acc[mi][3] += a[mi]*b.w;
      }
    }
    __syncthreads();
  }

  #pragma unroll
  for (int ni = 0; ni < 4; ni++){
    int t = n0 + tx*4 + ni;
    float pos = (float)t * (127.0f/65535.0f);
    int lo = (int)floorf(pos);
    int hi = imin(lo + 1, 127);
    float w = pos - (float)lo;
    #pragma unroll
    for (int ev2 = 0; ev2 < 2; ev2++){
      int e = ty*2 + ev2;
      float de = d_small[e*128 + lo]*(1.0f - w) + d_small[e*128 + hi]*w;
      float s = 0.f;
      #pragma unroll
      for (int i = 0; i < 8; i++){
        const float* wrow = w_small + (size_t)(e*8 + i)*128;
        float wi = wrow[lo]*(1.0f - w) + wrow[hi]*w;
        s += wi * acc[ev2*8 + i][ni];
      }
      dres[(size_t)e*NS + t] = de * s;
    }
  }
}

// ================= FFT machinery (four-step, N = 131072 = 256 x 512) =================
// Spectrum layout: S[k2*256 + k1], true k = k2 + 512*k1.
// All grids use blockIdx.y = EVENT-PAIR index (16 pairs).

template<int L, int LOG2L, int DIR>
__device__ __forceinline__ void fft_core(float*& ra, float*& ia, float*& rb, float*& ib)
{
  __shared__ float2 stw[256];
  const int tid = threadIdx.x;
  stw[tid] = twid((float)tid * (1.0f/512.0f));
  #pragma unroll
  for (int s = 0; s < LOG2L; s++){
    const int Ns = 1 << s;
    __syncthreads();
    #pragma unroll
    for (int q = 0; q < 8; q++){
      int bf = tid + 256*q;
      int r  = bf >> (LOG2L - 1);
      int j  = bf & (L/2 - 1);
      int sw = (r & 7) << 2;
      int jm = j & (Ns - 1);
      float2 w = stw[jm << (8 - s)];
      float wi = (DIR > 0) ? w.y : -w.y;
      float a_re = ra[r*L + (j ^ sw)];
      float a_im = ia[r*L + (j ^ sw)];
      float b_re = ra[r*L + ((j + L/2) ^ sw)];
      float b_im = ia[r*L + ((j + L/2) ^ sw)];
      float t_re = b_re*w.x - b_im*wi;
      float t_im = b_re*wi + b_im*w.x;
      int d = ((j >> s) << (s + 1)) | jm;
      rb[r*L + (d ^ sw)]        = a_re + t_re;
      ib[r*L + (d ^ sw)]        = a_im + t_im;
      rb[r*L + ((d + Ns) ^ sw)] = a_re - t_re;
      ib[r*L + ((d + Ns) ^ sw)] = a_im - t_im;
    }
    float* t;
    t = ra; ra = rb; rb = t;
    t = ia; ia = ib; ib = t;
  }
  __syncthreads();
}

// F1: z = a + i*b (two real signals, zero-padded), FFT_512 over n2,
// twiddle, write transposed Bt[k2*256 + n1].  srcA/srcB indexed by e*stride.
__global__ __launch_bounds__(256) void fwd512_pack_kernel(
    const float* __restrict__ srcA, int lenA, int strideA,
    const float* __restrict__ srcB, int lenB, int strideB,
    float2* __restrict__ Bt)
{
  __shared__ float reA[4096], imA[4096], reB[4096], imB[4096];
  const int e = blockIdx.y, t1 = blockIdx.x*8, tid = threadIdx.x;
  #pragma unroll
  for (int q = 0; q < 4; q++){
    int flat = tid + 256*q;
    int n2 = flat >> 1;
    int rb = (flat & 1)*4;
    int nb = t1 + rb + 256*n2;
    float4 va = make_float4(0.f,0.f,0.f,0.f);
    float4 vb = make_float4(0.f,0.f,0.f,0.f);
    if (nb < lenA) va = *(const float4*)(srcA + (size_t)e*strideA + nb);
    if (nb < lenB) vb = *(const float4*)(srcB + (size_t)e*strideB + nb);
    #pragma unroll
    for (int j = 0; j < 4; j++){
      int r = rb + j;
      int sw = (r & 7) << 2;
      reA[r*512 + (n2 ^ sw)] = (&va.x)[j];
      imA[r*512 + (n2 ^ sw)] = (&vb.x)[j];
    }
  }
  float *ra = reA, *ia = imA, *rb2 = reB, *ib2 = imB;
  fft_core<512, 9, +1>(ra, ia, rb2, ib2);
  float2* dst = Bt + ((size_t)e << 17);
  #pragma unroll
  for (int q = 0; q < 16; q++){
    int idx = tid + 256*q;
    int r = idx & 7, k2 = idx >> 3;
    int n1 = t1 + r;
    int sw = (r & 7) << 2;
    float xr = ra[r*512 + (k2 ^ sw)];
    float xi = ia[r*512 + (k2 ^ sw)];
    float2 w = twid((float)(n1*k2) * (1.0f/131072.0f));
    dst[k2*256 + n1] = make_float2(xr*w.x - xi*w.y, xr*w.y + xi*w.x);
  }
}

// F1-rooms: z = rooms[2e] + i*rooms[2e+1] computed inline from verbs/rho.
__global__ __launch_bounds__(256) void fwd512_pack_rooms_kernel(
    const float* __restrict__ verbs, const float* __restrict__ rho,
    float2* __restrict__ Bt)
{
  __shared__ float reA[4096], imA[4096], reB[4096], imB[4096];
  __shared__ float srho[32];
  const int e = blockIdx.y, t1 = blockIdx.x*8, tid = threadIdx.x;
  if (tid < 32) srho[tid] = rho[(2*e)*16 + tid];   // [0..15]=rho[2e], [16..31]=rho[2e+1]
  __syncthreads();
  #pragma unroll
  for (int q = 0; q < 4; q++){
    int flat = tid + 256*q;
    int n2 = flat >> 1;
    int rb = (flat & 1)*4;
    int nb = t1 + rb + 256*n2;
    float4 va = make_float4(0.f,0.f,0.f,0.f);
    float4 vb = make_float4(0.f,0.f,0.f,0.f);
    if (nb < NS){
      #pragma unroll
      for (int v = 0; v < 16; v++){
        float4 w4 = *(const float4*)(verbs + (size_t)v*NS + nb);
        float r0 = srho[v], r1 = srho[16 + v];
        va.x += r0*w4.x; va.y += r0*w4.y; va.z += r0*w4.z; va.w += r0*w4.w;
        vb.x += r1*w4.x; vb.y += r1*w4.y; vb.z += r1*w4.z; vb.w += r1*w4.w;
      }
    }
    #pragma unroll
    for (int j = 0; j < 4; j++){
      int r = rb + j;
      int sw = (r & 7) << 2;
      reA[r*512 + (n2 ^ sw)] = (&va.x)[j];
      imA[r*512 + (n2 ^ sw)] = (&vb.x)[j];
    }
  }
  float *ra = reA, *ia = imA, *rb2 = reB, *ib2 = imB;
  fft_core<512, 9, +1>(ra, ia, rb2, ib2);
  float2* dst = Bt + ((size_t)e << 17);
  #pragma unroll
  for (int q = 0; q < 16; q++){
    int idx = tid + 256*q;
    int r = idx & 7, k2 = idx >> 3;
    int n1 = t1 + r;
    int sw = (r & 7) << 2;
    float xr = ra[r*512 + (k2 ^ sw)];
    float xi = ia[r*512 + (k2 ^ sw)];
    float2 w = twid((float)(n1*k2) * (1.0f/131072.0f));
    dst[k2*256 + n1] = make_float2(xr*w.x - xi*w.y, xr*w.y + xi*w.x);
  }
}

// F2: in-place FFT_256 along contiguous rows (row = k2).
__global__ __launch_bounds__(256) void fwd256_kernel(float2* __restrict__ S)
{
  __shared__ float reA[4096], imA[4096], reB[4096], imB[4096];
  const int e = blockIdx.y, K0 = blockIdx.x*16, tid = threadIdx.x;
  float2* base = S + ((size_t)e << 17) + (size_t)K0*256;
  #pragma unroll
  for (int q = 0; q < 16; q++){
    int idx = tid + 256*q;
    int r = idx >> 8, col = idx & 255;
    float2 v = base[r*256 + col];
    int sw = (r & 7) << 2;
    reA[r*256 + (col ^ sw)] = v.x;
    imA[r*256 + (col ^ sw)] = v.y;
  }
  float *ra = reA, *ia = imA, *rb = reB, *ib = imB;
  fft_core<256, 8, +1>(ra, ia, rb, ib);
  #pragma unroll
  for (int q = 0; q < 16; q++){
    int idx = tid + 256*q;
    int r = idx >> 8, col = idx & 255;
    int sw = (r & 7) << 2;
    base[r*256 + col] = make_float2(ra[r*256 + (col ^ sw)], ia[r*256 + (col ^ sw)]);
  }
}

// I1: Hermitian-unpack TWO packed spectra, per-event product, repack
// Y = P0 + i*P1, inverse FFT_256, conj twiddle, write Ut[n1*512 + k2].
__global__ __launch_bounds__(256) void inv256_mul2_kernel(
    const float2* __restrict__ ZA, const float2* __restrict__ ZB,
    float2* __restrict__ Ut)
{
  __shared__ float reA[4096], imA[4096], reB[4096], imB[4096];
  const int e = blockIdx.y, K0 = blockIdx.x*16, tid = threadIdx.x;
  const float2* Za = ZA + ((size_t)e << 17);
  const float2* Zb = ZB + ((size_t)e << 17);
  #pragma unroll
  for (int q = 0; q < 16; q++){
    int idx = tid + 256*q;
    int r = idx >> 8, col = idx & 255;
    int k2 = K0 + r;
    int k2p, k1p;
    if (k2 == 0){ k2p = 0; k1p = (256 - col) & 255; }
    else        { k2p = 512 - k2; k1p = 255 - col; }
    float2 za  = Za[(size_t)k2*256 + col];
    float2 zap = Za[(size_t)k2p*256 + k1p];
    float2 zb  = Zb[(size_t)k2*256 + col];
    float2 zbp = Zb[(size_t)k2p*256 + k1p];
    // unpack: A0 = spec of first real, A1 = spec of second real
    float a0r = 0.5f*(za.x + zap.x), a0i = 0.5f*(za.y - zap.y);
    float a1r = 0.5f*(za.y + zap.y), a1i = 0.5f*(zap.x - za.x);
    float b0r = 0.5f*(zb.x + zbp.x), b0i = 0.5f*(zb.y - zbp.y);
    float b1r = 0.5f*(zb.y + zbp.y), b1i = 0.5f*(zbp.x - zb.x);
    // products per event
    float p0r = a0r*b0r - a0i*b0i, p0i = a0r*b0i + a0i*b0r;
    float p1r = a1r*b1r - a1i*b1i, p1i = a1r*b1i + a1i*b1r;
    // repack Y = P0 + i*P1
    int sw = (r & 7) << 2;
    reA[r*256 + (col ^ sw)] = p0r - p1i;
    imA[r*256 + (col ^ sw)] = p0i + p1r;
  }
  float *ra = reA, *ia = imA, *rb = reB, *ib = imB;
  fft_core<256, 8, -1>(ra, ia, rb, ib);
  float2* dst = Ut + ((size_t)e << 17);
  #pragma unroll
  for (int q = 0; q < 16; q++){
    int idx = tid + 256*q;
    int r = idx & 15, n1 = idx >> 4;
    int k2 = K0 + r;
    int sw = (r & 7) << 2;
    float xr = ra[r*256 + (n1 ^ sw)];
    float xi = ia[r*256 + (n1 ^ sw)];
    float2 w = twid((float)(n1*k2) * (1.0f/131072.0f));   // conj applied
    dst[n1*512 + k2] = make_float2(xr*w.x + xi*w.y, xi*w.x - xr*w.y);
  }
}

// I2+F1 fused: inverse FFT_512 -> packed conv pair (re=conv[2e], im=conv[2e+1]);
// write both to CONV; truncate (n2>=256 -> 0) and forward FFT_512 + twiddle -> Bt.
__global__ __launch_bounds__(256) void inv512_fwdpack2_kernel(
    const float2* __restrict__ Ut, float* __restrict__ conv,
    float2* __restrict__ Bt)
{
  __shared__ float reA[4096], imA[4096], reB[4096], imB[4096];
  const int e = blockIdx.y, t1 = blockIdx.x*8, tid = threadIdx.x;
  const float2* base = Ut + ((size_t)e << 17) + (size_t)t1*512;
  #pragma unroll
  for (int q = 0; q < 16; q++){
    int idx = tid + 256*q;
    int r = idx >> 9, col = idx & 511;
    float2 v = base[r*512 + col];
    int sw = (r & 7) << 2;
    reA[r*512 + (col ^ sw)] = v.x;
    imA[r*512 + (col ^ sw)] = v.y;
  }
  float *ra = reA, *ia = imA, *rb = reB, *ib = imB;
  fft_core<512, 9, -1>(ra, ia, rb, ib);
  // ra = inverse result; write CONV (both events) + build truncated input in rb/ib
  const float s = 1.0f/131072.0f;
  #pragma unroll
  for (int q = 0; q < 16; q++){
    int idx = tid + 256*q;
    int r = idx & 7, n2 = idx >> 3;
    int sw = (r & 7) << 2;
    int pos = r*512 + (n2 ^ sw);
    if (n2 < 256){
      int n = (t1 + r) + 256*n2;
      float y0 = ra[pos]*s, y1 = ia[pos]*s;
      conv[(size_t)(2*e)*NS + n]     = y0;
      conv[(size_t)(2*e + 1)*NS + n] = y1;
      rb[pos] = y0; ib[pos] = y1;
    } else {
      rb[pos] = 0.f; ib[pos] = 0.f;
    }
  }
  __syncthreads();
  float *r2 = rb, *i2 = ib, *r3 = ra, *i3 = ia;
  fft_core<512, 9, +1>(r2, i2, r3, i3);
  float2* dst = Bt + ((size_t)e << 17);
  #pragma unroll
  for (int q = 0; q < 16; q++){
    int idx = tid + 256*q;
    int r = idx & 7, k2 = idx >> 3;
    int n1 = t1 + r;
    int sw = (r & 7) << 2;
    float xr = r2[r*512 + (k2 ^ sw)];
    float xi = i2[r*512 + (k2 ^ sw)];
    float2 w = twid((float)(n1*k2) * (1.0f/131072.0f));
    dst[k2*256 + n1] = make_float2(xr*w.x - xi*w.y, xr*w.y + xi*w.x);
  }
}

// I2-final: inverse FFT_512 -> packed wet pair; mix with conv, write out.
__global__ __launch_bounds__(256) void inv512_mix2_kernel(
    const float2* __restrict__ Ut, const float* __restrict__ conv,
    const float* __restrict__ scal, float* __restrict__ dst)
{
  __shared__ float reA[4096], imA[4096], reB[4096], imB[4096];
  const int e = blockIdx.y, t1 = blockIdx.x*8, tid = threadIdx.x;
  const float2* base = Ut + ((size_t)e << 17) + (size_t)t1*512;
  #pragma unroll
  for (int q = 0; q < 16; q++){
    int idx = tid + 256*q;
    int r = idx >> 9, col = idx & 511;
    float2 v = base[r*512 + col];
    int sw = (r & 7) << 2;
    reA[r*512 + (col ^ sw)] = v.x;
    imA[r*512 + (col ^ sw)] = v.y;
  }
  float *ra = reA, *ia = imA, *rb = reB, *ib = imB;
  fft_core<512, 9, -1>(ra, ia, rb, ib);
  const float s = 1.0f/131072.0f;
  const int e0 = 2*e, e1 = 2*e + 1;
  float m00 = scal[e0*4 + 0], m10 = scal[e0*4 + 1], a20 = scal[e0*4 + 2];
  float m01 = scal[e1*4 + 0], m11 = scal[e1*4 + 1], a21 = scal[e1*4 + 2];
  #pragma unroll
  for (int q = 0; q < 8; q++){
    int idx = tid + 256*q;
    int r = idx & 7, n2 = idx >> 3;
    int n = (t1 + r) + 256*n2;
    int sw = (r & 7) << 2;
    int pos = r*512 + (n2 ^ sw);
    float w0 = ra[pos]*s, w1 = ia[pos]*s;
    size_t g0 = (size_t)e0*NS + n, g1 = (size_t)e1*NS + n;
    dst[g0] = (m00*conv[g0] + m10*w0)*a20;
    dst[g1] = (m01*conv[g1] + m11*w1)*a21;
  }
}

// ---------------- fallback: direct causal conv ----------------
template<int MODE>
__global__ __launch_bounds__(256) void tconv_kernel(
    const float* __restrict__ sig, int sig_len, int sig_stride,
    const float* __restrict__ go, const float* __restrict__ scal,
    float* __restrict__ dst)
{
  __shared__ __align__(16) float cs[2048];
  __shared__ __align__(16) float rs[4104];
  const int e = blockIdx.y;
  const int t0 = blockIdx.x * 2048;
  const int tid = threadIdx.x;
  const int tb = tid * 8;
  float acc[8] = {0,0,0,0,0,0,0,0};
  const int kcap = imin(sig_len, t0 + 2048);
  for (int c0 = 0; c0 < kcap; c0 += 2048){
    __syncthreads();
    for (int idx = tid; idx < 2048; idx += 256){
      int gsi = c0 + idx;
      cs[idx] = (gsi < sig_len) ? sig[(size_t)e*sig_stride + gsi] : 0.f;
    }
    const int rb = t0 - c0 - 2056;
    for (int idx = tid; idx < 4104; idx += 256){
      int g = rb + idx;
      rs[idx] = (g >= 0 && g < NS) ? go[(size_t)e*NS + g] : 0.f;
    }
    __syncthreads();
    float W[12];
    int P = tb + 2056;
    *(float4*)&W[0] = *(const float4*)&rs[P - 4];
    *(float4*)&W[4] = *(const float4*)&rs[P];
    *(float4*)&W[8] = *(const float4*)&rs[P + 4];
    for (int u = 0; u < 512; u++){
      float4 f4 = *(const float4*)&cs[4*u];
      #pragma unroll
      for (int j = 0; j < 8; j++){
        acc[j] += f4.x*W[4 + j];
        acc[j] += f4.y*W[3 + j];
        acc[j] += f4.z*W[2 + j];
        acc[j] += f4.w*W[1 + j];
      }
      #pragma unroll
      for (int x2 = 11; x2 >= 4; x2--) W[x2] = W[x2 - 4];
      P -= 4;
      *(float4*)&W[0] = *(const float4*)&rs[P - 4];
    }
  }
  if (MODE == 0){
    #pragma unroll
    for (int j = 0; j < 8; j++) dst[(size_t)e*NS + t0 + tb + j] = acc[j];
  } else {
    float m0 = scal[e*4 + 0], m1 = scal[e*4 + 1], a2 = scal[e*4 + 2];
    #pragma unroll
    for (int j = 0; j < 8; j++){
      size_t gi = (size_t)e*NS + t0 + tb + j;
      dst[gi] = (m0*sig[gi] + m1*acc[j]) * a2;
    }
  }
}

// ---------------- launcher ----------------
extern "C" void kernel_launch(void* const* d_in, const int* in_sizes, int n_in,
                              void* d_out, int out_size, void* d_ws, size_t ws_size,
                              hipStream_t stream)
{
  (void)in_sizes; (void)n_in; (void)out_size;
  const float* res_sel     = (const float*)d_in[0];
  const float* noise_sel   = (const float*)d_in[1];
  const float* env_sel     = (const float*)d_in[2];
  const float* dec_sel     = (const float*)d_in[3];
  const float* def_sel     = (const float*)d_in[4];
  const float* ndef_sel    = (const float*)d_in[5];
  const float* mix_sel     = (const float*)d_in[6];
  const float* room_sel    = (const float*)d_in[7];
  const float* amp         = (const float*)d_in[8];
  const float* r_items     = (const float*)d_in[9];
  const float* n_items     = (const float*)d_in[10];
  const float* e_items     = (const float*)d_in[11];
  const float* d_items     = (const float*)d_in[12];
  const float* warp_items  = (const float*)d_in[13];
  const float* nwarp_items = (const float*)d_in[14];
  const float* verbs       = (const float*)d_in[15];
  const float* waves       = (const float*)d_in[16];
  float* ws  = (float*)d_ws;
  float* out = (float*)d_out;

  const bool big_ws = ws_size >= (size_t)O_END * sizeof(float);

  if (big_ws) {
    weights_kernel<<<dim3(NEV), dim3(64), 0, stream>>>(
        noise_sel, env_sel, dec_sel, def_sel, ndef_sel, mix_sel, room_sel, amp,
        d_items, ws + O_SWE, ws + O_SWN, ws + O_SWD, ws + O_SWND,
        ws + O_DSM, ws + O_SCAL, ws + O_RHO);
    envs_kernel<<<dim3(NEV), dim3(128), 0, stream>>>(ws + O_SWE, e_items, ws + O_ENV_SMALL);
    nfil_kernel<<<dim3(128), dim3(256), 0, stream>>>(ws + O_SWN, n_items, ws + O_NFIL);
    warp_kernel<<<dim3(NEV), dim3(128), 0, stream>>>(ws + O_SWD, warp_items, ws + O_WSM);
    nwarp_kernel<<<dim3(NEV), dim3(128), 0, stream>>>(ws + O_SWND, nwarp_items, ws + O_ND);

    p1_softmax_kernel<<<dim3(256), dim3(256), 0, stream>>>(res_sel, ws + O_P1);
    p2_kernel<<<dim3(4, 32), dim3(256), 0, stream>>>(ws + O_P1, r_items, ws + O_P2);

    env_noise_kernel<<<dim3(1024), dim3(256), 0, stream>>>(ws + O_ENV_SMALL, ws + O_IMP);
    filt_kernel<<<dim3(34, NEV), dim3(256), 0, stream>>>(ws + O_NFIL, ws + O_IMP, ws + O_ND, ws + O_FILT);

    unsigned short* Ahi = (unsigned short*)(ws + O_X);
    split_a_kernel<<<dim3(256), dim3(256), 0, stream>>>(ws + O_P2, Ahi);
    gemm_dres_gen2_kernel<<<dim3(512), dim3(256), 0, stream>>>(
        Ahi, ws + O_WSM, ws + O_DSM, ws + O_DRES);

    // ---- event-pair-packed FFT convolution ----
    float2* Xf = (float2*)(ws + O_X);                 // filtered-pair spectra
    float2* Xd = (float2*)(ws + O_X + 4194304);       // dres-pair spectra
    float2* Xr = (float2*)(ws + O_Y);                 // rooms-pair spectra
    float2* Uc = (float2*)(ws + O_Y + 4194304);       // conv product, mid layout
    float2* Xc = Xf;                                  // conv-pair spectra (Xf dead)
    float2* Uw = Xd;                                  // wet product (Xd dead)

    fwd512_pack_kernel<<<dim3(32, 16), dim3(256), 0, stream>>>(
        ws + O_FILT, FLEN, 2*FLEN, ws + O_FILT + FLEN, FLEN, 2*FLEN, Xf);
    fwd256_kernel<<<dim3(32, 16), dim3(256), 0, stream>>>(Xf);
    fwd512_pack_kernel<<<dim3(32, 16), dim3(256), 0, stream>>>(
        ws + O_DRES, NS, 2*NS, ws + O_DRES + NS, NS, 2*NS, Xd);
    fwd256_kernel<<<dim3(32, 16), dim3(256), 0, stream>>>(Xd);
    fwd512_pack_rooms_kernel<<<dim3(32, 16), dim3(256), 0, stream>>>(
        verbs, ws + O_RHO, Xr);
    fwd256_kernel<<<dim3(32, 16), dim3(256), 0, stream>>>(Xr);

    inv256_mul2_kernel<<<dim3(32, 16), dim3(256), 0, stream>>>(Xf, Xd, Uc);
    inv512_fwdpack2_kernel<<<dim3(32, 16), dim3(256), 0, stream>>>(Uc, ws + O_CONV, Xc);
    fwd256_kernel<<<dim3(32, 16), dim3(256), 0, stream>>>(Xc);
    inv256_mul2_kernel<<<dim3(32, 16), dim3(256), 0, stream>>>(Xc, Xr, Uw);
    inv512_mix2_kernel<<<dim3(32, 16), dim3(256), 0, stream>>>(
        Uw, ws + O_CONV, ws + O_SCAL, out);
  } else {
    // fallback: legacy prep + f32 GEMM + direct time-domain conv
    prep_kernel<<<dim3(NEV), dim3(64), 0, stream>>>(
        noise_sel, env_sel, dec_sel, def_sel, ndef_sel, mix_sel, room_sel, amp,
        n_items, e_items, d_items, warp_items, nwarp_items,
        ws + O_ENV_SMALL, ws + O_NFIL, ws + O_ND, ws + O_WSM,
        ws + O_DSM, ws + O_SCAL, ws + O_RHO);
    p1_softmax_kernel<<<dim3(256), dim3(256), 0, stream>>>(res_sel, ws + O_P1);
    p2_kernel<<<dim3(4, 32), dim3(256), 0, stream>>>(ws + O_P1, r_items, ws + O_P2);
    env_noise_kernel<<<dim3(1024), dim3(256), 0, stream>>>(ws + O_ENV_SMALL, ws + O_IMP);
    filt_kernel<<<dim3(34, NEV), dim3(256), 0, stream>>>(ws + O_NFIL, ws + O_IMP, ws + O_ND, ws + O_FILT);
    rooms_kernel<<<dim3(256, NEV), dim3(256), 0, stream>>>(verbs, ws + O_RHO, ws + O_ROOMS);
    gemm_dres_kernel<<<dim3(1024), dim3(256), 0, stream>>>(
        ws + O_P2, waves, ws + O_WSM, ws + O_DSM, ws + O_DRES);
    tconv_kernel<0><<<dim3(32, NEV), dim3(256), 0, stream>>>(
        ws + O_FILT, FLEN, FLEN, ws + O_DRES, (const float*)nullptr, ws + O_CONV);
    tconv_kernel<1><<<dim3(32, NEV), dim3(256), 0, stream>>>(
        ws + O_CONV, NS, NS, ws + O_ROOMS, ws + O_SCAL, out);
  }
}

// Round 8
// 413.436 us; speedup vs baseline: 1.3664x; 1.3664x over previous
//
#include <hip/hip_runtime.h>
#include <math.h>

// ---------------- problem sizes ----------------
#define NEV    32      // n_events
#define NS     65536   // n_samples
#define NFFT   131072  // 2*NS
#define ENVS   128
#define ENVF   8192
#define FSAMP2 512
#define NEXP2  4
#define FLEN   8704    // filtered support (8192 + 512 - 1 -> padded to 8704)
#define GD     5622750u   // 22050*255 (phase denominator)
#define GDH    2811375u   // GD/2

// ---------------- workspace layout (float offsets) ----------------
enum : size_t {
  O_ENV_SMALL = 0,         // 32*128
  O_NFIL      = 4096,      // 32*4*512
  O_IMP       = 69632,     // 32*8192
  O_ND        = 331776,    // 32*4*128
  O_WSM       = 348160,    // 32*8*128
  O_DSM       = 380928,    // 32*128
  O_SCAL      = 385024,    // 32*4  (m0, m1, amp^2)
  O_RHO       = 385152,    // 32*16
  O_P1        = 385664,    // 256*1024
  O_P2        = 647808,    // 256*1024
  O_FILT      = 909952,    // 32*8704
  O_DRES      = 1188480,   // 32*65536
  O_CONV      = 3285632,   // 32*65536
  O_ROOMS     = 5382784,   // 32*65536 (fallback path only)
  O_SWE       = 7479936,   // 32*64
  O_SWN       = 7482048,   // 32*4*64
  O_SWD       = 7490304,   // 32*64
  O_SWND      = 7492416,   // 32*32
  O_X         = 7742080,   // 8,388,608 floats: Xf | Xd  (16 pair-slices each)
  O_Y         = 16130688,  // 8,388,608 floats: Xr | Uc
  O_END       = 24519296,  // *4 bytes = 98,077,184
};

typedef float f32x4 __attribute__((ext_vector_type(4)));
typedef short bf16x8 __attribute__((ext_vector_type(8)));

union U8 { uint4 q; bf16x8 v; unsigned short u[8]; };

__device__ __forceinline__ int imin(int a, int b){ return a < b ? a : b; }

__device__ __forceinline__ float wsum(float v){
  #pragma unroll
  for (int o = 32; o > 0; o >>= 1) v += __shfl_xor(v, o);
  return v;
}
__device__ __forceinline__ float wmax(float v){
  #pragma unroll
  for (int o = 32; o > 0; o >>= 1) v = fmaxf(v, __shfl_xor(v, o));
  return v;
}

__device__ __forceinline__ unsigned short f2bf(float f){
  unsigned u = __float_as_uint(f);
  unsigned r = (u + 0x7fffu + ((u >> 16) & 1u)) >> 16;
  return (unsigned short)r;
}

// e^{-2*pi*i*frac} via HW trig (input in revolutions)
__device__ __forceinline__ float2 twid(float frac){
  float c, s;
  asm("v_cos_f32 %0, %1" : "=v"(c) : "v"(frac));
  asm("v_sin_f32 %0, %1" : "=v"(s) : "v"(frac));
  return make_float2(c, -s);
}

// ---------------- JAX threefry2x32, partitionable 32-bit path ----------------
__device__ __forceinline__ unsigned tf_rotl(unsigned x, int d){ return (x << d) | (x >> (32 - d)); }

__device__ unsigned threefry_bits(unsigned chi, unsigned clo){
  const unsigned k0 = 0u, k1 = 42u, k2 = 0x1BD11BDAu ^ 0u ^ 42u;
  unsigned x0 = chi + k0;
  unsigned x1 = clo + k1;
  x0 += x1; x1 = tf_rotl(x1,13); x1 ^= x0;
  x0 += x1; x1 = tf_rotl(x1,15); x1 ^= x0;
  x0 += x1; x1 = tf_rotl(x1,26); x1 ^= x0;
  x0 += x1; x1 = tf_rotl(x1, 6); x1 ^= x0;
  x0 += k1; x1 += k2 + 1u;
  x0 += x1; x1 = tf_rotl(x1,17); x1 ^= x0;
  x0 += x1; x1 = tf_rotl(x1,29); x1 ^= x0;
  x0 += x1; x1 = tf_rotl(x1,16); x1 ^= x0;
  x0 += x1; x1 = tf_rotl(x1,24); x1 ^= x0;
  x0 += k2; x1 += k0 + 2u;
  x0 += x1; x1 = tf_rotl(x1,13); x1 ^= x0;
  x0 += x1; x1 = tf_rotl(x1,15); x1 ^= x0;
  x0 += x1; x1 = tf_rotl(x1,26); x1 ^= x0;
  x0 += x1; x1 = tf_rotl(x1, 6); x1 ^= x0;
  x0 += k0; x1 += k1 + 3u;
  x0 += x1; x1 = tf_rotl(x1,17); x1 ^= x0;
  x0 += x1; x1 = tf_rotl(x1,29); x1 ^= x0;
  x0 += x1; x1 = tf_rotl(x1,16); x1 ^= x0;
  x0 += x1; x1 = tf_rotl(x1,24); x1 ^= x0;
  x0 += k1; x1 += k2 + 4u;
  x0 += x1; x1 = tf_rotl(x1,13); x1 ^= x0;
  x0 += x1; x1 = tf_rotl(x1,15); x1 ^= x0;
  x0 += x1; x1 = tf_rotl(x1,26); x1 ^= x0;
  x0 += x1; x1 = tf_rotl(x1, 6); x1 ^= x0;
  x0 += k2; x1 += k0 + 5u;
  return x0 ^ x1;
}

// ---------------- weights: softmaxes + decay/mix/room ----------------
__global__ __launch_bounds__(64) void weights_kernel(
    const float* __restrict__ noise_sel, const float* __restrict__ env_sel,
    const float* __restrict__ dec_sel,   const float* __restrict__ def_sel,
    const float* __restrict__ ndef_sel,  const float* __restrict__ mix_sel,
    const float* __restrict__ room_sel,  const float* __restrict__ amp,
    const float* __restrict__ d_items,
    float* __restrict__ swE, float* __restrict__ swN,
    float* __restrict__ swD, float* __restrict__ swND,
    float* __restrict__ d_small, float* __restrict__ scal,
    float* __restrict__ rho)
{
  const int e = blockIdx.x;
  const int l = threadIdx.x;

  {
    float x = env_sel[e*64 + l];
    float mx = wmax(x);
    float ex = expf(x - mx);
    float sm = wsum(ex);
    swE[e*64 + l] = ex / sm;
  }
  #pragma unroll
  for (int x4 = 0; x4 < NEXP2; x4++){
    float v = noise_sel[(e*NEXP2 + x4)*64 + l];
    float mxv = wmax(v);
    float exv = expf(v - mxv);
    float smv = wsum(exv);
    swN[(e*NEXP2 + x4)*64 + l] = exv / smv;
  }
  {
    float x = def_sel[e*64 + l];
    float mx = wmax(x);
    float ex = expf(x - mx);
    float sm = wsum(ex);
    swD[e*64 + l] = ex / sm;
  }
  {
    float x = (l < 32) ? ndef_sel[e*32 + l] : -1e30f;
    float mx = wmax(x);
    float ex = (l < 32) ? expf(x - mx) : 0.f;
    float sm = wsum(ex);
    if (l < 32) swND[e*32 + l] = ex / sm;
  }
  {
    float x = dec_sel[e*64 + l];
    float mx = wmax(x);
    float ex = expf(x - mx);
    float sm = wsum(ex);
    float wgt = ex / sm;
    float di = d_items[l];
    float dp = 0.5f + 0.5f*(1.0f/(1.0f + expf(-di)));
    float d0 = wsum(wgt*dp);
    float ld = logf(d0 + 1e-12f);
    #pragma unroll
    for (int c = 0; c < 2; c++){
      int f = l + 64*c;
      d_small[e*128 + f] = expf((float)(f+1)*ld);
    }
  }
  if (l == 0){
    float a = mix_sel[e*2 + 0], b = mix_sel[e*2 + 1];
    float mm = fmaxf(a, b);
    float ea = expf(a - mm), eb = expf(b - mm);
    float ss = ea + eb;
    scal[e*4 + 0] = ea/ss;
    scal[e*4 + 1] = eb/ss;
    float am = amp[e];
    scal[e*4 + 2] = am*am;
  }
  {
    float x = (l < 16) ? room_sel[e*16 + l] : -1e30f;
    float mx = wmax(x);
    float ex = (l < 16) ? expf(x - mx) : 0.f;
    float sm = wsum(ex);
    if (l < 16) rho[e*16 + l] = ex/sm;
  }
}

// ---------------- output-parallel small lookups ----------------
__global__ __launch_bounds__(128) void envs_kernel(
    const float* __restrict__ swE, const float* __restrict__ e_items,
    float* __restrict__ env_small)
{
  const int e = blockIdx.x, j = threadIdx.x;
  __shared__ float sw[64];
  if (j < 64) sw[j] = swE[e*64 + j];
  __syncthreads();
  float acc = 0.f;
  #pragma unroll 8
  for (int k = 0; k < 64; k++){ float it = e_items[k*ENVS + j]; acc += sw[k]*(it*it); }
  env_small[e*ENVS + j] = acc;
}

__global__ __launch_bounds__(256) void nfil_kernel(
    const float* __restrict__ swN, const float* __restrict__ n_items,
    float* __restrict__ nfil)
{
  const int b = blockIdx.x;
  const int tid = threadIdx.x;
  __shared__ float sw[64];
  if (tid < 64) sw[tid] = swN[b*64 + tid];
  __syncthreads();
  #pragma unroll
  for (int c = 0; c < 2; c++){
    int tau = tid + 256*c;
    float acc = 0.f;
    #pragma unroll 8
    for (int f = 0; f < 64; f++) acc += sw[f]*n_items[f*FSAMP2 + tau];
    float ham = 0.54f - 0.46f*cosf((6.2831853071795864769f * (float)tau) / 511.0f);
    nfil[b*FSAMP2 + tau] = acc*ham;
  }
}

__global__ __launch_bounds__(128) void warp_kernel(
    const float* __restrict__ swD, const float* __restrict__ warp_items,
    float* __restrict__ w_small)
{
  const int e = blockIdx.x, f = threadIdx.x;
  __shared__ float sw[64];
  if (f < 64) sw[f] = swD[e*64 + f];
  __syncthreads();
  float acc[8] = {0,0,0,0,0,0,0,0};
  for (int k = 0; k < 64; k++){
    float wk = sw[k];
    const float* row = warp_items + (size_t)k*1024 + f;
    #pragma unroll
    for (int i = 0; i < 8; i++) acc[i] += wk*row[i*128];
  }
  float mx = -1e30f;
  #pragma unroll
  for (int i = 0; i < 8; i++) mx = fmaxf(mx, acc[i]);
  float ev[8]; float s = 0.f;
  #pragma unroll
  for (int i = 0; i < 8; i++){ ev[i] = expf(acc[i] - mx); s += ev[i]; }
  #pragma unroll
  for (int i = 0; i < 8; i++) w_small[(e*8 + i)*128 + f] = ev[i]/s;
}

__global__ __launch_bounds__(128) void nwarp_kernel(
    const float* __restrict__ swND, const float* __restrict__ nwarp_items,
    float* __restrict__ nd_small)
{
  const int e = blockIdx.x, f = threadIdx.x;
  __shared__ float sw[32];
  if (f < 32) sw[f] = swND[e*32 + f];
  __syncthreads();
  float acc[4] = {0,0,0,0};
  for (int k = 0; k < 32; k++){
    float wk = sw[k];
    const float* row = nwarp_items + (size_t)k*512 + f;
    #pragma unroll
    for (int x = 0; x < 4; x++) acc[x] += wk*row[x*128];
  }
  float mx = -1e30f;
  #pragma unroll
  for (int x = 0; x < 4; x++) mx = fmaxf(mx, acc[x]);
  float ev[4]; float s = 0.f;
  #pragma unroll
  for (int x = 0; x < 4; x++){ ev[x] = expf(acc[x] - mx); s += ev[x]; }
  #pragma unroll
  for (int x = 0; x < 4; x++) nd_small[(e*4 + x)*128 + f] = ev[x]/s;
}

// ---------------- legacy prep (fallback path only) ----------------
__global__ __launch_bounds__(64) void prep_kernel(
    const float* __restrict__ noise_sel, const float* __restrict__ env_sel,
    const float* __restrict__ dec_sel,   const float* __restrict__ def_sel,
    const float* __restrict__ ndef_sel,  const float* __restrict__ mix_sel,
    const float* __restrict__ room_sel,  const float* __restrict__ amp,
    const float* __restrict__ n_items,   const float* __restrict__ e_items,
    const float* __restrict__ d_items,   const float* __restrict__ warp_items,
    const float* __restrict__ nwarp_items,
    float* __restrict__ env_small, float* __restrict__ nfil,
    float* __restrict__ nd_small,  float* __restrict__ w_small,
    float* __restrict__ d_small,   float* __restrict__ scal,
    float* __restrict__ rho)
{
  const int e = blockIdx.x;
  const int l = threadIdx.x;
  __shared__ float sw[64];
  __shared__ float buf[1024];

  {
    float x = env_sel[e*64 + l];
    float mx = wmax(x);
    float ex = expf(x - mx);
    float sm = wsum(ex);
    sw[l] = ex / sm;
  }
  __syncthreads();
  #pragma unroll
  for (int c = 0; c < 2; c++){
    int j = l + 64*c;
    float acc = 0.f;
    for (int k = 0; k < 64; k++){ float it = e_items[k*ENVS + j]; acc += sw[k]*(it*it); }
    env_small[e*ENVS + j] = acc;
  }
  __syncthreads();

  for (int x = 0; x < NEXP2; x++){
    float v = noise_sel[(e*NEXP2 + x)*64 + l];
    float mxv = wmax(v);
    float exv = expf(v - mxv);
    float smv = wsum(exv);
    sw[l] = exv / smv;
    __syncthreads();
    for (int c = 0; c < 8; c++){
      int tau = l + 64*c;
      float acc = 0.f;
      for (int f = 0; f < 64; f++) acc += sw[f]*n_items[f*FSAMP2 + tau];
      float ham = 0.54f - 0.46f*cosf((6.2831853071795864769f * (float)tau) / 511.0f);
      nfil[(e*NEXP2 + x)*FSAMP2 + tau] = acc*ham;
    }
    __syncthreads();
  }

  {
    float x = def_sel[e*64 + l];
    float mx = wmax(x);
    float ex = expf(x - mx);
    float sm = wsum(ex);
    sw[l] = ex / sm;
  }
  __syncthreads();
  for (int c = 0; c < 16; c++){
    int idx = l + 64*c;
    float acc = 0.f;
    for (int k = 0; k < 64; k++) acc += sw[k]*warp_items[k*1024 + idx];
    buf[idx] = acc;
  }
  __syncthreads();
  #pragma unroll
  for (int c = 0; c < 2; c++){
    int f = l + 64*c;
    float mx = -1e30f;
    for (int i = 0; i < 8; i++) mx = fmaxf(mx, buf[i*128 + f]);
    float ev[8]; float s = 0.f;
    for (int i = 0; i < 8; i++){ ev[i] = expf(buf[i*128 + f] - mx); s += ev[i]; }
    for (int i = 0; i < 8; i++) w_small[(e*8 + i)*128 + f] = ev[i]/s;
  }
  __syncthreads();

  {
    float x = (l < 32) ? ndef_sel[e*32 + l] : -1e30f;
    float mx = wmax(x);
    float ex = (l < 32) ? expf(x - mx) : 0.f;
    float sm = wsum(ex);
    sw[l] = (l < 32) ? ex/sm : 0.f;
  }
  __syncthreads();
  for (int c = 0; c < 8; c++){
    int idx = l + 64*c;
    float acc = 0.f;
    for (int k = 0; k < 32; k++) acc += sw[k]*nwarp_items[k*512 + idx];
    buf[idx] = acc;
  }
  __syncthreads();
  #pragma unroll
  for (int c = 0; c < 2; c++){
    int j = l + 64*c;
    float mx = -1e30f;
    for (int x = 0; x < 4; x++) mx = fmaxf(mx, buf[x*128 + j]);
    float ev[4]; float s = 0.f;
    for (int x = 0; x < 4; x++){ ev[x] = expf(buf[x*128 + j] - mx); s += ev[x]; }
    for (int x = 0; x < 4; x++) nd_small[(e*4 + x)*128 + j] = ev[x]/s;
  }
  __syncthreads();

  {
    float x = dec_sel[e*64 + l];
    float mx = wmax(x);
    float ex = expf(x - mx);
    float sm = wsum(ex);
    float wgt = ex / sm;
    float di = d_items[l];
    float dp = 0.5f + 0.5f*(1.0f/(1.0f + expf(-di)));
    float d0 = wsum(wgt*dp);
    float ld = logf(d0 + 1e-12f);
    #pragma unroll
    for (int c = 0; c < 2; c++){
      int f = l + 64*c;
      d_small[e*128 + f] = expf((float)(f+1)*ld);
    }
  }
  if (l == 0){
    float a = mix_sel[e*2 + 0], b = mix_sel[e*2 + 1];
    float mm = fmaxf(a, b);
    float ea = expf(a - mm), eb = expf(b - mm);
    float ss = ea + eb;
    scal[e*4 + 0] = ea/ss;
    scal[e*4 + 1] = eb/ss;
    float am = amp[e];
    scal[e*4 + 2] = am*am;
  }
  {
    float x = (l < 16) ? room_sel[e*16 + l] : -1e30f;
    float mx = wmax(x);
    float ex = (l < 16) ? expf(x - mx) : 0.f;
    float sm = wsum(ex);
    if (l < 16) rho[e*16 + l] = ex/sm;
  }
}

// ---------------- P1 = softmax(res_sel) ----------------
__global__ __launch_bounds__(256) void p1_softmax_kernel(
    const float* __restrict__ res_sel, float* __restrict__ P1)
{
  const int m = blockIdx.x;
  const int tid = threadIdx.x;
  __shared__ float red[4], red2[4];
  const float* row = res_sel + (size_t)m*1024;
  float4 v = ((const float4*)row)[tid];
  float mx = fmaxf(fmaxf(v.x, v.y), fmaxf(v.z, v.w));
  #pragma unroll
  for (int o = 32; o > 0; o >>= 1) mx = fmaxf(mx, __shfl_xor(mx, o));
  if ((tid & 63) == 0) red[tid >> 6] = mx;
  __syncthreads();
  mx = fmaxf(fmaxf(red[0], red[1]), fmaxf(red[2], red[3]));
  float e0 = expf(v.x - mx), e1 = expf(v.y - mx), e2 = expf(v.z - mx), e3 = expf(v.w - mx);
  float s = e0 + e1 + e2 + e3;
  #pragma unroll
  for (int o = 32; o > 0; o >>= 1) s += __shfl_xor(s, o);
  if ((tid & 63) == 0) red2[tid >> 6] = s;
  __syncthreads();
  s = red2[0] + red2[1] + red2[2] + red2[3];
  float inv = 1.0f/s;
  ((float4*)(P1 + (size_t)m*1024))[tid] = make_float4(e0*inv, e1*inv, e2*inv, e3*inv);
}

// ---------------- P2 = P1 @ r_items ----------------
__global__ __launch_bounds__(256) void p2_kernel(
    const float* __restrict__ P1, const float* __restrict__ r_items,
    float* __restrict__ P2)
{
  __shared__ __align__(16) float sp1[8][1024];
  const int bx = blockIdx.x;
  const int mg = blockIdx.y;
  const int tid = threadIdx.x;
  for (int idx = tid; idx < 2048; idx += 256)
    ((float4*)&sp1[0][0])[idx] = ((const float4*)(P1 + (size_t)mg*8*1024))[idx];
  __syncthreads();
  const int n = bx*256 + tid;
  float acc[8] = {0,0,0,0,0,0,0,0};
  for (int k = 0; k < 1024; k++){
    float wv = r_items[(size_t)k*1024 + n];
    #pragma unroll
    for (int r = 0; r < 8; r++) acc[r] += sp1[r][k]*wv;
  }
  #pragma unroll
  for (int r = 0; r < 8; r++) P2[(size_t)(mg*8 + r)*1024 + n] = acc[r];
}

// ---------------- split A = P2 into bf16 hi (fragment order) ----------------
__global__ __launch_bounds__(256) void split_a_kernel(
    const float* __restrict__ P2, unsigned short* __restrict__ Ahi)
{
  const int row = blockIdx.x;
  for (int k = threadIdx.x; k < 1024; k += 256){
    float f = P2[(size_t)row*1024 + k];
    Ahi[(size_t)(k >> 3)*2048 + row*8 + (k & 7)] = f2bf(f);
  }
}

// ---------------- impulses = interp(env_small,8192) * uniform_noise ----------------
__global__ __launch_bounds__(256) void env_noise_kernel(
    const float* __restrict__ env_small, float* __restrict__ impulses)
{
  const int flat = blockIdx.x*256 + threadIdx.x;
  const int e = flat >> 13, i = flat & 8191;
  unsigned bits = threefry_bits(0u, (unsigned)flat);
  float u01 = __uint_as_float((bits >> 9) | 0x3f800000u) - 1.0f;
  float nz  = fmaxf(-1.0f, u01*2.0f - 1.0f);
  float pos = (float)i * (127.0f/8191.0f);
  int lo = (int)floorf(pos);
  int hi = imin(lo + 1, 127);
  float w = pos - (float)lo;
  const float* es = env_small + e*ENVS;
  float v = es[lo]*(1.0f - w) + es[hi]*w;
  impulses[flat] = v*nz;
}

// ---------------- filtered: 512-tap FIR + nd combine ----------------
__global__ __launch_bounds__(256) void filt_kernel(
    const float* __restrict__ nfil, const float* __restrict__ impulses,
    const float* __restrict__ nd_small, float* __restrict__ filtered)
{
  __shared__ float nf[4*512];
  __shared__ float imp[768];
  const int e = blockIdx.y, t0 = blockIdx.x*256, tid = threadIdx.x;
  for (int idx = tid; idx < 2048; idx += 256) nf[idx] = nfil[e*2048 + idx];
  for (int idx = tid; idx < 768; idx += 256){
    int g = t0 - 512 + idx;
    imp[idx] = (g >= 0 && g < ENVF) ? impulses[e*ENVF + g] : 0.f;
  }
  __syncthreads();
  const int t = t0 + tid;
  float s0 = 0.f, s1 = 0.f, s2 = 0.f, s3 = 0.f;
  for (int tau = 0; tau < 512; tau++){
    float iv = imp[512 + tid - tau];
    s0 += nf[0*512 + tau]*iv;
    s1 += nf[1*512 + tau]*iv;
    s2 += nf[2*512 + tau]*iv;
    s3 += nf[3*512 + tau]*iv;
  }
  float pos = (float)t * (127.0f/65535.0f);
  int lo = (int)floorf(pos);
  int hi = imin(lo + 1, 127);
  float w = pos - (float)lo;
  const float* nds = nd_small + e*512;
  float acc = 0.f;
  acc += s0*(nds[0*128 + lo]*(1.0f - w) + nds[0*128 + hi]*w);
  acc += s1*(nds[1*128 + lo]*(1.0f - w) + nds[1*128 + hi]*w);
  acc += s2*(nds[2*128 + lo]*(1.0f - w) + nds[2*128 + hi]*w);
  acc += s3*(nds[3*128 + lo]*(1.0f - w) + nds[3*128 + hi]*w);
  filtered[e*FLEN + t] = acc;
}

// ---------------- rooms (fallback path only) ----------------
__global__ __launch_bounds__(256) void rooms_kernel(
    const float* __restrict__ verbs, const float* __restrict__ rho,
    float* __restrict__ rooms)
{
  const int t = blockIdx.x*256 + threadIdx.x;
  const int e = blockIdx.y;
  float acc = 0.f;
  #pragma unroll
  for (int v = 0; v < 16; v++) acc += rho[e*16 + v]*verbs[(size_t)v*NS + t];
  rooms[(size_t)e*NS + t] = acc;
}

// ---------------- rare-path waveform: exact f64 replication of numpy ----------------
__device__ __noinline__ float slow_wave(int wf, int n, int i){
  const double stp = 3980.0 / 255.0;
  double fi = (i == 255) ? 4000.0 : __dadd_rn(__dmul_rn((double)i, stp), 20.0);
  double tn = (double)n / 22050.0;
  double ph = __dmul_rn(fi, tn);
  double fr = ph - trunc(ph);
  if (wf == 1) return (float)(2.0*fr - 1.0);
  if (wf == 3){ double sw = 2.0*fr - 1.0; return (float)(2.0*fabs(sw) - 1.0); }
  if (fr == 0.0 || fr == 0.5){
    if (ph == 0.0) return 0.0f;
    double sv = sin(__dmul_rn(6.283185307179586, ph));
    return (sv > 0.0) ? 1.0f : ((sv < 0.0) ? -1.0f : 0.0f);
  }
  return (fr < 0.5) ? 1.0f : -1.0f;
}

// generate 8 wave values (rows i0..i0+7, column n) and split to bf16 hi/lo
__device__ __forceinline__ void gen8(int wf, int n, int i0,
                                     unsigned m_in, unsigned stepn,
                                     U8& bh, U8& bl)
{
  unsigned m = m_in;
  #pragma unroll
  for (int j = 0; j < 8; j++){
    float fr = (float)m * (1.0f/5622750.0f);
    float val;
    bool rare;
    if (wf == 0){
      asm("v_sin_f32 %0, %1" : "=v"(val) : "v"(fr));
      rare = false;
    } else if (wf == 1){
      val = fmaf(fr, 2.0f, -1.0f);
      rare = (m == 0u);
    } else if (wf == 2){
      val = (m < GDH) ? 1.0f : -1.0f;
      rare = (m == 0u) || (m == GDH);
    } else {
      val = fmaf(fabsf(fmaf(fr, 2.0f, -1.0f)), 2.0f, -1.0f);
      rare = (m == 0u);
    }
    if (rare) val = slow_wave(wf, n, i0 + j);
    unsigned ub = __float_as_uint(val);
    unsigned th = ub & 0xFFFF0000u;
    float lres = val - __uint_as_float(th);
    bh.u[j] = (unsigned short)(ub >> 16);
    bl.u[j] = (unsigned short)(__float_as_uint(lres) >> 16);
    m += stepn;
    if (m >= GD) m -= GD;
  }
}

// ---------------- MFMA GEMM v3: 512 thr / 8 waves, one 16-col tile per wave ----
// M=256, N=65536, K=1024. Grid 512 blocks. BN=128, wave w owns cols
// [n0+16w, +16). Per-thread: ONE column's B-gen (8 vals/step), acc = 16 f32x4.
// A slice (16KB/k-step) via global_load_lds double-buffer shared by 8 waves.
__global__ __launch_bounds__(512, 2) void gemm_dres_gen3_kernel(
    const unsigned short* __restrict__ Ahi,
    const float* __restrict__ w_small, const float* __restrict__ d_small,
    float* __restrict__ dres)
{
  __shared__ __align__(16) unsigned short Abuf[2][8192];   // 2 x 16 KB

  const int tid = threadIdx.x;
  const int l = tid & 63, w = tid >> 6;   // 8 waves
  const int g = l >> 4, c = l & 15;
  const int n = blockIdx.x*128 + w*16 + c;

  f32x4 acc[16];
  #pragma unroll
  for (int m = 0; m < 16; m++) acc[m] = (f32x4){0.f,0.f,0.f,0.f};

  // modular phase state: m(i) = (n*(3980*i + 5100)) mod GD ; i0 = (k0&255)+g*8
  const unsigned stepn = (3980u*(unsigned)n) % GD;
  const unsigned s32 = (32u*stepn) % GD;
  const unsigned K0g = 3980u*(unsigned)(g*8) + 5100u;
  const unsigned m0 = (unsigned)(((unsigned long long)(unsigned)n * K0g) % GD);
  unsigned mseg = m0;

  typedef const __attribute__((address_space(1))) void GV;
  typedef __attribute__((address_space(3))) void LV;

  // prologue: stage k0=0 slice (2 issues x 8KB; per-wave linear chunks)
  #pragma unroll
  for (int q = 0; q < 2; q++){
    const unsigned short* src = Ahi + (size_t)q*4096 + (size_t)w*512 + (size_t)l*8;
    __builtin_amdgcn_global_load_lds((GV*)src, (LV*)&Abuf[0][q*4096 + w*512], 16, 0, 0);
  }
  __syncthreads();

  for (int k0 = 0; k0 < 1024; k0 += 32){
    const int cur = (k0 >> 5) & 1, nxt = cur ^ 1;
    const int wf = k0 >> 8;
    if ((k0 & 255) == 0) mseg = m0;

    if (k0 + 32 < 1024){
      const size_t slice = (size_t)((k0 + 32) >> 5) * 8192;
      #pragma unroll
      for (int q = 0; q < 2; q++){
        const unsigned short* src = Ahi + slice + (size_t)q*4096 + (size_t)w*512 + (size_t)l*8;
        __builtin_amdgcn_global_load_lds((GV*)src, (LV*)&Abuf[nxt][q*4096 + w*512], 16, 0, 0);
      }
    }

    const int i0 = (k0 & 255) + g*8;
    U8 bh, bl;
    gen8(wf, n, i0, mseg, stepn, bh, bl);
    mseg += s32; if (mseg >= GD) mseg -= GD;

    #pragma unroll
    for (int m = 0; m < 16; m++){
      U8 ah;
      ah.q = *(const uint4*)&Abuf[cur][g*2048 + (m*16 + c)*8];
      acc[m] = __builtin_amdgcn_mfma_f32_16x16x32_bf16(ah.v, bh.v, acc[m], 0, 0, 0);
      acc[m] = __builtin_amdgcn_mfma_f32_16x16x32_bf16(ah.v, bl.v, acc[m], 0, 0, 0);
    }
    __syncthreads();   // drains stage vmcnt + protects buffer swap
  }

  // epilogue: dres[e,t] = d_e(t) * sum_i w_i(t) * res[e*8+i, t]
  const int t = n;
  float pos = (float)t * (127.0f/65535.0f);
  int lo = (int)floorf(pos);
  int hi = imin(lo + 1, 127);
  float fr = pos - (float)lo;
  #pragma unroll
  for (int m = 0; m < 16; m++){
    int e = 2*m + (g >> 1);
    float s = 0.f;
    #pragma unroll
    for (int jj = 0; jj < 4; jj++){
      int i = (g & 1)*4 + jj;
      const float* wr = w_small + (size_t)(e*8 + i)*128;
      float wi = wr[lo]*(1.0f - fr) + wr[hi]*fr;
      s += wi * acc[m][jj];
    }
    s += __shfl_xor(s, 16);
    if ((g & 1) == 0){
      float de = d_small[e*128 + lo]*(1.0f - fr) + d_small[e*128 + hi]*fr;
      dres[(size_t)e*NS + t] = de * s;
    }
  }
}

// ---------------- fallback f32 GEMM ----------------
__global__ __launch_bounds__(256) void gemm_dres_kernel(
    const float* __restrict__ P2, const float* __restrict__ waves,
    const float* __restrict__ w_small, const float* __restrict__ d_small,
    float* __restrict__ dres)
{
  __shared__ __align__(16) float At[32][256];
  __shared__ __align__(16) float Bt[32][64];
  const int tid = threadIdx.x;
  const int tx = tid & 15, ty = tid >> 4;
  const int n0 = blockIdx.x * 64;
  float acc[16][4];
  #pragma unroll
  for (int a = 0; a < 16; a++)
    #pragma unroll
    for (int b = 0; b < 4; b++) acc[a][b] = 0.f;

  for (int k0 = 0; k0 < 1024; k0 += 32){
    {
      const float4* src = (const float4*)(P2 + (size_t)tid*1024 + k0);
      #pragma unroll
      for (int q = 0; q < 8; q++){
        float4 v = src[q];
        At[q*4 + 0][tid] = v.x; At[q*4 + 1][tid] = v.y;
        At[q*4 + 2][tid] = v.z; At[q*4 + 3][tid] = v.w;
      }
    }
    {
      int c  = tid & 15;
      int kr = tid >> 4;
      *(float4*)&Bt[kr][c*4]      = *((const float4*)(waves + (size_t)(k0 + kr)*NS + n0) + c);
      *(float4*)&Bt[kr + 16][c*4] = *((const float4*)(waves + (size_t)(k0 + kr + 16)*NS + n0) + c);
    }
    __syncthreads();
    #pragma unroll 4
    for (int k = 0; k < 32; k++){
      float a[16];
      *(float4*)&a[0]  = *(const float4*)&At[k][ty*16 + 0];
      *(float4*)&a[4]  = *(const float4*)&At[k][ty*16 + 4];
      *(float4*)&a[8]  = *(const float4*)&At[k][ty*16 + 8];
      *(float4*)&a[12] = *(const float4*)&At[k][ty*16 + 12];
      float4 b = *(const float4*)&Bt[k][tx*4];
      #pragma unroll
      for (int mi = 0; mi < 16; mi++){
        acc[mi][0] += a[mi]*b.x;
        acc[mi][1] += a[mi]*b.y;
        acc[mi][2] += a[mi]*b.z;
        acc[mi][3] += a[mi]*b.w;
      }
    }
    __syncthreads();
  }

  #pragma unroll
  for (int ni = 0; ni < 4; ni++){
    int t = n0 + tx*4 + ni;
    float pos = (float)t * (127.0f/65535.0f);
    int lo = (int)floorf(pos);
    int hi = imin(lo + 1, 127);
    float w = pos - (float)lo;
    #pragma unroll
    for (int ev2 = 0; ev2 < 2; ev2++){
      int e = ty*2 + ev2;
      float de = d_small[e*128 + lo]*(1.0f - w) + d_small[e*128 + hi]*w;
      float s = 0.f;
      #pragma unroll
      for (int i = 0; i < 8; i++){
        const float* wrow = w_small + (size_t)(e*8 + i)*128;
        float wi = wrow[lo]*(1.0f - w) + wrow[hi]*w;
        s += wi * acc[ev2*8 + i][ni];
      }
      dres[(size_t)e*NS + t] = de * s;
    }
  }
}

// ================= FFT machinery (four-step, N = 131072 = 256 x 512) =================
// Spectrum layout: S[k2*256 + k1], true k = k2 + 512*k1.
// All grids use blockIdx.y = EVENT-PAIR index (16 pairs).

template<int L, int LOG2L, int DIR>
__device__ __forceinline__ void fft_core(float*& ra, float*& ia, float*& rb, float*& ib)
{
  __shared__ float2 stw[256];
  const int tid = threadIdx.x;
  stw[tid] = twid((float)tid * (1.0f/512.0f));
  #pragma unroll
  for (int s = 0; s < LOG2L; s++){
    const int Ns = 1 << s;
    __syncthreads();
    #pragma unroll
    for (int q = 0; q < 8; q++){
      int bf = tid + 256*q;
      int r  = bf >> (LOG2L - 1);
      int j  = bf & (L/2 - 1);
      int sw = (r & 7) << 2;
      int jm = j & (Ns - 1);
      float2 w = stw[jm << (8 - s)];
      float wi = (DIR > 0) ? w.y : -w.y;
      float a_re = ra[r*L + (j ^ sw)];
      float a_im = ia[r*L + (j ^ sw)];
      float b_re = ra[r*L + ((j + L/2) ^ sw)];
      float b_im = ia[r*L + ((j + L/2) ^ sw)];
      float t_re = b_re*w.x - b_im*wi;
      float t_im = b_re*wi + b_im*w.x;
      int d = ((j >> s) << (s + 1)) | jm;
      rb[r*L + (d ^ sw)]        = a_re + t_re;
      ib[r*L + (d ^ sw)]        = a_im + t_im;
      rb[r*L + ((d + Ns) ^ sw)] = a_re - t_re;
      ib[r*L + ((d + Ns) ^ sw)] = a_im - t_im;
    }
    float* t;
    t = ra; ra = rb; rb = t;
    t = ia; ia = ib; ib = t;
  }
  __syncthreads();
}

// F1: z = a + i*b (two real signals, zero-padded), FFT_512 over n2,
// twiddle, write transposed Bt[k2*256 + n1].
__global__ __launch_bounds__(256) void fwd512_pack_kernel(
    const float* __restrict__ srcA, int lenA, int strideA,
    const float* __restrict__ srcB, int lenB, int strideB,
    float2* __restrict__ Bt)
{
  __shared__ float reA[4096], imA[4096], reB[4096], imB[4096];
  const int e = blockIdx.y, t1 = blockIdx.x*8, tid = threadIdx.x;
  #pragma unroll
  for (int q = 0; q < 4; q++){
    int flat = tid + 256*q;
    int n2 = flat >> 1;
    int rb = (flat & 1)*4;
    int nb = t1 + rb + 256*n2;
    float4 va = make_float4(0.f,0.f,0.f,0.f);
    float4 vb = make_float4(0.f,0.f,0.f,0.f);
    if (nb < lenA) va = *(const float4*)(srcA + (size_t)e*strideA + nb);
    if (nb < lenB) vb = *(const float4*)(srcB + (size_t)e*strideB + nb);
    #pragma unroll
    for (int j = 0; j < 4; j++){
      int r = rb + j;
      int sw = (r & 7) << 2;
      reA[r*512 + (n2 ^ sw)] = (&va.x)[j];
      imA[r*512 + (n2 ^ sw)] = (&vb.x)[j];
    }
  }
  float *ra = reA, *ia = imA, *rb2 = reB, *ib2 = imB;
  fft_core<512, 9, +1>(ra, ia, rb2, ib2);
  float2* dst = Bt + ((size_t)e << 17);
  #pragma unroll
  for (int q = 0; q < 16; q++){
    int idx = tid + 256*q;
    int r = idx & 7, k2 = idx >> 3;
    int n1 = t1 + r;
    int sw = (r & 7) << 2;
    float xr = ra[r*512 + (k2 ^ sw)];
    float xi = ia[r*512 + (k2 ^ sw)];
    float2 w = twid((float)(n1*k2) * (1.0f/131072.0f));
    dst[k2*256 + n1] = make_float2(xr*w.x - xi*w.y, xr*w.y + xi*w.x);
  }
}

// F1-rooms: z = rooms[2e] + i*rooms[2e+1] computed inline from verbs/rho.
__global__ __launch_bounds__(256) void fwd512_pack_rooms_kernel(
    const float* __restrict__ verbs, const float* __restrict__ rho,
    float2* __restrict__ Bt)
{
  __shared__ float reA[4096], imA[4096], reB[4096], imB[4096];
  __shared__ float srho[32];
  const int e = blockIdx.y, t1 = blockIdx.x*8, tid = threadIdx.x;
  if (tid < 32) srho[tid] = rho[(2*e)*16 + tid];
  __syncthreads();
  #pragma unroll
  for (int q = 0; q < 4; q++){
    int flat = tid + 256*q;
    int n2 = flat >> 1;
    int rb = (flat & 1)*4;
    int nb = t1 + rb + 256*n2;
    float4 va = make_float4(0.f,0.f,0.f,0.f);
    float4 vb = make_float4(0.f,0.f,0.f,0.f);
    if (nb < NS){
      #pragma unroll
      for (int v = 0; v < 16; v++){
        float4 w4 = *(const float4*)(verbs + (size_t)v*NS + nb);
        float r0 = srho[v], r1 = srho[16 + v];
        va.x += r0*w4.x; va.y += r0*w4.y; va.z += r0*w4.z; va.w += r0*w4.w;
        vb.x += r1*w4.x; vb.y += r1*w4.y; vb.z += r1*w4.z; vb.w += r1*w4.w;
      }
    }
    #pragma unroll
    for (int j = 0; j < 4; j++){
      int r = rb + j;
      int sw = (r & 7) << 2;
      reA[r*512 + (n2 ^ sw)] = (&va.x)[j];
      imA[r*512 + (n2 ^ sw)] = (&vb.x)[j];
    }
  }
  float *ra = reA, *ia = imA, *rb2 = reB, *ib2 = imB;
  fft_core<512, 9, +1>(ra, ia, rb2, ib2);
  float2* dst = Bt + ((size_t)e << 17);
  #pragma unroll
  for (int q = 0; q < 16; q++){
    int idx = tid + 256*q;
    int r = idx & 7, k2 = idx >> 3;
    int n1 = t1 + r;
    int sw = (r & 7) << 2;
    float xr = ra[r*512 + (k2 ^ sw)];
    float xi = ia[r*512 + (k2 ^ sw)];
    float2 w = twid((float)(n1*k2) * (1.0f/131072.0f));
    dst[k2*256 + n1] = make_float2(xr*w.x - xi*w.y, xr*w.y + xi*w.x);
  }
}

// F2: in-place FFT_256 along contiguous rows (row = k2).
__global__ __launch_bounds__(256) void fwd256_kernel(float2* __restrict__ S)
{
  __shared__ float reA[4096], imA[4096], reB[4096], imB[4096];
  const int e = blockIdx.y, K0 = blockIdx.x*16, tid = threadIdx.x;
  float2* base = S + ((size_t)e << 17) + (size_t)K0*256;
  #pragma unroll
  for (int q = 0; q < 16; q++){
    int idx = tid + 256*q;
    int r = idx >> 8, col = idx & 255;
    float2 v = base[r*256 + col];
    int sw = (r & 7) << 2;
    reA[r*256 + (col ^ sw)] = v.x;
    imA[r*256 + (col ^ sw)] = v.y;
  }
  float *ra = reA, *ia = imA, *rb = reB, *ib = imB;
  fft_core<256, 8, +1>(ra, ia, rb, ib);
  #pragma unroll
  for (int q = 0; q < 16; q++){
    int idx = tid + 256*q;
    int r = idx >> 8, col = idx & 255;
    int sw = (r & 7) << 2;
    base[r*256 + col] = make_float2(ra[r*256 + (col ^ sw)], ia[r*256 + (col ^ sw)]);
  }
}

// I1: Hermitian-unpack TWO packed spectra, per-event product, repack
// Y = P0 + i*P1, inverse FFT_256, conj twiddle, write Ut[n1*512 + k2].
__global__ __launch_bounds__(256) void inv256_mul2_kernel(
    const float2* __restrict__ ZA, const float2* __restrict__ ZB,
    float2* __restrict__ Ut)
{
  __shared__ float reA[4096], imA[4096], reB[4096], imB[4096];
  const int e = blockIdx.y, K0 = blockIdx.x*16, tid = threadIdx.x;
  const float2* Za = ZA + ((size_t)e << 17);
  const float2* Zb = ZB + ((size_t)e << 17);
  #pragma unroll
  for (int q = 0; q < 16; q++){
    int idx = tid + 256*q;
    int r = idx >> 8, col = idx & 255;
    int k2 = K0 + r;
    int k2p, k1p;
    if (k2 == 0){ k2p = 0; k1p = (256 - col) & 255; }
    else        { k2p = 512 - k2; k1p = 255 - col; }
    float2 za  = Za[(size_t)k2*256 + col];
    float2 zap = Za[(size_t)k2p*256 + k1p];
    float2 zb  = Zb[(size_t)k2*256 + col];
    float2 zbp = Zb[(size_t)k2p*256 + k1p];
    float a0r = 0.5f*(za.x + zap.x), a0i = 0.5f*(za.y - zap.y);
    float a1r = 0.5f*(za.y + zap.y), a1i = 0.5f*(zap.x - za.x);
    float b0r = 0.5f*(zb.x + zbp.x), b0i = 0.5f*(zb.y - zbp.y);
    float b1r = 0.5f*(zb.y + zbp.y), b1i = 0.5f*(zbp.x - zb.x);
    float p0r = a0r*b0r - a0i*b0i, p0i = a0r*b0i + a0i*b0r;
    float p1r = a1r*b1r - a1i*b1i, p1i = a1r*b1i + a1i*b1r;
    int sw = (r & 7) << 2;
    reA[r*256 + (col ^ sw)] = p0r - p1i;
    imA[r*256 + (col ^ sw)] = p0i + p1r;
  }
  float *ra = reA, *ia = imA, *rb = reB, *ib = imB;
  fft_core<256, 8, -1>(ra, ia, rb, ib);
  float2* dst = Ut + ((size_t)e << 17);
  #pragma unroll
  for (int q = 0; q < 16; q++){
    int idx = tid + 256*q;
    int r = idx & 15, n1 = idx >> 4;
    int k2 = K0 + r;
    int sw = (r & 7) << 2;
    float xr = ra[r*256 + (n1 ^ sw)];
    float xi = ia[r*256 + (n1 ^ sw)];
    float2 w = twid((float)(n1*k2) * (1.0f/131072.0f));
    dst[n1*512 + k2] = make_float2(xr*w.x + xi*w.y, xi*w.x - xr*w.y);
  }
}

// I2+F1 fused: inverse FFT_512 -> packed conv pair; write CONV;
// truncate (n2>=256 -> 0) and forward FFT_512 + twiddle -> Bt.
__global__ __launch_bounds__(256) void inv512_fwdpack2_kernel(
    const float2* __restrict__ Ut, float* __restrict__ conv,
    float2* __restrict__ Bt)
{
  __shared__ float reA[4096], imA[4096], reB[4096], imB[4096];
  const int e = blockIdx.y, t1 = blockIdx.x*8, tid = threadIdx.x;
  const float2* base = Ut + ((size_t)e << 17) + (size_t)t1*512;
  #pragma unroll
  for (int q = 0; q < 16; q++){
    int idx = tid + 256*q;
    int r = idx >> 9, col = idx & 511;
    float2 v = base[r*512 + col];
    int sw = (r & 7) << 2;
    reA[r*512 + (col ^ sw)] = v.x;
    imA[r*512 + (col ^ sw)] = v.y;
  }
  float *ra = reA, *ia = imA, *rb = reB, *ib = imB;
  fft_core<512, 9, -1>(ra, ia, rb, ib);
  const float s = 1.0f/131072.0f;
  #pragma unroll
  for (int q = 0; q < 16; q++){
    int idx = tid + 256*q;
    int r = idx & 7, n2 = idx >> 3;
    int sw = (r & 7) << 2;
    int pos = r*512 + (n2 ^ sw);
    if (n2 < 256){
      int n = (t1 + r) + 256*n2;
      float y0 = ra[pos]*s, y1 = ia[pos]*s;
      conv[(size_t)(2*e)*NS + n]     = y0;
      conv[(size_t)(2*e + 1)*NS + n] = y1;
      rb[pos] = y0; ib[pos] = y1;
    } else {
      rb[pos] = 0.f; ib[pos] = 0.f;
    }
  }
  __syncthreads();
  float *r2 = rb, *i2 = ib, *r3 = ra, *i3 = ia;
  fft_core<512, 9, +1>(r2, i2, r3, i3);
  float2* dst = Bt + ((size_t)e << 17);
  #pragma unroll
  for (int q = 0; q < 16; q++){
    int idx = tid + 256*q;
    int r = idx & 7, k2 = idx >> 3;
    int n1 = t1 + r;
    int sw = (r & 7) << 2;
    float xr = r2[r*512 + (k2 ^ sw)];
    float xi = i2[r*512 + (k2 ^ sw)];
    float2 w = twid((float)(n1*k2) * (1.0f/131072.0f));
    dst[k2*256 + n1] = make_float2(xr*w.x - xi*w.y, xr*w.y + xi*w.x);
  }
}

// I2-final: inverse FFT_512 -> packed wet pair; mix with conv, write out.
__global__ __launch_bounds__(256) void inv512_mix2_kernel(
    const float2* __restrict__ Ut, const float* __restrict__ conv,
    const float* __restrict__ scal, float* __restrict__ dst)
{
  __shared__ float reA[4096], imA[4096], reB[4096], imB[4096];
  const int e = blockIdx.y, t1 = blockIdx.x*8, tid = threadIdx.x;
  const float2* base = Ut + ((size_t)e << 17) + (size_t)t1*512;
  #pragma unroll
  for (int q = 0; q < 16; q++){
    int idx = tid + 256*q;
    int r = idx >> 9, col = idx & 511;
    float2 v = base[r*512 + col];
    int sw = (r & 7) << 2;
    reA[r*512 + (col ^ sw)] = v.x;
    imA[r*512 + (col ^ sw)] = v.y;
  }
  float *ra = reA, *ia = imA, *rb = reB, *ib = imB;
  fft_core<512, 9, -1>(ra, ia, rb, ib);
  const float s = 1.0f/131072.0f;
  const int e0 = 2*e, e1 = 2*e + 1;
  float m00 = scal[e0*4 + 0], m10 = scal[e0*4 + 1], a20 = scal[e0*4 + 2];
  float m01 = scal[e1*4 + 0], m11 = scal[e1*4 + 1], a21 = scal[e1*4 + 2];
  #pragma unroll
  for (int q = 0; q < 8; q++){
    int idx = tid + 256*q;
    int r = idx & 7, n2 = idx >> 3;
    int n = (t1 + r) + 256*n2;
    int sw = (r & 7) << 2;
    int pos = r*512 + (n2 ^ sw);
    float w0 = ra[pos]*s, w1 = ia[pos]*s;
    size_t g0 = (size_t)e0*NS + n, g1 = (size_t)e1*NS + n;
    dst[g0] = (m00*conv[g0] + m10*w0)*a20;
    dst[g1] = (m01*conv[g1] + m11*w1)*a21;
  }
}

// ---------------- fallback: direct causal conv ----------------
template<int MODE>
__global__ __launch_bounds__(256) void tconv_kernel(
    const float* __restrict__ sig, int sig_len, int sig_stride,
    const float* __restrict__ go, const float* __restrict__ scal,
    float* __restrict__ dst)
{
  __shared__ __align__(16) float cs[2048];
  __shared__ __align__(16) float rs[4104];
  const int e = blockIdx.y;
  const int t0 = blockIdx.x * 2048;
  const int tid = threadIdx.x;
  const int tb = tid * 8;
  float acc[8] = {0,0,0,0,0,0,0,0};
  const int kcap = imin(sig_len, t0 + 2048);
  for (int c0 = 0; c0 < kcap; c0 += 2048){
    __syncthreads();
    for (int idx = tid; idx < 2048; idx += 256){
      int gsi = c0 + idx;
      cs[idx] = (gsi < sig_len) ? sig[(size_t)e*sig_stride + gsi] : 0.f;
    }
    const int rb = t0 - c0 - 2056;
    for (int idx = tid; idx < 4104; idx += 256){
      int g = rb + idx;
      rs[idx] = (g >= 0 && g < NS) ? go[(size_t)e*NS + g] : 0.f;
    }
    __syncthreads();
    float W[12];
    int P = tb + 2056;
    *(float4*)&W[0] = *(const float4*)&rs[P - 4];
    *(float4*)&W[4] = *(const float4*)&rs[P];
    *(float4*)&W[8] = *(const float4*)&rs[P + 4];
    for (int u = 0; u < 512; u++){
      float4 f4 = *(const float4*)&cs[4*u];
      #pragma unroll
      for (int j = 0; j < 8; j++){
        acc[j] += f4.x*W[4 + j];
        acc[j] += f4.y*W[3 + j];
        acc[j] += f4.z*W[2 + j];
        acc[j] += f4.w*W[1 + j];
      }
      #pragma unroll
      for (int x2 = 11; x2 >= 4; x2--) W[x2] = W[x2 - 4];
      P -= 4;
      *(float4*)&W[0] = *(const float4*)&rs[P - 4];
    }
  }
  if (MODE == 0){
    #pragma unroll
    for (int j = 0; j < 8; j++) dst[(size_t)e*NS + t0 + tb + j] = acc[j];
  } else {
    float m0 = scal[e*4 + 0], m1 = scal[e*4 + 1], a2 = scal[e*4 + 2];
    #pragma unroll
    for (int j = 0; j < 8; j++){
      size_t gi = (size_t)e*NS + t0 + tb + j;
      dst[gi] = (m0*sig[gi] + m1*acc[j]) * a2;
    }
  }
}

// ---------------- launcher ----------------
extern "C" void kernel_launch(void* const* d_in, const int* in_sizes, int n_in,
                              void* d_out, int out_size, void* d_ws, size_t ws_size,
                              hipStream_t stream)
{
  (void)in_sizes; (void)n_in; (void)out_size;
  const float* res_sel     = (const float*)d_in[0];
  const float* noise_sel   = (const float*)d_in[1];
  const float* env_sel     = (const float*)d_in[2];
  const float* dec_sel     = (const float*)d_in[3];
  const float* def_sel     = (const float*)d_in[4];
  const float* ndef_sel    = (const float*)d_in[5];
  const float* mix_sel     = (const float*)d_in[6];
  const float* room_sel    = (const float*)d_in[7];
  const float* amp         = (const float*)d_in[8];
  const float* r_items     = (const float*)d_in[9];
  const float* n_items     = (const float*)d_in[10];
  const float* e_items     = (const float*)d_in[11];
  const float* d_items     = (const float*)d_in[12];
  const float* warp_items  = (const float*)d_in[13];
  const float* nwarp_items = (const float*)d_in[14];
  const float* verbs       = (const float*)d_in[15];
  const float* waves       = (const float*)d_in[16];
  float* ws  = (float*)d_ws;
  float* out = (float*)d_out;

  const bool big_ws = ws_size >= (size_t)O_END * sizeof(float);

  if (big_ws) {
    weights_kernel<<<dim3(NEV), dim3(64), 0, stream>>>(
        noise_sel, env_sel, dec_sel, def_sel, ndef_sel, mix_sel, room_sel, amp,
        d_items, ws + O_SWE, ws + O_SWN, ws + O_SWD, ws + O_SWND,
        ws + O_DSM, ws + O_SCAL, ws + O_RHO);
    envs_kernel<<<dim3(NEV), dim3(128), 0, stream>>>(ws + O_SWE, e_items, ws + O_ENV_SMALL);
    nfil_kernel<<<dim3(128), dim3(256), 0, stream>>>(ws + O_SWN, n_items, ws + O_NFIL);
    warp_kernel<<<dim3(NEV), dim3(128), 0, stream>>>(ws + O_SWD, warp_items, ws + O_WSM);
    nwarp_kernel<<<dim3(NEV), dim3(128), 0, stream>>>(ws + O_SWND, nwarp_items, ws + O_ND);

    p1_softmax_kernel<<<dim3(256), dim3(256), 0, stream>>>(res_sel, ws + O_P1);
    p2_kernel<<<dim3(4, 32), dim3(256), 0, stream>>>(ws + O_P1, r_items, ws + O_P2);

    env_noise_kernel<<<dim3(1024), dim3(256), 0, stream>>>(ws + O_ENV_SMALL, ws + O_IMP);
    filt_kernel<<<dim3(34, NEV), dim3(256), 0, stream>>>(ws + O_NFIL, ws + O_IMP, ws + O_ND, ws + O_FILT);

    unsigned short* Ahi = (unsigned short*)(ws + O_X);
    split_a_kernel<<<dim3(256), dim3(256), 0, stream>>>(ws + O_P2, Ahi);
    gemm_dres_gen3_kernel<<<dim3(512), dim3(512), 0, stream>>>(
        Ahi, ws + O_WSM, ws + O_DSM, ws + O_DRES);

    // ---- event-pair-packed FFT convolution ----
    float2* Xf = (float2*)(ws + O_X);                 // filtered-pair spectra
    float2* Xd = (float2*)(ws + O_X + 4194304);       // dres-pair spectra
    float2* Xr = (float2*)(ws + O_Y);                 // rooms-pair spectra
    float2* Uc = (float2*)(ws + O_Y + 4194304);       // conv product, mid layout
    float2* Xc = Xf;                                  // conv-pair spectra (Xf dead)
    float2* Uw = Xd;                                  // wet product (Xd dead)

    fwd512_pack_kernel<<<dim3(32, 16), dim3(256), 0, stream>>>(
        ws + O_FILT, FLEN, 2*FLEN, ws + O_FILT + FLEN, FLEN, 2*FLEN, Xf);
    fwd256_kernel<<<dim3(32, 16), dim3(256), 0, stream>>>(Xf);
    fwd512_pack_kernel<<<dim3(32, 16), dim3(256), 0, stream>>>(
        ws + O_DRES, NS, 2*NS, ws + O_DRES + NS, NS, 2*NS, Xd);
    fwd256_kernel<<<dim3(32, 16), dim3(256), 0, stream>>>(Xd);
    fwd512_pack_rooms_kernel<<<dim3(32, 16), dim3(256), 0, stream>>>(
        verbs, ws + O_RHO, Xr);
    fwd256_kernel<<<dim3(32, 16), dim3(256), 0, stream>>>(Xr);

    inv256_mul2_kernel<<<dim3(32, 16), dim3(256), 0, stream>>>(Xf, Xd, Uc);
    inv512_fwdpack2_kernel<<<dim3(32, 16), dim3(256), 0, stream>>>(Uc, ws + O_CONV, Xc);
    fwd256_kernel<<<dim3(32, 16), dim3(256), 0, stream>>>(Xc);
    inv256_mul2_kernel<<<dim3(32, 16), dim3(256), 0, stream>>>(Xc, Xr, Uw);
    inv512_mix2_kernel<<<dim3(32, 16), dim3(256), 0, stream>>>(
        Uw, ws + O_CONV, ws + O_SCAL, out);
  } else {
    // fallback: legacy prep + f32 GEMM + direct time-domain conv
    prep_kernel<<<dim3(NEV), dim3(64), 0, stream>>>(
        noise_sel, env_sel, dec_sel, def_sel, ndef_sel, mix_sel, room_sel, amp,
        n_items, e_items, d_items, warp_items, nwarp_items,
        ws + O_ENV_SMALL, ws + O_NFIL, ws + O_ND, ws + O_WSM,
        ws + O_DSM, ws + O_SCAL, ws + O_RHO);
    p1_softmax_kernel<<<dim3(256), dim3(256), 0, stream>>>(res_sel, ws + O_P1);
    p2_kernel<<<dim3(4, 32), dim3(256), 0, stream>>>(ws + O_P1, r_items, ws + O_P2);
    env_noise_kernel<<<dim3(1024), dim3(256), 0, stream>>>(ws + O_ENV_SMALL, ws + O_IMP);
    filt_kernel<<<dim3(34, NEV), dim3(256), 0, stream>>>(ws + O_NFIL, ws + O_IMP, ws + O_ND, ws + O_FILT);
    rooms_kernel<<<dim3(256, NEV), dim3(256), 0, stream>>>(verbs, ws + O_RHO, ws + O_ROOMS);
    gemm_dres_kernel<<<dim3(1024), dim3(256), 0, stream>>>(
        ws + O_P2, waves, ws + O_WSM, ws + O_DSM, ws + O_DRES);
    tconv_kernel<0><<<dim3(32, NEV), dim3(256), 0, stream>>>(
        ws + O_FILT, FLEN, FLEN, ws + O_DRES, (const float*)nullptr, ws + O_CONV);
    tconv_kernel<1><<<dim3(32, NEV), dim3(256), 0, stream>>>(
        ws + O_CONV, NS, NS, ws + O_ROOMS, ws + O_SCAL, out);
  }
}

// Round 9
// 388.195 us; speedup vs baseline: 1.4552x; 1.0650x over previous
//
#include <hip/hip_runtime.h>
#include <math.h>

// ---------------- problem sizes ----------------
#define NEV    32      // n_events
#define NS     65536   // n_samples
#define NFFT   131072  // 2*NS
#define ENVS   128
#define ENVF   8192
#define FSAMP2 512
#define NEXP2  4
#define FLEN   8704    // filtered support (8192 + 512 - 1 -> padded to 8704)
#define GD     5622750u   // 22050*255 (phase denominator)
#define GDH    2811375u   // GD/2

// ---------------- workspace layout (float offsets) ----------------
enum : size_t {
  O_ENV_SMALL = 0,         // 32*128
  O_NFIL      = 4096,      // 32*4*512
  O_IMP       = 69632,     // 32*8192
  O_ND        = 331776,    // 32*4*128
  O_WSM       = 348160,    // 32*8*128
  O_DSM       = 380928,    // 32*128
  O_SCAL      = 385024,    // 32*4  (m0, m1, amp^2)
  O_RHO       = 385152,    // 32*16
  O_P1        = 385664,    // 256*1024
  O_P2        = 647808,    // 256*1024
  O_FILT      = 909952,    // 32*8704
  O_DRES      = 1188480,   // 32*65536
  O_CONV      = 3285632,   // 32*65536
  O_ROOMS     = 5382784,   // 32*65536 (fallback path only)
  O_SWE       = 7479936,   // 32*64
  O_SWN       = 7482048,   // 32*4*64
  O_SWD       = 7490304,   // 32*64
  O_SWND      = 7492416,   // 32*32
  O_X         = 7742080,   // 8,388,608 floats: Xf | Xd  (16 pair-slices each)
  O_Y         = 16130688,  // 8,388,608 floats: Xr | Uc
  O_END       = 24519296,  // *4 bytes = 98,077,184
};

typedef float f32x4 __attribute__((ext_vector_type(4)));
typedef short bf16x8 __attribute__((ext_vector_type(8)));

union U8 { uint4 q; bf16x8 v; unsigned short u[8]; };

__device__ __forceinline__ int imin(int a, int b){ return a < b ? a : b; }

__device__ __forceinline__ float wsum(float v){
  #pragma unroll
  for (int o = 32; o > 0; o >>= 1) v += __shfl_xor(v, o);
  return v;
}
__device__ __forceinline__ float wmax(float v){
  #pragma unroll
  for (int o = 32; o > 0; o >>= 1) v = fmaxf(v, __shfl_xor(v, o));
  return v;
}

__device__ __forceinline__ unsigned short f2bf(float f){
  unsigned u = __float_as_uint(f);
  unsigned r = (u + 0x7fffu + ((u >> 16) & 1u)) >> 16;
  return (unsigned short)r;
}

// e^{-2*pi*i*frac} via HW trig (input in revolutions)
__device__ __forceinline__ float2 twid(float frac){
  float c, s;
  asm("v_cos_f32 %0, %1" : "=v"(c) : "v"(frac));
  asm("v_sin_f32 %0, %1" : "=v"(s) : "v"(frac));
  return make_float2(c, -s);
}

// ---------------- JAX threefry2x32, partitionable 32-bit path ----------------
__device__ __forceinline__ unsigned tf_rotl(unsigned x, int d){ return (x << d) | (x >> (32 - d)); }

__device__ unsigned threefry_bits(unsigned chi, unsigned clo){
  const unsigned k0 = 0u, k1 = 42u, k2 = 0x1BD11BDAu ^ 0u ^ 42u;
  unsigned x0 = chi + k0;
  unsigned x1 = clo + k1;
  x0 += x1; x1 = tf_rotl(x1,13); x1 ^= x0;
  x0 += x1; x1 = tf_rotl(x1,15); x1 ^= x0;
  x0 += x1; x1 = tf_rotl(x1,26); x1 ^= x0;
  x0 += x1; x1 = tf_rotl(x1, 6); x1 ^= x0;
  x0 += k1; x1 += k2 + 1u;
  x0 += x1; x1 = tf_rotl(x1,17); x1 ^= x0;
  x0 += x1; x1 = tf_rotl(x1,29); x1 ^= x0;
  x0 += x1; x1 = tf_rotl(x1,16); x1 ^= x0;
  x0 += x1; x1 = tf_rotl(x1,24); x1 ^= x0;
  x0 += k2; x1 += k0 + 2u;
  x0 += x1; x1 = tf_rotl(x1,13); x1 ^= x0;
  x0 += x1; x1 = tf_rotl(x1,15); x1 ^= x0;
  x0 += x1; x1 = tf_rotl(x1,26); x1 ^= x0;
  x0 += x1; x1 = tf_rotl(x1, 6); x1 ^= x0;
  x0 += k0; x1 += k1 + 3u;
  x0 += x1; x1 = tf_rotl(x1,17); x1 ^= x0;
  x0 += x1; x1 = tf_rotl(x1,29); x1 ^= x0;
  x0 += x1; x1 = tf_rotl(x1,16); x1 ^= x0;
  x0 += x1; x1 = tf_rotl(x1,24); x1 ^= x0;
  x0 += k1; x1 += k2 + 4u;
  x0 += x1; x1 = tf_rotl(x1,13); x1 ^= x0;
  x0 += x1; x1 = tf_rotl(x1,15); x1 ^= x0;
  x0 += x1; x1 = tf_rotl(x1,26); x1 ^= x0;
  x0 += x1; x1 = tf_rotl(x1, 6); x1 ^= x0;
  x0 += k2; x1 += k0 + 5u;
  return x0 ^ x1;
}

// ---------------- weights: softmaxes + decay/mix/room ----------------
__global__ __launch_bounds__(64) void weights_kernel(
    const float* __restrict__ noise_sel, const float* __restrict__ env_sel,
    const float* __restrict__ dec_sel,   const float* __restrict__ def_sel,
    const float* __restrict__ ndef_sel,  const float* __restrict__ mix_sel,
    const float* __restrict__ room_sel,  const float* __restrict__ amp,
    const float* __restrict__ d_items,
    float* __restrict__ swE, float* __restrict__ swN,
    float* __restrict__ swD, float* __restrict__ swND,
    float* __restrict__ d_small, float* __restrict__ scal,
    float* __restrict__ rho)
{
  const int e = blockIdx.x;
  const int l = threadIdx.x;

  {
    float x = env_sel[e*64 + l];
    float mx = wmax(x);
    float ex = expf(x - mx);
    float sm = wsum(ex);
    swE[e*64 + l] = ex / sm;
  }
  #pragma unroll
  for (int x4 = 0; x4 < NEXP2; x4++){
    float v = noise_sel[(e*NEXP2 + x4)*64 + l];
    float mxv = wmax(v);
    float exv = expf(v - mxv);
    float smv = wsum(exv);
    swN[(e*NEXP2 + x4)*64 + l] = exv / smv;
  }
  {
    float x = def_sel[e*64 + l];
    float mx = wmax(x);
    float ex = expf(x - mx);
    float sm = wsum(ex);
    swD[e*64 + l] = ex / sm;
  }
  {
    float x = (l < 32) ? ndef_sel[e*32 + l] : -1e30f;
    float mx = wmax(x);
    float ex = (l < 32) ? expf(x - mx) : 0.f;
    float sm = wsum(ex);
    if (l < 32) swND[e*32 + l] = ex / sm;
  }
  {
    float x = dec_sel[e*64 + l];
    float mx = wmax(x);
    float ex = expf(x - mx);
    float sm = wsum(ex);
    float wgt = ex / sm;
    float di = d_items[l];
    float dp = 0.5f + 0.5f*(1.0f/(1.0f + expf(-di)));
    float d0 = wsum(wgt*dp);
    float ld = logf(d0 + 1e-12f);
    #pragma unroll
    for (int c = 0; c < 2; c++){
      int f = l + 64*c;
      d_small[e*128 + f] = expf((float)(f+1)*ld);
    }
  }
  if (l == 0){
    float a = mix_sel[e*2 + 0], b = mix_sel[e*2 + 1];
    float mm = fmaxf(a, b);
    float ea = expf(a - mm), eb = expf(b - mm);
    float ss = ea + eb;
    scal[e*4 + 0] = ea/ss;
    scal[e*4 + 1] = eb/ss;
    float am = amp[e];
    scal[e*4 + 2] = am*am;
  }
  {
    float x = (l < 16) ? room_sel[e*16 + l] : -1e30f;
    float mx = wmax(x);
    float ex = (l < 16) ? expf(x - mx) : 0.f;
    float sm = wsum(ex);
    if (l < 16) rho[e*16 + l] = ex/sm;
  }
}

// ---------------- output-parallel small lookups ----------------
__global__ __launch_bounds__(128) void envs_kernel(
    const float* __restrict__ swE, const float* __restrict__ e_items,
    float* __restrict__ env_small)
{
  const int e = blockIdx.x, j = threadIdx.x;
  __shared__ float sw[64];
  if (j < 64) sw[j] = swE[e*64 + j];
  __syncthreads();
  float acc = 0.f;
  #pragma unroll 8
  for (int k = 0; k < 64; k++){ float it = e_items[k*ENVS + j]; acc += sw[k]*(it*it); }
  env_small[e*ENVS + j] = acc;
}

__global__ __launch_bounds__(256) void nfil_kernel(
    const float* __restrict__ swN, const float* __restrict__ n_items,
    float* __restrict__ nfil)
{
  const int b = blockIdx.x;
  const int tid = threadIdx.x;
  __shared__ float sw[64];
  if (tid < 64) sw[tid] = swN[b*64 + tid];
  __syncthreads();
  #pragma unroll
  for (int c = 0; c < 2; c++){
    int tau = tid + 256*c;
    float acc = 0.f;
    #pragma unroll 8
    for (int f = 0; f < 64; f++) acc += sw[f]*n_items[f*FSAMP2 + tau];
    float ham = 0.54f - 0.46f*cosf((6.2831853071795864769f * (float)tau) / 511.0f);
    nfil[b*FSAMP2 + tau] = acc*ham;
  }
}

__global__ __launch_bounds__(128) void warp_kernel(
    const float* __restrict__ swD, const float* __restrict__ warp_items,
    float* __restrict__ w_small)
{
  const int e = blockIdx.x, f = threadIdx.x;
  __shared__ float sw[64];
  if (f < 64) sw[f] = swD[e*64 + f];
  __syncthreads();
  float acc[8] = {0,0,0,0,0,0,0,0};
  for (int k = 0; k < 64; k++){
    float wk = sw[k];
    const float* row = warp_items + (size_t)k*1024 + f;
    #pragma unroll
    for (int i = 0; i < 8; i++) acc[i] += wk*row[i*128];
  }
  float mx = -1e30f;
  #pragma unroll
  for (int i = 0; i < 8; i++) mx = fmaxf(mx, acc[i]);
  float ev[8]; float s = 0.f;
  #pragma unroll
  for (int i = 0; i < 8; i++){ ev[i] = expf(acc[i] - mx); s += ev[i]; }
  #pragma unroll
  for (int i = 0; i < 8; i++) w_small[(e*8 + i)*128 + f] = ev[i]/s;
}

__global__ __launch_bounds__(128) void nwarp_kernel(
    const float* __restrict__ swND, const float* __restrict__ nwarp_items,
    float* __restrict__ nd_small)
{
  const int e = blockIdx.x, f = threadIdx.x;
  __shared__ float sw[32];
  if (f < 32) sw[f] = swND[e*32 + f];
  __syncthreads();
  float acc[4] = {0,0,0,0};
  for (int k = 0; k < 32; k++){
    float wk = sw[k];
    const float* row = nwarp_items + (size_t)k*512 + f;
    #pragma unroll
    for (int x = 0; x < 4; x++) acc[x] += wk*row[x*128];
  }
  float mx = -1e30f;
  #pragma unroll
  for (int x = 0; x < 4; x++) mx = fmaxf(mx, acc[x]);
  float ev[4]; float s = 0.f;
  #pragma unroll
  for (int x = 0; x < 4; x++){ ev[x] = expf(acc[x] - mx); s += ev[x]; }
  #pragma unroll
  for (int x = 0; x < 4; x++) nd_small[(e*4 + x)*128 + f] = ev[x]/s;
}

// ---------------- legacy prep (fallback path only) ----------------
__global__ __launch_bounds__(64) void prep_kernel(
    const float* __restrict__ noise_sel, const float* __restrict__ env_sel,
    const float* __restrict__ dec_sel,   const float* __restrict__ def_sel,
    const float* __restrict__ ndef_sel,  const float* __restrict__ mix_sel,
    const float* __restrict__ room_sel,  const float* __restrict__ amp,
    const float* __restrict__ n_items,   const float* __restrict__ e_items,
    const float* __restrict__ d_items,   const float* __restrict__ warp_items,
    const float* __restrict__ nwarp_items,
    float* __restrict__ env_small, float* __restrict__ nfil,
    float* __restrict__ nd_small,  float* __restrict__ w_small,
    float* __restrict__ d_small,   float* __restrict__ scal,
    float* __restrict__ rho)
{
  const int e = blockIdx.x;
  const int l = threadIdx.x;
  __shared__ float sw[64];
  __shared__ float buf[1024];

  {
    float x = env_sel[e*64 + l];
    float mx = wmax(x);
    float ex = expf(x - mx);
    float sm = wsum(ex);
    sw[l] = ex / sm;
  }
  __syncthreads();
  #pragma unroll
  for (int c = 0; c < 2; c++){
    int j = l + 64*c;
    float acc = 0.f;
    for (int k = 0; k < 64; k++){ float it = e_items[k*ENVS + j]; acc += sw[k]*(it*it); }
    env_small[e*ENVS + j] = acc;
  }
  __syncthreads();

  for (int x = 0; x < NEXP2; x++){
    float v = noise_sel[(e*NEXP2 + x)*64 + l];
    float mxv = wmax(v);
    float exv = expf(v - mxv);
    float smv = wsum(exv);
    sw[l] = exv / smv;
    __syncthreads();
    for (int c = 0; c < 8; c++){
      int tau = l + 64*c;
      float acc = 0.f;
      for (int f = 0; f < 64; f++) acc += sw[f]*n_items[f*FSAMP2 + tau];
      float ham = 0.54f - 0.46f*cosf((6.2831853071795864769f * (float)tau) / 511.0f);
      nfil[(e*NEXP2 + x)*FSAMP2 + tau] = acc*ham;
    }
    __syncthreads();
  }

  {
    float x = def_sel[e*64 + l];
    float mx = wmax(x);
    float ex = expf(x - mx);
    float sm = wsum(ex);
    sw[l] = ex / sm;
  }
  __syncthreads();
  for (int c = 0; c < 16; c++){
    int idx = l + 64*c;
    float acc = 0.f;
    for (int k = 0; k < 64; k++) acc += sw[k]*warp_items[k*1024 + idx];
    buf[idx] = acc;
  }
  __syncthreads();
  #pragma unroll
  for (int c = 0; c < 2; c++){
    int f = l + 64*c;
    float mx = -1e30f;
    for (int i = 0; i < 8; i++) mx = fmaxf(mx, buf[i*128 + f]);
    float ev[8]; float s = 0.f;
    for (int i = 0; i < 8; i++){ ev[i] = expf(buf[i*128 + f] - mx); s += ev[i]; }
    for (int i = 0; i < 8; i++) w_small[(e*8 + i)*128 + f] = ev[i]/s;
  }
  __syncthreads();

  {
    float x = (l < 32) ? ndef_sel[e*32 + l] : -1e30f;
    float mx = wmax(x);
    float ex = (l < 32) ? expf(x - mx) : 0.f;
    float sm = wsum(ex);
    sw[l] = (l < 32) ? ex/sm : 0.f;
  }
  __syncthreads();
  for (int c = 0; c < 8; c++){
    int idx = l + 64*c;
    float acc = 0.f;
    for (int k = 0; k < 32; k++) acc += sw[k]*nwarp_items[k*512 + idx];
    buf[idx] = acc;
  }
  __syncthreads();
  #pragma unroll
  for (int c = 0; c < 2; c++){
    int j = l + 64*c;
    float mx = -1e30f;
    for (int x = 0; x < 4; x++) mx = fmaxf(mx, buf[x*128 + j]);
    float ev[4]; float s = 0.f;
    for (int x = 0; x < 4; x++){ ev[x] = expf(buf[x*128 + j] - mx); s += ev[x]; }
    for (int x = 0; x < 4; x++) nd_small[(e*4 + x)*128 + j] = ev[x]/s;
  }
  __syncthreads();

  {
    float x = dec_sel[e*64 + l];
    float mx = wmax(x);
    float ex = expf(x - mx);
    float sm = wsum(ex);
    float wgt = ex / sm;
    float di = d_items[l];
    float dp = 0.5f + 0.5f*(1.0f/(1.0f + expf(-di)));
    float d0 = wsum(wgt*dp);
    float ld = logf(d0 + 1e-12f);
    #pragma unroll
    for (int c = 0; c < 2; c++){
      int f = l + 64*c;
      d_small[e*128 + f] = expf((float)(f+1)*ld);
    }
  }
  if (l == 0){
    float a = mix_sel[e*2 + 0], b = mix_sel[e*2 + 1];
    float mm = fmaxf(a, b);
    float ea = expf(a - mm), eb = expf(b - mm);
    float ss = ea + eb;
    scal[e*4 + 0] = ea/ss;
    scal[e*4 + 1] = eb/ss;
    float am = amp[e];
    scal[e*4 + 2] = am*am;
  }
  {
    float x = (l < 16) ? room_sel[e*16 + l] : -1e30f;
    float mx = wmax(x);
    float ex = (l < 16) ? expf(x - mx) : 0.f;
    float sm = wsum(ex);
    if (l < 16) rho[e*16 + l] = ex/sm;
  }
}

// ---------------- P1 = softmax(res_sel) ----------------
__global__ __launch_bounds__(256) void p1_softmax_kernel(
    const float* __restrict__ res_sel, float* __restrict__ P1)
{
  const int m = blockIdx.x;
  const int tid = threadIdx.x;
  __shared__ float red[4], red2[4];
  const float* row = res_sel + (size_t)m*1024;
  float4 v = ((const float4*)row)[tid];
  float mx = fmaxf(fmaxf(v.x, v.y), fmaxf(v.z, v.w));
  #pragma unroll
  for (int o = 32; o > 0; o >>= 1) mx = fmaxf(mx, __shfl_xor(mx, o));
  if ((tid & 63) == 0) red[tid >> 6] = mx;
  __syncthreads();
  mx = fmaxf(fmaxf(red[0], red[1]), fmaxf(red[2], red[3]));
  float e0 = expf(v.x - mx), e1 = expf(v.y - mx), e2 = expf(v.z - mx), e3 = expf(v.w - mx);
  float s = e0 + e1 + e2 + e3;
  #pragma unroll
  for (int o = 32; o > 0; o >>= 1) s += __shfl_xor(s, o);
  if ((tid & 63) == 0) red2[tid >> 6] = s;
  __syncthreads();
  s = red2[0] + red2[1] + red2[2] + red2[3];
  float inv = 1.0f/s;
  ((float4*)(P1 + (size_t)m*1024))[tid] = make_float4(e0*inv, e1*inv, e2*inv, e3*inv);
}

// ---------------- P2 = P1 @ r_items ----------------
__global__ __launch_bounds__(256) void p2_kernel(
    const float* __restrict__ P1, const float* __restrict__ r_items,
    float* __restrict__ P2)
{
  __shared__ __align__(16) float sp1[8][1024];
  const int bx = blockIdx.x;
  const int mg = blockIdx.y;
  const int tid = threadIdx.x;
  for (int idx = tid; idx < 2048; idx += 256)
    ((float4*)&sp1[0][0])[idx] = ((const float4*)(P1 + (size_t)mg*8*1024))[idx];
  __syncthreads();
  const int n = bx*256 + tid;
  float acc[8] = {0,0,0,0,0,0,0,0};
  for (int k = 0; k < 1024; k++){
    float wv = r_items[(size_t)k*1024 + n];
    #pragma unroll
    for (int r = 0; r < 8; r++) acc[r] += sp1[r][k]*wv;
  }
  #pragma unroll
  for (int r = 0; r < 8; r++) P2[(size_t)(mg*8 + r)*1024 + n] = acc[r];
}

// ---------------- split A = P2 into bf16 hi (fragment order) ----------------
__global__ __launch_bounds__(256) void split_a_kernel(
    const float* __restrict__ P2, unsigned short* __restrict__ Ahi)
{
  const int row = blockIdx.x;
  for (int k = threadIdx.x; k < 1024; k += 256){
    float f = P2[(size_t)row*1024 + k];
    Ahi[(size_t)(k >> 3)*2048 + row*8 + (k & 7)] = f2bf(f);
  }
}

// ---------------- impulses = interp(env_small,8192) * uniform_noise ----------------
__global__ __launch_bounds__(256) void env_noise_kernel(
    const float* __restrict__ env_small, float* __restrict__ impulses)
{
  const int flat = blockIdx.x*256 + threadIdx.x;
  const int e = flat >> 13, i = flat & 8191;
  unsigned bits = threefry_bits(0u, (unsigned)flat);
  float u01 = __uint_as_float((bits >> 9) | 0x3f800000u) - 1.0f;
  float nz  = fmaxf(-1.0f, u01*2.0f - 1.0f);
  float pos = (float)i * (127.0f/8191.0f);
  int lo = (int)floorf(pos);
  int hi = imin(lo + 1, 127);
  float w = pos - (float)lo;
  const float* es = env_small + e*ENVS;
  float v = es[lo]*(1.0f - w) + es[hi]*w;
  impulses[flat] = v*nz;
}

// ---------------- filtered: 512-tap FIR + nd combine ----------------
__global__ __launch_bounds__(256) void filt_kernel(
    const float* __restrict__ nfil, const float* __restrict__ impulses,
    const float* __restrict__ nd_small, float* __restrict__ filtered)
{
  __shared__ float nf[4*512];
  __shared__ float imp[768];
  const int e = blockIdx.y, t0 = blockIdx.x*256, tid = threadIdx.x;
  for (int idx = tid; idx < 2048; idx += 256) nf[idx] = nfil[e*2048 + idx];
  for (int idx = tid; idx < 768; idx += 256){
    int g = t0 - 512 + idx;
    imp[idx] = (g >= 0 && g < ENVF) ? impulses[e*ENVF + g] : 0.f;
  }
  __syncthreads();
  const int t = t0 + tid;
  float s0 = 0.f, s1 = 0.f, s2 = 0.f, s3 = 0.f;
  for (int tau = 0; tau < 512; tau++){
    float iv = imp[512 + tid - tau];
    s0 += nf[0*512 + tau]*iv;
    s1 += nf[1*512 + tau]*iv;
    s2 += nf[2*512 + tau]*iv;
    s3 += nf[3*512 + tau]*iv;
  }
  float pos = (float)t * (127.0f/65535.0f);
  int lo = (int)floorf(pos);
  int hi = imin(lo + 1, 127);
  float w = pos - (float)lo;
  const float* nds = nd_small + e*512;
  float acc = 0.f;
  acc += s0*(nds[0*128 + lo]*(1.0f - w) + nds[0*128 + hi]*w);
  acc += s1*(nds[1*128 + lo]*(1.0f - w) + nds[1*128 + hi]*w);
  acc += s2*(nds[2*128 + lo]*(1.0f - w) + nds[2*128 + hi]*w);
  acc += s3*(nds[3*128 + lo]*(1.0f - w) + nds[3*128 + hi]*w);
  filtered[e*FLEN + t] = acc;
}

// ---------------- rooms (fallback path only) ----------------
__global__ __launch_bounds__(256) void rooms_kernel(
    const float* __restrict__ verbs, const float* __restrict__ rho,
    float* __restrict__ rooms)
{
  const int t = blockIdx.x*256 + threadIdx.x;
  const int e = blockIdx.y;
  float acc = 0.f;
  #pragma unroll
  for (int v = 0; v < 16; v++) acc += rho[e*16 + v]*verbs[(size_t)v*NS + t];
  rooms[(size_t)e*NS + t] = acc;
}

// ---------------- rare-path waveform: exact f64 replication of numpy ----------------
__device__ __noinline__ float slow_wave(int wf, int n, int i){
  const double stp = 3980.0 / 255.0;
  double fi = (i == 255) ? 4000.0 : __dadd_rn(__dmul_rn((double)i, stp), 20.0);
  double tn = (double)n / 22050.0;
  double ph = __dmul_rn(fi, tn);
  double fr = ph - trunc(ph);
  if (wf == 1) return (float)(2.0*fr - 1.0);
  if (wf == 3){ double sw = 2.0*fr - 1.0; return (float)(2.0*fabs(sw) - 1.0); }
  if (fr == 0.0 || fr == 0.5){
    if (ph == 0.0) return 0.0f;
    double sv = sin(__dmul_rn(6.283185307179586, ph));
    return (sv > 0.0) ? 1.0f : ((sv < 0.0) ? -1.0f : 0.0f);
  }
  return (fr < 0.5) ? 1.0f : -1.0f;
}

// generate 8 wave values (rows i0..i0+7, column n) and split to bf16 hi/lo
__device__ __forceinline__ void gen8(int wf, int n, int i0,
                                     unsigned m_in, unsigned stepn,
                                     U8& bh, U8& bl)
{
  unsigned m = m_in;
  #pragma unroll
  for (int j = 0; j < 8; j++){
    float fr = (float)m * (1.0f/5622750.0f);
    float val;
    bool rare;
    if (wf == 0){
      asm("v_sin_f32 %0, %1" : "=v"(val) : "v"(fr));
      rare = false;
    } else if (wf == 1){
      val = fmaf(fr, 2.0f, -1.0f);
      rare = (m == 0u);
    } else if (wf == 2){
      val = (m < GDH) ? 1.0f : -1.0f;
      rare = (m == 0u) || (m == GDH);
    } else {
      val = fmaf(fabsf(fmaf(fr, 2.0f, -1.0f)), 2.0f, -1.0f);
      rare = (m == 0u);
    }
    if (rare) val = slow_wave(wf, n, i0 + j);
    unsigned ub = __float_as_uint(val);
    unsigned th = ub & 0xFFFF0000u;
    float lres = val - __uint_as_float(th);
    bh.u[j] = (unsigned short)(ub >> 16);
    bl.u[j] = (unsigned short)(__float_as_uint(lres) >> 16);
    m += stepn;
    if (m >= GD) m -= GD;
  }
}

// ---------------- MFMA GEMM v3: 512 thr / 8 waves, one 16-col tile per wave ----
__global__ __launch_bounds__(512, 2) void gemm_dres_gen3_kernel(
    const unsigned short* __restrict__ Ahi,
    const float* __restrict__ w_small, const float* __restrict__ d_small,
    float* __restrict__ dres)
{
  __shared__ __align__(16) unsigned short Abuf[2][8192];   // 2 x 16 KB

  const int tid = threadIdx.x;
  const int l = tid & 63, w = tid >> 6;   // 8 waves
  const int g = l >> 4, c = l & 15;
  const int n = blockIdx.x*128 + w*16 + c;

  f32x4 acc[16];
  #pragma unroll
  for (int m = 0; m < 16; m++) acc[m] = (f32x4){0.f,0.f,0.f,0.f};

  const unsigned stepn = (3980u*(unsigned)n) % GD;
  const unsigned s32 = (32u*stepn) % GD;
  const unsigned K0g = 3980u*(unsigned)(g*8) + 5100u;
  const unsigned m0 = (unsigned)(((unsigned long long)(unsigned)n * K0g) % GD);
  unsigned mseg = m0;

  typedef const __attribute__((address_space(1))) void GV;
  typedef __attribute__((address_space(3))) void LV;

  #pragma unroll
  for (int q = 0; q < 2; q++){
    const unsigned short* src = Ahi + (size_t)q*4096 + (size_t)w*512 + (size_t)l*8;
    __builtin_amdgcn_global_load_lds((GV*)src, (LV*)&Abuf[0][q*4096 + w*512], 16, 0, 0);
  }
  __syncthreads();

  for (int k0 = 0; k0 < 1024; k0 += 32){
    const int cur = (k0 >> 5) & 1, nxt = cur ^ 1;
    const int wf = k0 >> 8;
    if ((k0 & 255) == 0) mseg = m0;

    if (k0 + 32 < 1024){
      const size_t slice = (size_t)((k0 + 32) >> 5) * 8192;
      #pragma unroll
      for (int q = 0; q < 2; q++){
        const unsigned short* src = Ahi + slice + (size_t)q*4096 + (size_t)w*512 + (size_t)l*8;
        __builtin_amdgcn_global_load_lds((GV*)src, (LV*)&Abuf[nxt][q*4096 + w*512], 16, 0, 0);
      }
    }

    const int i0 = (k0 & 255) + g*8;
    U8 bh, bl;
    gen8(wf, n, i0, mseg, stepn, bh, bl);
    mseg += s32; if (mseg >= GD) mseg -= GD;

    #pragma unroll
    for (int m = 0; m < 16; m++){
      U8 ah;
      ah.q = *(const uint4*)&Abuf[cur][g*2048 + (m*16 + c)*8];
      acc[m] = __builtin_amdgcn_mfma_f32_16x16x32_bf16(ah.v, bh.v, acc[m], 0, 0, 0);
      acc[m] = __builtin_amdgcn_mfma_f32_16x16x32_bf16(ah.v, bl.v, acc[m], 0, 0, 0);
    }
    __syncthreads();
  }

  const int t = n;
  float pos = (float)t * (127.0f/65535.0f);
  int lo = (int)floorf(pos);
  int hi = imin(lo + 1, 127);
  float fr = pos - (float)lo;
  #pragma unroll
  for (int m = 0; m < 16; m++){
    int e = 2*m + (g >> 1);
    float s = 0.f;
    #pragma unroll
    for (int jj = 0; jj < 4; jj++){
      int i = (g & 1)*4 + jj;
      const float* wr = w_small + (size_t)(e*8 + i)*128;
      float wi = wr[lo]*(1.0f - fr) + wr[hi]*fr;
      s += wi * acc[m][jj];
    }
    s += __shfl_xor(s, 16);
    if ((g & 1) == 0){
      float de = d_small[e*128 + lo]*(1.0f - fr) + d_small[e*128 + hi]*fr;
      dres[(size_t)e*NS + t] = de * s;
    }
  }
}

// ---------------- fallback f32 GEMM ----------------
__global__ __launch_bounds__(256) void gemm_dres_kernel(
    const float* __restrict__ P2, const float* __restrict__ waves,
    const float* __restrict__ w_small, const float* __restrict__ d_small,
    float* __restrict__ dres)
{
  __shared__ __align__(16) float At[32][256];
  __shared__ __align__(16) float Bt[32][64];
  const int tid = threadIdx.x;
  const int tx = tid & 15, ty = tid >> 4;
  const int n0 = blockIdx.x * 64;
  float acc[16][4];
  #pragma unroll
  for (int a = 0; a < 16; a++)
    #pragma unroll
    for (int b = 0; b < 4; b++) acc[a][b] = 0.f;

  for (int k0 = 0; k0 < 1024; k0 += 32){
    {
      const float4* src = (const float4*)(P2 + (size_t)tid*1024 + k0);
      #pragma unroll
      for (int q = 0; q < 8; q++){
        float4 v = src[q];
        At[q*4 + 0][tid] = v.x; At[q*4 + 1][tid] = v.y;
        At[q*4 + 2][tid] = v.z; At[q*4 + 3][tid] = v.w;
      }
    }
    {
      int c  = tid & 15;
      int kr = tid >> 4;
      *(float4*)&Bt[kr][c*4]      = *((const float4*)(waves + (size_t)(k0 + kr)*NS + n0) + c);
      *(float4*)&Bt[kr + 16][c*4] = *((const float4*)(waves + (size_t)(k0 + kr + 16)*NS + n0) + c);
    }
    __syncthreads();
    #pragma unroll 4
    for (int k = 0; k < 32; k++){
      float a[16];
      *(float4*)&a[0]  = *(const float4*)&At[k][ty*16 + 0];
      *(float4*)&a[4]  = *(const float4*)&At[k][ty*16 + 4];
      *(float4*)&a[8]  = *(const float4*)&At[k][ty*16 + 8];
      *(float4*)&a[12] = *(const float4*)&At[k][ty*16 + 12];
      float4 b = *(const float4*)&Bt[k][tx*4];
      #pragma unroll
      for (int mi = 0; mi < 16; mi++){
        acc[mi][0] += a[mi]*b.x;
        acc[mi][1] += a[mi]*b.y;
        acc[mi][2] += a[mi]*b.z;
        acc[mi][3] += a[mi]*b.w;
      }
    }
    __syncthreads();
  }

  #pragma unroll
  for (int ni = 0; ni < 4; ni++){
    int t = n0 + tx*4 + ni;
    float pos = (float)t * (127.0f/65535.0f);
    int lo = (int)floorf(pos);
    int hi = imin(lo + 1, 127);
    float w = pos - (float)lo;
    #pragma unroll
    for (int ev2 = 0; ev2 < 2; ev2++){
      int e = ty*2 + ev2;
      float de = d_small[e*128 + lo]*(1.0f - w) + d_small[e*128 + hi]*w;
      float s = 0.f;
      #pragma unroll
      for (int i = 0; i < 8; i++){
        const float* wrow = w_small + (size_t)(e*8 + i)*128;
        float wi = wrow[lo]*(1.0f - w) + wrow[hi]*w;
        s += wi * acc[ev2*8 + i][ni];
      }
      dres[(size_t)e*NS + t] = de * s;
    }
  }
}

// ================= FFT machinery (four-step, N = 131072 = 256 x 512) =================
// Spectrum layout: S[k2*256 + k1], true k = k2 + 512*k1.
// Mixed-radix Stockham: radix-2 first (512 only, twiddle-free), then radix-4.
// Twiddles via HW trig; w2=w1^2, w3=w1*w2 in registers. Same bank swizzle.

template<int L, int Ns, int DIR>
__device__ __forceinline__ void r4_stage(const float* __restrict__ xr,
                                         const float* __restrict__ xi,
                                         float* __restrict__ yr,
                                         float* __restrict__ yi)
{
  const int tid = threadIdx.x;
  constexpr int BPR = L/4;              // butterflies per row
  #pragma unroll
  for (int q = 0; q < 4; q++){
    int bf = tid + 256*q;               // 1024 butterflies
    int r  = bf / BPR;
    int j  = bf % BPR;
    int sw = (r & 7) << 2;
    int jm = j & (Ns - 1);
    float2 w1 = twid((float)jm * (1.0f/(4.0f*(float)Ns)));
    if (DIR < 0) w1.y = -w1.y;
    float2 w2 = make_float2(w1.x*w1.x - w1.y*w1.y, 2.0f*w1.x*w1.y);
    float2 w3 = make_float2(w2.x*w1.x - w2.y*w1.y, w2.x*w1.y + w2.y*w1.x);
    const float* xrr = xr + r*L;
    const float* xir = xi + r*L;
    float ar  = xrr[j ^ sw],           ai  = xir[j ^ sw];
    float b0r = xrr[(j+BPR) ^ sw],     b0i = xir[(j+BPR) ^ sw];
    float c0r = xrr[(j+2*BPR) ^ sw],   c0i = xir[(j+2*BPR) ^ sw];
    float d0r = xrr[(j+3*BPR) ^ sw],   d0i = xir[(j+3*BPR) ^ sw];
    float br = b0r*w1.x - b0i*w1.y,  bi = b0r*w1.y + b0i*w1.x;
    float cr = c0r*w2.x - c0i*w2.y,  ci = c0r*w2.y + c0i*w2.x;
    float dr = d0r*w3.x - d0i*w3.y,  di = d0r*w3.y + d0i*w3.x;
    float apc_r = ar + cr, apc_i = ai + ci;
    float amc_r = ar - cr, amc_i = ai - ci;
    float bpd_r = br + dr, bpd_i = bi + di;
    float bmd_r = br - dr, bmd_i = bi - di;
    int dbase = ((j - jm) << 2) + jm;   // (j/Ns)*4Ns + jm
    float* yrr = yr + r*L;
    float* yir = yi + r*L;
    yrr[dbase ^ sw]          = apc_r + bpd_r;
    yir[dbase ^ sw]          = apc_i + bpd_i;
    yrr[(dbase + 2*Ns) ^ sw] = apc_r - bpd_r;
    yir[(dbase + 2*Ns) ^ sw] = apc_i - bpd_i;
    if (DIR > 0){
      yrr[(dbase + Ns) ^ sw]   = amc_r + bmd_i;   // X1 = (a-c) - i(b-d)
      yir[(dbase + Ns) ^ sw]   = amc_i - bmd_r;
      yrr[(dbase + 3*Ns) ^ sw] = amc_r - bmd_i;   // X3 = (a-c) + i(b-d)
      yir[(dbase + 3*Ns) ^ sw] = amc_i + bmd_r;
    } else {
      yrr[(dbase + Ns) ^ sw]   = amc_r - bmd_i;
      yir[(dbase + Ns) ^ sw]   = amc_i + bmd_r;
      yrr[(dbase + 3*Ns) ^ sw] = amc_r + bmd_i;
      yir[(dbase + 3*Ns) ^ sw] = amc_i - bmd_r;
    }
  }
}

#define FFT_SWAP { float* t_; t_=ra;ra=rb;rb=t_; t_=ia;ia=ib;ib=t_; }

template<int L, int DIR>
__device__ __forceinline__ void fft_core4(float*& ra, float*& ia, float*& rb, float*& ib)
{
  const int tid = threadIdx.x;
  if (L == 512){
    // radix-2 stage, Ns=1 (twiddle = 1): y[2j]=a+b, y[2j+1]=a-b
    __syncthreads();
    #pragma unroll
    for (int q = 0; q < 8; q++){
      int bf = tid + 256*q;             // 2048 butterflies
      int r = bf >> 8, j = bf & 255;
      int sw = (r & 7) << 2;
      float ar = ra[r*512 + (j ^ sw)],        ai = ia[r*512 + (j ^ sw)];
      float br = ra[r*512 + ((j+256) ^ sw)],  bi = ia[r*512 + ((j+256) ^ sw)];
      rb[r*512 + ((2*j) ^ sw)]   = ar + br;
      ib[r*512 + ((2*j) ^ sw)]   = ai + bi;
      rb[r*512 + ((2*j+1) ^ sw)] = ar - br;
      ib[r*512 + ((2*j+1) ^ sw)] = ai - bi;
    }
    FFT_SWAP
    __syncthreads(); r4_stage<512,   2, DIR>(ra, ia, rb, ib); FFT_SWAP
    __syncthreads(); r4_stage<512,   8, DIR>(ra, ia, rb, ib); FFT_SWAP
    __syncthreads(); r4_stage<512,  32, DIR>(ra, ia, rb, ib); FFT_SWAP
    __syncthreads(); r4_stage<512, 128, DIR>(ra, ia, rb, ib); FFT_SWAP
  } else {
    __syncthreads(); r4_stage<256,   1, DIR>(ra, ia, rb, ib); FFT_SWAP
    __syncthreads(); r4_stage<256,   4, DIR>(ra, ia, rb, ib); FFT_SWAP
    __syncthreads(); r4_stage<256,  16, DIR>(ra, ia, rb, ib); FFT_SWAP
    __syncthreads(); r4_stage<256,  64, DIR>(ra, ia, rb, ib); FFT_SWAP
  }
  __syncthreads();
}

// F1: z = a + i*b (two real signals, zero-padded), FFT_512 over n2,
// twiddle, write transposed Bt[k2*256 + n1].
__global__ __launch_bounds__(256) void fwd512_pack_kernel(
    const float* __restrict__ srcA, int lenA, int strideA,
    const float* __restrict__ srcB, int lenB, int strideB,
    float2* __restrict__ Bt)
{
  __shared__ float reA[4096], imA[4096], reB[4096], imB[4096];
  const int e = blockIdx.y, t1 = blockIdx.x*8, tid = threadIdx.x;
  #pragma unroll
  for (int q = 0; q < 4; q++){
    int flat = tid + 256*q;
    int n2 = flat >> 1;
    int rb = (flat & 1)*4;
    int nb = t1 + rb + 256*n2;
    float4 va = make_float4(0.f,0.f,0.f,0.f);
    float4 vb = make_float4(0.f,0.f,0.f,0.f);
    if (nb < lenA) va = *(const float4*)(srcA + (size_t)e*strideA + nb);
    if (nb < lenB) vb = *(const float4*)(srcB + (size_t)e*strideB + nb);
    #pragma unroll
    for (int j = 0; j < 4; j++){
      int r = rb + j;
      int sw = (r & 7) << 2;
      reA[r*512 + (n2 ^ sw)] = (&va.x)[j];
      imA[r*512 + (n2 ^ sw)] = (&vb.x)[j];
    }
  }
  float *ra = reA, *ia = imA, *rb2 = reB, *ib2 = imB;
  fft_core4<512, +1>(ra, ia, rb2, ib2);
  float2* dst = Bt + ((size_t)e << 17);
  #pragma unroll
  for (int q = 0; q < 16; q++){
    int idx = tid + 256*q;
    int r = idx & 7, k2 = idx >> 3;
    int n1 = t1 + r;
    int sw = (r & 7) << 2;
    float xr = ra[r*512 + (k2 ^ sw)];
    float xi = ia[r*512 + (k2 ^ sw)];
    float2 w = twid((float)(n1*k2) * (1.0f/131072.0f));
    dst[k2*256 + n1] = make_float2(xr*w.x - xi*w.y, xr*w.y + xi*w.x);
  }
}

// F1-rooms: z = rooms[2e] + i*rooms[2e+1] computed inline from verbs/rho.
__global__ __launch_bounds__(256) void fwd512_pack_rooms_kernel(
    const float* __restrict__ verbs, const float* __restrict__ rho,
    float2* __restrict__ Bt)
{
  __shared__ float reA[4096], imA[4096], reB[4096], imB[4096];
  __shared__ float srho[32];
  const int e = blockIdx.y, t1 = blockIdx.x*8, tid = threadIdx.x;
  if (tid < 32) srho[tid] = rho[(2*e)*16 + tid];
  __syncthreads();
  #pragma unroll
  for (int q = 0; q < 4; q++){
    int flat = tid + 256*q;
    int n2 = flat >> 1;
    int rb = (flat & 1)*4;
    int nb = t1 + rb + 256*n2;
    float4 va = make_float4(0.f,0.f,0.f,0.f);
    float4 vb = make_float4(0.f,0.f,0.f,0.f);
    if (nb < NS){
      #pragma unroll
      for (int v = 0; v < 16; v++){
        float4 w4 = *(const float4*)(verbs + (size_t)v*NS + nb);
        float r0 = srho[v], r1 = srho[16 + v];
        va.x += r0*w4.x; va.y += r0*w4.y; va.z += r0*w4.z; va.w += r0*w4.w;
        vb.x += r1*w4.x; vb.y += r1*w4.y; vb.z += r1*w4.z; vb.w += r1*w4.w;
      }
    }
    #pragma unroll
    for (int j = 0; j < 4; j++){
      int r = rb + j;
      int sw = (r & 7) << 2;
      reA[r*512 + (n2 ^ sw)] = (&va.x)[j];
      imA[r*512 + (n2 ^ sw)] = (&vb.x)[j];
    }
  }
  float *ra = reA, *ia = imA, *rb2 = reB, *ib2 = imB;
  fft_core4<512, +1>(ra, ia, rb2, ib2);
  float2* dst = Bt + ((size_t)e << 17);
  #pragma unroll
  for (int q = 0; q < 16; q++){
    int idx = tid + 256*q;
    int r = idx & 7, k2 = idx >> 3;
    int n1 = t1 + r;
    int sw = (r & 7) << 2;
    float xr = ra[r*512 + (k2 ^ sw)];
    float xi = ia[r*512 + (k2 ^ sw)];
    float2 w = twid((float)(n1*k2) * (1.0f/131072.0f));
    dst[k2*256 + n1] = make_float2(xr*w.x - xi*w.y, xr*w.y + xi*w.x);
  }
}

// F2: in-place FFT_256 along contiguous rows (row = k2).
__global__ __launch_bounds__(256) void fwd256_kernel(float2* __restrict__ S)
{
  __shared__ float reA[4096], imA[4096], reB[4096], imB[4096];
  const int e = blockIdx.y, K0 = blockIdx.x*16, tid = threadIdx.x;
  float2* base = S + ((size_t)e << 17) + (size_t)K0*256;
  #pragma unroll
  for (int q = 0; q < 16; q++){
    int idx = tid + 256*q;
    int r = idx >> 8, col = idx & 255;
    float2 v = base[r*256 + col];
    int sw = (r & 7) << 2;
    reA[r*256 + (col ^ sw)] = v.x;
    imA[r*256 + (col ^ sw)] = v.y;
  }
  float *ra = reA, *ia = imA, *rb = reB, *ib = imB;
  fft_core4<256, +1>(ra, ia, rb, ib);
  #pragma unroll
  for (int q = 0; q < 16; q++){
    int idx = tid + 256*q;
    int r = idx >> 8, col = idx & 255;
    int sw = (r & 7) << 2;
    base[r*256 + col] = make_float2(ra[r*256 + (col ^ sw)], ia[r*256 + (col ^ sw)]);
  }
}

// I1: Hermitian-unpack TWO packed spectra, per-event product, repack
// Y = P0 + i*P1, inverse FFT_256, conj twiddle, write Ut[n1*512 + k2].
__global__ __launch_bounds__(256) void inv256_mul2_kernel(
    const float2* __restrict__ ZA, const float2* __restrict__ ZB,
    float2* __restrict__ Ut)
{
  __shared__ float reA[4096], imA[4096], reB[4096], imB[4096];
  const int e = blockIdx.y, K0 = blockIdx.x*16, tid = threadIdx.x;
  const float2* Za = ZA + ((size_t)e << 17);
  const float2* Zb = ZB + ((size_t)e << 17);
  #pragma unroll
  for (int q = 0; q < 16; q++){
    int idx = tid + 256*q;
    int r = idx >> 8, col = idx & 255;
    int k2 = K0 + r;
    int k2p, k1p;
    if (k2 == 0){ k2p = 0; k1p = (256 - col) & 255; }
    else        { k2p = 512 - k2; k1p = 255 - col; }
    float2 za  = Za[(size_t)k2*256 + col];
    float2 zap = Za[(size_t)k2p*256 + k1p];
    float2 zb  = Zb[(size_t)k2*256 + col];
    float2 zbp = Zb[(size_t)k2p*256 + k1p];
    float a0r = 0.5f*(za.x + zap.x), a0i = 0.5f*(za.y - zap.y);
    float a1r = 0.5f*(za.y + zap.y), a1i = 0.5f*(zap.x - za.x);
    float b0r = 0.5f*(zb.x + zbp.x), b0i = 0.5f*(zb.y - zbp.y);
    float b1r = 0.5f*(zb.y + zbp.y), b1i = 0.5f*(zbp.x - zb.x);
    float p0r = a0r*b0r - a0i*b0i, p0i = a0r*b0i + a0i*b0r;
    float p1r = a1r*b1r - a1i*b1i, p1i = a1r*b1i + a1i*b1r;
    int sw = (r & 7) << 2;
    reA[r*256 + (col ^ sw)] = p0r - p1i;
    imA[r*256 + (col ^ sw)] = p0i + p1r;
  }
  float *ra = reA, *ia = imA, *rb = reB, *ib = imB;
  fft_core4<256, -1>(ra, ia, rb, ib);
  float2* dst = Ut + ((size_t)e << 17);
  #pragma unroll
  for (int q = 0; q < 16; q++){
    int idx = tid + 256*q;
    int r = idx & 15, n1 = idx >> 4;
    int k2 = K0 + r;
    int sw = (r & 7) << 2;
    float xr = ra[r*256 + (n1 ^ sw)];
    float xi = ia[r*256 + (n1 ^ sw)];
    float2 w = twid((float)(n1*k2) * (1.0f/131072.0f));   // conj applied
    dst[n1*512 + k2] = make_float2(xr*w.x + xi*w.y, xi*w.x - xr*w.y);
  }
}

// I2+F1 fused: inverse FFT_512 -> packed conv pair; write CONV;
// truncate (n2>=256 -> 0) and forward FFT_512 + twiddle -> Bt.
__global__ __launch_bounds__(256) void inv512_fwdpack2_kernel(
    const float2* __restrict__ Ut, float* __restrict__ conv,
    float2* __restrict__ Bt)
{
  __shared__ float reA[4096], imA[4096], reB[4096], imB[4096];
  const int e = blockIdx.y, t1 = blockIdx.x*8, tid = threadIdx.x;
  const float2* base = Ut + ((size_t)e << 17) + (size_t)t1*512;
  #pragma unroll
  for (int q = 0; q < 16; q++){
    int idx = tid + 256*q;
    int r = idx >> 9, col = idx & 511;
    float2 v = base[r*512 + col];
    int sw = (r & 7) << 2;
    reA[r*512 + (col ^ sw)] = v.x;
    imA[r*512 + (col ^ sw)] = v.y;
  }
  float *ra = reA, *ia = imA, *rb = reB, *ib = imB;
  fft_core4<512, -1>(ra, ia, rb, ib);
  const float s = 1.0f/131072.0f;
  #pragma unroll
  for (int q = 0; q < 16; q++){
    int idx = tid + 256*q;
    int r = idx & 7, n2 = idx >> 3;
    int sw = (r & 7) << 2;
    int pos = r*512 + (n2 ^ sw);
    if (n2 < 256){
      int n = (t1 + r) + 256*n2;
      float y0 = ra[pos]*s, y1 = ia[pos]*s;
      conv[(size_t)(2*e)*NS + n]     = y0;
      conv[(size_t)(2*e + 1)*NS + n] = y1;
      rb[pos] = y0; ib[pos] = y1;
    } else {
      rb[pos] = 0.f; ib[pos] = 0.f;
    }
  }
  __syncthreads();
  float *r2 = rb, *i2 = ib, *r3 = ra, *i3 = ia;
  fft_core4<512, +1>(r2, i2, r3, i3);
  float2* dst = Bt + ((size_t)e << 17);
  #pragma unroll
  for (int q = 0; q < 16; q++){
    int idx = tid + 256*q;
    int r = idx & 7, k2 = idx >> 3;
    int n1 = t1 + r;
    int sw = (r & 7) << 2;
    float xr = r2[r*512 + (k2 ^ sw)];
    float xi = i2[r*512 + (k2 ^ sw)];
    float2 w = twid((float)(n1*k2) * (1.0f/131072.0f));
    dst[k2*256 + n1] = make_float2(xr*w.x - xi*w.y, xr*w.y + xi*w.x);
  }
}

// I2-final: inverse FFT_512 -> packed wet pair; mix with conv, write out.
__global__ __launch_bounds__(256) void inv512_mix2_kernel(
    const float2* __restrict__ Ut, const float* __restrict__ conv,
    const float* __restrict__ scal, float* __restrict__ dst)
{
  __shared__ float reA[4096], imA[4096], reB[4096], imB[4096];
  const int e = blockIdx.y, t1 = blockIdx.x*8, tid = threadIdx.x;
  const float2* base = Ut + ((size_t)e << 17) + (size_t)t1*512;
  #pragma unroll
  for (int q = 0; q < 16; q++){
    int idx = tid + 256*q;
    int r = idx >> 9, col = idx & 511;
    float2 v = base[r*512 + col];
    int sw = (r & 7) << 2;
    reA[r*512 + (col ^ sw)] = v.x;
    imA[r*512 + (col ^ sw)] = v.y;
  }
  float *ra = reA, *ia = imA, *rb = reB, *ib = imB;
  fft_core4<512, -1>(ra, ia, rb, ib);
  const float s = 1.0f/131072.0f;
  const int e0 = 2*e, e1 = 2*e + 1;
  float m00 = scal[e0*4 + 0], m10 = scal[e0*4 + 1], a20 = scal[e0*4 + 2];
  float m01 = scal[e1*4 + 0], m11 = scal[e1*4 + 1], a21 = scal[e1*4 + 2];
  #pragma unroll
  for (int q = 0; q < 8; q++){
    int idx = tid + 256*q;
    int r = idx & 7, n2 = idx >> 3;
    int n = (t1 + r) + 256*n2;
    int sw = (r & 7) << 2;
    int pos = r*512 + (n2 ^ sw);
    float w0 = ra[pos]*s, w1 = ia[pos]*s;
    size_t g0 = (size_t)e0*NS + n, g1 = (size_t)e1*NS + n;
    dst[g0] = (m00*conv[g0] + m10*w0)*a20;
    dst[g1] = (m01*conv[g1] + m11*w1)*a21;
  }
}

// ---------------- fallback: direct causal conv ----------------
template<int MODE>
__global__ __launch_bounds__(256) void tconv_kernel(
    const float* __restrict__ sig, int sig_len, int sig_stride,
    const float* __restrict__ go, const float* __restrict__ scal,
    float* __restrict__ dst)
{
  __shared__ __align__(16) float cs[2048];
  __shared__ __align__(16) float rs[4104];
  const int e = blockIdx.y;
  const int t0 = blockIdx.x * 2048;
  const int tid = threadIdx.x;
  const int tb = tid * 8;
  float acc[8] = {0,0,0,0,0,0,0,0};
  const int kcap = imin(sig_len, t0 + 2048);
  for (int c0 = 0; c0 < kcap; c0 += 2048){
    __syncthreads();
    for (int idx = tid; idx < 2048; idx += 256){
      int gsi = c0 + idx;
      cs[idx] = (gsi < sig_len) ? sig[(size_t)e*sig_stride + gsi] : 0.f;
    }
    const int rb = t0 - c0 - 2056;
    for (int idx = tid; idx < 4104; idx += 256){
      int g = rb + idx;
      rs[idx] = (g >= 0 && g < NS) ? go[(size_t)e*NS + g] : 0.f;
    }
    __syncthreads();
    float W[12];
    int P = tb + 2056;
    *(float4*)&W[0] = *(const float4*)&rs[P - 4];
    *(float4*)&W[4] = *(const float4*)&rs[P];
    *(float4*)&W[8] = *(const float4*)&rs[P + 4];
    for (int u = 0; u < 512; u++){
      float4 f4 = *(const float4*)&cs[4*u];
      #pragma unroll
      for (int j = 0; j < 8; j++){
        acc[j] += f4.x*W[4 + j];
        acc[j] += f4.y*W[3 + j];
        acc[j] += f4.z*W[2 + j];
        acc[j] += f4.w*W[1 + j];
      }
      #pragma unroll
      for (int x2 = 11; x2 >= 4; x2--) W[x2] = W[x2 - 4];
      P -= 4;
      *(float4*)&W[0] = *(const float4*)&rs[P - 4];
    }
  }
  if (MODE == 0){
    #pragma unroll
    for (int j = 0; j < 8; j++) dst[(size_t)e*NS + t0 + tb + j] = acc[j];
  } else {
    float m0 = scal[e*4 + 0], m1 = scal[e*4 + 1], a2 = scal[e*4 + 2];
    #pragma unroll
    for (int j = 0; j < 8; j++){
      size_t gi = (size_t)e*NS + t0 + tb + j;
      dst[gi] = (m0*sig[gi] + m1*acc[j]) * a2;
    }
  }
}

// ---------------- launcher ----------------
extern "C" void kernel_launch(void* const* d_in, const int* in_sizes, int n_in,
                              void* d_out, int out_size, void* d_ws, size_t ws_size,
                              hipStream_t stream)
{
  (void)in_sizes; (void)n_in; (void)out_size;
  const float* res_sel     = (const float*)d_in[0];
  const float* noise_sel   = (const float*)d_in[1];
  const float* env_sel     = (const float*)d_in[2];
  const float* dec_sel     = (const float*)d_in[3];
  const float* def_sel     = (const float*)d_in[4];
  const float* ndef_sel    = (const float*)d_in[5];
  const float* mix_sel     = (const float*)d_in[6];
  const float* room_sel    = (const float*)d_in[7];
  const float* amp         = (const float*)d_in[8];
  const float* r_items     = (const float*)d_in[9];
  const float* n_items     = (const float*)d_in[10];
  const float* e_items     = (const float*)d_in[11];
  const float* d_items     = (const float*)d_in[12];
  const float* warp_items  = (const float*)d_in[13];
  const float* nwarp_items = (const float*)d_in[14];
  const float* verbs       = (const float*)d_in[15];
  const float* waves       = (const float*)d_in[16];
  float* ws  = (float*)d_ws;
  float* out = (float*)d_out;

  const bool big_ws = ws_size >= (size_t)O_END * sizeof(float);

  if (big_ws) {
    weights_kernel<<<dim3(NEV), dim3(64), 0, stream>>>(
        noise_sel, env_sel, dec_sel, def_sel, ndef_sel, mix_sel, room_sel, amp,
        d_items, ws + O_SWE, ws + O_SWN, ws + O_SWD, ws + O_SWND,
        ws + O_DSM, ws + O_SCAL, ws + O_RHO);
    envs_kernel<<<dim3(NEV), dim3(128), 0, stream>>>(ws + O_SWE, e_items, ws + O_ENV_SMALL);
    nfil_kernel<<<dim3(128), dim3(256), 0, stream>>>(ws + O_SWN, n_items, ws + O_NFIL);
    warp_kernel<<<dim3(NEV), dim3(128), 0, stream>>>(ws + O_SWD, warp_items, ws + O_WSM);
    nwarp_kernel<<<dim3(NEV), dim3(128), 0, stream>>>(ws + O_SWND, nwarp_items, ws + O_ND);

    p1_softmax_kernel<<<dim3(256), dim3(256), 0, stream>>>(res_sel, ws + O_P1);
    p2_kernel<<<dim3(4, 32), dim3(256), 0, stream>>>(ws + O_P1, r_items, ws + O_P2);

    env_noise_kernel<<<dim3(1024), dim3(256), 0, stream>>>(ws + O_ENV_SMALL, ws + O_IMP);
    filt_kernel<<<dim3(34, NEV), dim3(256), 0, stream>>>(ws + O_NFIL, ws + O_IMP, ws + O_ND, ws + O_FILT);

    unsigned short* Ahi = (unsigned short*)(ws + O_X);
    split_a_kernel<<<dim3(256), dim3(256), 0, stream>>>(ws + O_P2, Ahi);
    gemm_dres_gen3_kernel<<<dim3(512), dim3(512), 0, stream>>>(
        Ahi, ws + O_WSM, ws + O_DSM, ws + O_DRES);

    // ---- event-pair-packed FFT convolution ----
    float2* Xf = (float2*)(ws + O_X);
    float2* Xd = (float2*)(ws + O_X + 4194304);
    float2* Xr = (float2*)(ws + O_Y);
    float2* Uc = (float2*)(ws + O_Y + 4194304);
    float2* Xc = Xf;
    float2* Uw = Xd;

    fwd512_pack_kernel<<<dim3(32, 16), dim3(256), 0, stream>>>(
        ws + O_FILT, FLEN, 2*FLEN, ws + O_FILT + FLEN, FLEN, 2*FLEN, Xf);
    fwd256_kernel<<<dim3(32, 16), dim3(256), 0, stream>>>(Xf);
    fwd512_pack_kernel<<<dim3(32, 16), dim3(256), 0, stream>>>(
        ws + O_DRES, NS, 2*NS, ws + O_DRES + NS, NS, 2*NS, Xd);
    fwd256_kernel<<<dim3(32, 16), dim3(256), 0, stream>>>(Xd);
    fwd512_pack_rooms_kernel<<<dim3(32, 16), dim3(256), 0, stream>>>(
        verbs, ws + O_RHO, Xr);
    fwd256_kernel<<<dim3(32, 16), dim3(256), 0, stream>>>(Xr);

    inv256_mul2_kernel<<<dim3(32, 16), dim3(256), 0, stream>>>(Xf, Xd, Uc);
    inv512_fwdpack2_kernel<<<dim3(32, 16), dim3(256), 0, stream>>>(Uc, ws + O_CONV, Xc);
    fwd256_kernel<<<dim3(32, 16), dim3(256), 0, stream>>>(Xc);
    inv256_mul2_kernel<<<dim3(32, 16), dim3(256), 0, stream>>>(Xc, Xr, Uw);
    inv512_mix2_kernel<<<dim3(32, 16), dim3(256), 0, stream>>>(
        Uw, ws + O_CONV, ws + O_SCAL, out);
  } else {
    // fallback: legacy prep + f32 GEMM + direct time-domain conv
    prep_kernel<<<dim3(NEV), dim3(64), 0, stream>>>(
        noise_sel, env_sel, dec_sel, def_sel, ndef_sel, mix_sel, room_sel, amp,
        n_items, e_items, d_items, warp_items, nwarp_items,
        ws + O_ENV_SMALL, ws + O_NFIL, ws + O_ND, ws + O_WSM,
        ws + O_DSM, ws + O_SCAL, ws + O_RHO);
    p1_softmax_kernel<<<dim3(256), dim3(256), 0, stream>>>(res_sel, ws + O_P1);
    p2_kernel<<<dim3(4, 32), dim3(256), 0, stream>>>(ws + O_P1, r_items, ws + O_P2);
    env_noise_kernel<<<dim3(1024), dim3(256), 0, stream>>>(ws + O_ENV_SMALL, ws + O_IMP);
    filt_kernel<<<dim3(34, NEV), dim3(256), 0, stream>>>(ws + O_NFIL, ws + O_IMP, ws + O_ND, ws + O_FILT);
    rooms_kernel<<<dim3(256, NEV), dim3(256), 0, stream>>>(verbs, ws + O_RHO, ws + O_ROOMS);
    gemm_dres_kernel<<<dim3(1024), dim3(256), 0, stream>>>(
        ws + O_P2, waves, ws + O_WSM, ws + O_DSM, ws + O_DRES);
    tconv_kernel<0><<<dim3(32, NEV), dim3(256), 0, stream>>>(
        ws + O_FILT, FLEN, FLEN, ws + O_DRES, (const float*)nullptr, ws + O_CONV);
    tconv_kernel<1><<<dim3(32, NEV), dim3(256), 0, stream>>>(
        ws + O_CONV, NS, NS, ws + O_ROOMS, ws + O_SCAL, out);
  }
}

// Round 10
// 356.184 us; speedup vs baseline: 1.5860x; 1.0899x over previous
//
#include <hip/hip_runtime.h>
#include <math.h>

// ---------------- problem sizes ----------------
#define NEV    32      // n_events
#define NS     65536   // n_samples
#define NFFT   131072  // 2*NS
#define ENVS   128
#define ENVF   8192
#define FSAMP2 512
#define NEXP2  4
#define FLEN   8704    // filtered support (8192 + 512 - 1 -> padded to 8704)
#define GD     5622750u   // 22050*255 (phase denominator)
#define GDH    2811375u   // GD/2

// ---------------- workspace layout (float offsets) ----------------
enum : size_t {
  O_ENV_SMALL = 0,         // 32*128
  O_NFIL      = 4096,      // 32*4*512
  O_IMP       = 69632,     // 32*8192
  O_ND        = 331776,    // 32*4*128
  O_WSM       = 348160,    // 32*8*128
  O_DSM       = 380928,    // 32*128
  O_SCAL      = 385024,    // 32*4  (m0, m1, amp^2)
  O_RHO       = 385152,    // 32*16
  O_P1        = 385664,    // 256*1024 (fallback only)
  O_P2        = 647808,    // 256*1024 (fallback only)
  O_FILT      = 909952,    // 32*8704
  O_DRES      = 1188480,   // 32*65536
  O_CONV      = 3285632,   // 32*65536
  O_ROOMS     = 5382784,   // 32*65536 (fallback path only)
  O_SWE       = 7479936,   // 32*64
  O_SWN       = 7482048,   // 32*4*64
  O_SWD       = 7490304,   // 32*64
  O_SWND      = 7492416,   // 32*32
  O_X         = 7742080,   // 8,388,608 floats: Xf | Xd  (16 pair-slices each)
  O_Y         = 16130688,  // 8,388,608 floats: Xr | Uc
  O_END       = 24519296,  // *4 bytes = 98,077,184
};

typedef float f32x4 __attribute__((ext_vector_type(4)));
typedef short bf16x8 __attribute__((ext_vector_type(8)));

union U8 { uint4 q; bf16x8 v; unsigned short u[8]; };

__device__ __forceinline__ int imin(int a, int b){ return a < b ? a : b; }

__device__ __forceinline__ float wsum(float v){
  #pragma unroll
  for (int o = 32; o > 0; o >>= 1) v += __shfl_xor(v, o);
  return v;
}
__device__ __forceinline__ float wmax(float v){
  #pragma unroll
  for (int o = 32; o > 0; o >>= 1) v = fmaxf(v, __shfl_xor(v, o));
  return v;
}

__device__ __forceinline__ unsigned short f2bf(float f){
  unsigned u = __float_as_uint(f);
  unsigned r = (u + 0x7fffu + ((u >> 16) & 1u)) >> 16;
  return (unsigned short)r;
}

// e^{-2*pi*i*frac} via HW trig (input in revolutions)
__device__ __forceinline__ float2 twid(float frac){
  float c, s;
  asm("v_cos_f32 %0, %1" : "=v"(c) : "v"(frac));
  asm("v_sin_f32 %0, %1" : "=v"(s) : "v"(frac));
  return make_float2(c, -s);
}

// ---------------- JAX threefry2x32, partitionable 32-bit path ----------------
__device__ __forceinline__ unsigned tf_rotl(unsigned x, int d){ return (x << d) | (x >> (32 - d)); }

__device__ unsigned threefry_bits(unsigned chi, unsigned clo){
  const unsigned k0 = 0u, k1 = 42u, k2 = 0x1BD11BDAu ^ 0u ^ 42u;
  unsigned x0 = chi + k0;
  unsigned x1 = clo + k1;
  x0 += x1; x1 = tf_rotl(x1,13); x1 ^= x0;
  x0 += x1; x1 = tf_rotl(x1,15); x1 ^= x0;
  x0 += x1; x1 = tf_rotl(x1,26); x1 ^= x0;
  x0 += x1; x1 = tf_rotl(x1, 6); x1 ^= x0;
  x0 += k1; x1 += k2 + 1u;
  x0 += x1; x1 = tf_rotl(x1,17); x1 ^= x0;
  x0 += x1; x1 = tf_rotl(x1,29); x1 ^= x0;
  x0 += x1; x1 = tf_rotl(x1,16); x1 ^= x0;
  x0 += x1; x1 = tf_rotl(x1,24); x1 ^= x0;
  x0 += k2; x1 += k0 + 2u;
  x0 += x1; x1 = tf_rotl(x1,13); x1 ^= x0;
  x0 += x1; x1 = tf_rotl(x1,15); x1 ^= x0;
  x0 += x1; x1 = tf_rotl(x1,26); x1 ^= x0;
  x0 += x1; x1 = tf_rotl(x1, 6); x1 ^= x0;
  x0 += k0; x1 += k1 + 3u;
  x0 += x1; x1 = tf_rotl(x1,17); x1 ^= x0;
  x0 += x1; x1 = tf_rotl(x1,29); x1 ^= x0;
  x0 += x1; x1 = tf_rotl(x1,16); x1 ^= x0;
  x0 += x1; x1 = tf_rotl(x1,24); x1 ^= x0;
  x0 += k1; x1 += k2 + 4u;
  x0 += x1; x1 = tf_rotl(x1,13); x1 ^= x0;
  x0 += x1; x1 = tf_rotl(x1,15); x1 ^= x0;
  x0 += x1; x1 = tf_rotl(x1,26); x1 ^= x0;
  x0 += x1; x1 = tf_rotl(x1, 6); x1 ^= x0;
  x0 += k2; x1 += k0 + 5u;
  return x0 ^ x1;
}

// ---------------- weights: softmaxes + decay/mix/room ----------------
__global__ __launch_bounds__(64) void weights_kernel(
    const float* __restrict__ noise_sel, const float* __restrict__ env_sel,
    const float* __restrict__ dec_sel,   const float* __restrict__ def_sel,
    const float* __restrict__ ndef_sel,  const float* __restrict__ mix_sel,
    const float* __restrict__ room_sel,  const float* __restrict__ amp,
    const float* __restrict__ d_items,
    float* __restrict__ swE, float* __restrict__ swN,
    float* __restrict__ swD, float* __restrict__ swND,
    float* __restrict__ d_small, float* __restrict__ scal,
    float* __restrict__ rho)
{
  const int e = blockIdx.x;
  const int l = threadIdx.x;

  {
    float x = env_sel[e*64 + l];
    float mx = wmax(x);
    float ex = expf(x - mx);
    float sm = wsum(ex);
    swE[e*64 + l] = ex / sm;
  }
  #pragma unroll
  for (int x4 = 0; x4 < NEXP2; x4++){
    float v = noise_sel[(e*NEXP2 + x4)*64 + l];
    float mxv = wmax(v);
    float exv = expf(v - mxv);
    float smv = wsum(exv);
    swN[(e*NEXP2 + x4)*64 + l] = exv / smv;
  }
  {
    float x = def_sel[e*64 + l];
    float mx = wmax(x);
    float ex = expf(x - mx);
    float sm = wsum(ex);
    swD[e*64 + l] = ex / sm;
  }
  {
    float x = (l < 32) ? ndef_sel[e*32 + l] : -1e30f;
    float mx = wmax(x);
    float ex = (l < 32) ? expf(x - mx) : 0.f;
    float sm = wsum(ex);
    if (l < 32) swND[e*32 + l] = ex / sm;
  }
  {
    float x = dec_sel[e*64 + l];
    float mx = wmax(x);
    float ex = expf(x - mx);
    float sm = wsum(ex);
    float wgt = ex / sm;
    float di = d_items[l];
    float dp = 0.5f + 0.5f*(1.0f/(1.0f + expf(-di)));
    float d0 = wsum(wgt*dp);
    float ld = logf(d0 + 1e-12f);
    #pragma unroll
    for (int c = 0; c < 2; c++){
      int f = l + 64*c;
      d_small[e*128 + f] = expf((float)(f+1)*ld);
    }
  }
  if (l == 0){
    float a = mix_sel[e*2 + 0], b = mix_sel[e*2 + 1];
    float mm = fmaxf(a, b);
    float ea = expf(a - mm), eb = expf(b - mm);
    float ss = ea + eb;
    scal[e*4 + 0] = ea/ss;
    scal[e*4 + 1] = eb/ss;
    float am = amp[e];
    scal[e*4 + 2] = am*am;
  }
  {
    float x = (l < 16) ? room_sel[e*16 + l] : -1e30f;
    float mx = wmax(x);
    float ex = (l < 16) ? expf(x - mx) : 0.f;
    float sm = wsum(ex);
    if (l < 16) rho[e*16 + l] = ex/sm;
  }
}

// ---------------- fused output-parallel lookups (envs | nfil | warp | nwarp) ----
// blocks: [0,32) envs, [32,160) nfil, [160,192) warp, [192,224) nwarp
__global__ __launch_bounds__(256) void lookups_kernel(
    const float* __restrict__ swE,  const float* __restrict__ swN,
    const float* __restrict__ swD,  const float* __restrict__ swND,
    const float* __restrict__ e_items, const float* __restrict__ n_items,
    const float* __restrict__ warp_items, const float* __restrict__ nwarp_items,
    float* __restrict__ env_small, float* __restrict__ nfil,
    float* __restrict__ w_small,   float* __restrict__ nd_small)
{
  __shared__ float sw[64];
  const int b = blockIdx.x;
  const int tid = threadIdx.x;

  if (b < 32){                                 // envs
    const int e = b, j = tid;
    if (j < 64) sw[j] = swE[e*64 + j];
    __syncthreads();
    if (j < 128){
      float acc = 0.f;
      #pragma unroll 8
      for (int k = 0; k < 64; k++){ float it = e_items[k*ENVS + j]; acc += sw[k]*(it*it); }
      env_small[e*ENVS + j] = acc;
    }
  } else if (b < 160){                         // nfil
    const int bb = b - 32;
    if (tid < 64) sw[tid] = swN[bb*64 + tid];
    __syncthreads();
    #pragma unroll
    for (int c = 0; c < 2; c++){
      int tau = tid + 256*c;
      float acc = 0.f;
      #pragma unroll 8
      for (int f = 0; f < 64; f++) acc += sw[f]*n_items[f*FSAMP2 + tau];
      float ham = 0.54f - 0.46f*cosf((6.2831853071795864769f * (float)tau) / 511.0f);
      nfil[bb*FSAMP2 + tau] = acc*ham;
    }
  } else if (b < 192){                         // warp
    const int e = b - 160, f = tid;
    if (f < 64) sw[f] = swD[e*64 + f];
    __syncthreads();
    if (f < 128){
      float acc[8] = {0,0,0,0,0,0,0,0};
      for (int k = 0; k < 64; k++){
        float wk = sw[k];
        const float* row = warp_items + (size_t)k*1024 + f;
        #pragma unroll
        for (int i = 0; i < 8; i++) acc[i] += wk*row[i*128];
      }
      float mx = -1e30f;
      #pragma unroll
      for (int i = 0; i < 8; i++) mx = fmaxf(mx, acc[i]);
      float ev[8]; float s = 0.f;
      #pragma unroll
      for (int i = 0; i < 8; i++){ ev[i] = expf(acc[i] - mx); s += ev[i]; }
      #pragma unroll
      for (int i = 0; i < 8; i++) w_small[(e*8 + i)*128 + f] = ev[i]/s;
    }
  } else {                                     // nwarp
    const int e = b - 192, f = tid;
    if (f < 32) sw[f] = swND[e*32 + f];
    __syncthreads();
    if (f < 128){
      float acc[4] = {0,0,0,0};
      for (int k = 0; k < 32; k++){
        float wk = sw[k];
        const float* row = nwarp_items + (size_t)k*512 + f;
        #pragma unroll
        for (int x = 0; x < 4; x++) acc[x] += wk*row[x*128];
      }
      float mx = -1e30f;
      #pragma unroll
      for (int x = 0; x < 4; x++) mx = fmaxf(mx, acc[x]);
      float ev[4]; float s = 0.f;
      #pragma unroll
      for (int x = 0; x < 4; x++){ ev[x] = expf(acc[x] - mx); s += ev[x]; }
      #pragma unroll
      for (int x = 0; x < 4; x++) nd_small[(e*4 + x)*128 + f] = ev[x]/s;
    }
  }
}

// ---------------- fused p1+p2+split: softmax(res_sel) @ r_items -> Ahi (bf16) ----
// grid (4, 32): bx = col tile of 256, mg = row group of 8.
__global__ __launch_bounds__(256) void p2s_kernel(
    const float* __restrict__ res_sel, const float* __restrict__ r_items,
    unsigned short* __restrict__ Ahi)
{
  __shared__ __align__(16) float sp1[8][1024];
  const int bx = blockIdx.x;
  const int mg = blockIdx.y;
  const int tid = threadIdx.x;
  for (int idx = tid; idx < 2048; idx += 256)
    ((float4*)&sp1[0][0])[idx] = ((const float4*)(res_sel + (size_t)mg*8*1024))[idx];
  __syncthreads();
  // per-row softmax: 32 lanes per row
  {
    const int r = tid >> 5, lr = tid & 31;
    float mx = -1e30f;
    #pragma unroll 8
    for (int k = 0; k < 32; k++) mx = fmaxf(mx, sp1[r][lr + 32*k]);
    #pragma unroll
    for (int o = 16; o > 0; o >>= 1) mx = fmaxf(mx, __shfl_xor(mx, o));
    float sm = 0.f;
    float ev[32];
    #pragma unroll 8
    for (int k = 0; k < 32; k++){ ev[k] = expf(sp1[r][lr + 32*k] - mx); sm += ev[k]; }
    #pragma unroll
    for (int o = 16; o > 0; o >>= 1) sm += __shfl_xor(sm, o);
    float inv = 1.0f/sm;
    #pragma unroll 8
    for (int k = 0; k < 32; k++) sp1[r][lr + 32*k] = ev[k]*inv;
  }
  __syncthreads();
  const int n = bx*256 + tid;
  float acc[8] = {0,0,0,0,0,0,0,0};
  for (int k = 0; k < 1024; k++){
    float wv = r_items[(size_t)k*1024 + n];
    #pragma unroll
    for (int r = 0; r < 8; r++) acc[r] += sp1[r][k]*wv;
  }
  // write Ahi in MFMA fragment order: Ahi[(k>>3)*2048 + row*8 + (k&7)], k = n
  const size_t base = (size_t)(n >> 3)*2048 + (size_t)(n & 7);
  #pragma unroll
  for (int r = 0; r < 8; r++)
    Ahi[base + (size_t)(mg*8 + r)*8] = f2bf(acc[r]);
}

// ---------------- legacy prep (fallback path only) ----------------
__global__ __launch_bounds__(64) void prep_kernel(
    const float* __restrict__ noise_sel, const float* __restrict__ env_sel,
    const float* __restrict__ dec_sel,   const float* __restrict__ def_sel,
    const float* __restrict__ ndef_sel,  const float* __restrict__ mix_sel,
    const float* __restrict__ room_sel,  const float* __restrict__ amp,
    const float* __restrict__ n_items,   const float* __restrict__ e_items,
    const float* __restrict__ d_items,   const float* __restrict__ warp_items,
    const float* __restrict__ nwarp_items,
    float* __restrict__ env_small, float* __restrict__ nfil,
    float* __restrict__ nd_small,  float* __restrict__ w_small,
    float* __restrict__ d_small,   float* __restrict__ scal,
    float* __restrict__ rho)
{
  const int e = blockIdx.x;
  const int l = threadIdx.x;
  __shared__ float sw[64];
  __shared__ float buf[1024];

  {
    float x = env_sel[e*64 + l];
    float mx = wmax(x);
    float ex = expf(x - mx);
    float sm = wsum(ex);
    sw[l] = ex / sm;
  }
  __syncthreads();
  #pragma unroll
  for (int c = 0; c < 2; c++){
    int j = l + 64*c;
    float acc = 0.f;
    for (int k = 0; k < 64; k++){ float it = e_items[k*ENVS + j]; acc += sw[k]*(it*it); }
    env_small[e*ENVS + j] = acc;
  }
  __syncthreads();

  for (int x = 0; x < NEXP2; x++){
    float v = noise_sel[(e*NEXP2 + x)*64 + l];
    float mxv = wmax(v);
    float exv = expf(v - mxv);
    float smv = wsum(exv);
    sw[l] = exv / smv;
    __syncthreads();
    for (int c = 0; c < 8; c++){
      int tau = l + 64*c;
      float acc = 0.f;
      for (int f = 0; f < 64; f++) acc += sw[f]*n_items[f*FSAMP2 + tau];
      float ham = 0.54f - 0.46f*cosf((6.2831853071795864769f * (float)tau) / 511.0f);
      nfil[(e*NEXP2 + x)*FSAMP2 + tau] = acc*ham;
    }
    __syncthreads();
  }

  {
    float x = def_sel[e*64 + l];
    float mx = wmax(x);
    float ex = expf(x - mx);
    float sm = wsum(ex);
    sw[l] = ex / sm;
  }
  __syncthreads();
  for (int c = 0; c < 16; c++){
    int idx = l + 64*c;
    float acc = 0.f;
    for (int k = 0; k < 64; k++) acc += sw[k]*warp_items[k*1024 + idx];
    buf[idx] = acc;
  }
  __syncthreads();
  #pragma unroll
  for (int c = 0; c < 2; c++){
    int f = l + 64*c;
    float mx = -1e30f;
    for (int i = 0; i < 8; i++) mx = fmaxf(mx, buf[i*128 + f]);
    float ev[8]; float s = 0.f;
    for (int i = 0; i < 8; i++){ ev[i] = expf(buf[i*128 + f] - mx); s += ev[i]; }
    for (int i = 0; i < 8; i++) w_small[(e*8 + i)*128 + f] = ev[i]/s;
  }
  __syncthreads();

  {
    float x = (l < 32) ? ndef_sel[e*32 + l] : -1e30f;
    float mx = wmax(x);
    float ex = (l < 32) ? expf(x - mx) : 0.f;
    float sm = wsum(ex);
    sw[l] = (l < 32) ? ex/sm : 0.f;
  }
  __syncthreads();
  for (int c = 0; c < 8; c++){
    int idx = l + 64*c;
    float acc = 0.f;
    for (int k = 0; k < 32; k++) acc += sw[k]*nwarp_items[k*512 + idx];
    buf[idx] = acc;
  }
  __syncthreads();
  #pragma unroll
  for (int c = 0; c < 2; c++){
    int j = l + 64*c;
    float mx = -1e30f;
    for (int x = 0; x < 4; x++) mx = fmaxf(mx, buf[x*128 + j]);
    float ev[4]; float s = 0.f;
    for (int x = 0; x < 4; x++){ ev[x] = expf(buf[x*128 + j] - mx); s += ev[x]; }
    for (int x = 0; x < 4; x++) nd_small[(e*4 + x)*128 + j] = ev[x]/s;
  }
  __syncthreads();

  {
    float x = dec_sel[e*64 + l];
    float mx = wmax(x);
    float ex = expf(x - mx);
    float sm = wsum(ex);
    float wgt = ex / sm;
    float di = d_items[l];
    float dp = 0.5f + 0.5f*(1.0f/(1.0f + expf(-di)));
    float d0 = wsum(wgt*dp);
    float ld = logf(d0 + 1e-12f);
    #pragma unroll
    for (int c = 0; c < 2; c++){
      int f = l + 64*c;
      d_small[e*128 + f] = expf((float)(f+1)*ld);
    }
  }
  if (l == 0){
    float a = mix_sel[e*2 + 0], b = mix_sel[e*2 + 1];
    float mm = fmaxf(a, b);
    float ea = expf(a - mm), eb = expf(b - mm);
    float ss = ea + eb;
    scal[e*4 + 0] = ea/ss;
    scal[e*4 + 1] = eb/ss;
    float am = amp[e];
    scal[e*4 + 2] = am*am;
  }
  {
    float x = (l < 16) ? room_sel[e*16 + l] : -1e30f;
    float mx = wmax(x);
    float ex = (l < 16) ? expf(x - mx) : 0.f;
    float sm = wsum(ex);
    if (l < 16) rho[e*16 + l] = ex/sm;
  }
}

// ---------------- P1 = softmax(res_sel)  (fallback only) ----------------
__global__ __launch_bounds__(256) void p1_softmax_kernel(
    const float* __restrict__ res_sel, float* __restrict__ P1)
{
  const int m = blockIdx.x;
  const int tid = threadIdx.x;
  __shared__ float red[4], red2[4];
  const float* row = res_sel + (size_t)m*1024;
  float4 v = ((const float4*)row)[tid];
  float mx = fmaxf(fmaxf(v.x, v.y), fmaxf(v.z, v.w));
  #pragma unroll
  for (int o = 32; o > 0; o >>= 1) mx = fmaxf(mx, __shfl_xor(mx, o));
  if ((tid & 63) == 0) red[tid >> 6] = mx;
  __syncthreads();
  mx = fmaxf(fmaxf(red[0], red[1]), fmaxf(red[2], red[3]));
  float e0 = expf(v.x - mx), e1 = expf(v.y - mx), e2 = expf(v.z - mx), e3 = expf(v.w - mx);
  float s = e0 + e1 + e2 + e3;
  #pragma unroll
  for (int o = 32; o > 0; o >>= 1) s += __shfl_xor(s, o);
  if ((tid & 63) == 0) red2[tid >> 6] = s;
  __syncthreads();
  s = red2[0] + red2[1] + red2[2] + red2[3];
  float inv = 1.0f/s;
  ((float4*)(P1 + (size_t)m*1024))[tid] = make_float4(e0*inv, e1*inv, e2*inv, e3*inv);
}

// ---------------- P2 = P1 @ r_items  (fallback only) ----------------
__global__ __launch_bounds__(256) void p2_kernel(
    const float* __restrict__ P1, const float* __restrict__ r_items,
    float* __restrict__ P2)
{
  __shared__ __align__(16) float sp1[8][1024];
  const int bx = blockIdx.x;
  const int mg = blockIdx.y;
  const int tid = threadIdx.x;
  for (int idx = tid; idx < 2048; idx += 256)
    ((float4*)&sp1[0][0])[idx] = ((const float4*)(P1 + (size_t)mg*8*1024))[idx];
  __syncthreads();
  const int n = bx*256 + tid;
  float acc[8] = {0,0,0,0,0,0,0,0};
  for (int k = 0; k < 1024; k++){
    float wv = r_items[(size_t)k*1024 + n];
    #pragma unroll
    for (int r = 0; r < 8; r++) acc[r] += sp1[r][k]*wv;
  }
  #pragma unroll
  for (int r = 0; r < 8; r++) P2[(size_t)(mg*8 + r)*1024 + n] = acc[r];
}

// ---------------- impulses = interp(env_small,8192) * uniform_noise ----------------
__global__ __launch_bounds__(256) void env_noise_kernel(
    const float* __restrict__ env_small, float* __restrict__ impulses)
{
  const int flat = blockIdx.x*256 + threadIdx.x;
  const int e = flat >> 13, i = flat & 8191;
  unsigned bits = threefry_bits(0u, (unsigned)flat);
  float u01 = __uint_as_float((bits >> 9) | 0x3f800000u) - 1.0f;
  float nz  = fmaxf(-1.0f, u01*2.0f - 1.0f);
  float pos = (float)i * (127.0f/8191.0f);
  int lo = (int)floorf(pos);
  int hi = imin(lo + 1, 127);
  float w = pos - (float)lo;
  const float* es = env_small + e*ENVS;
  float v = es[lo]*(1.0f - w) + es[hi]*w;
  impulses[flat] = v*nz;
}

// ---------------- filtered: 512-tap FIR + nd combine ----------------
__global__ __launch_bounds__(256) void filt_kernel(
    const float* __restrict__ nfil, const float* __restrict__ impulses,
    const float* __restrict__ nd_small, float* __restrict__ filtered)
{
  __shared__ float nf[4*512];
  __shared__ float imp[768];
  const int e = blockIdx.y, t0 = blockIdx.x*256, tid = threadIdx.x;
  for (int idx = tid; idx < 2048; idx += 256) nf[idx] = nfil[e*2048 + idx];
  for (int idx = tid; idx < 768; idx += 256){
    int g = t0 - 512 + idx;
    imp[idx] = (g >= 0 && g < ENVF) ? impulses[e*ENVF + g] : 0.f;
  }
  __syncthreads();
  const int t = t0 + tid;
  float s0 = 0.f, s1 = 0.f, s2 = 0.f, s3 = 0.f;
  for (int tau = 0; tau < 512; tau++){
    float iv = imp[512 + tid - tau];
    s0 += nf[0*512 + tau]*iv;
    s1 += nf[1*512 + tau]*iv;
    s2 += nf[2*512 + tau]*iv;
    s3 += nf[3*512 + tau]*iv;
  }
  float pos = (float)t * (127.0f/65535.0f);
  int lo = (int)floorf(pos);
  int hi = imin(lo + 1, 127);
  float w = pos - (float)lo;
  const float* nds = nd_small + e*512;
  float acc = 0.f;
  acc += s0*(nds[0*128 + lo]*(1.0f - w) + nds[0*128 + hi]*w);
  acc += s1*(nds[1*128 + lo]*(1.0f - w) + nds[1*128 + hi]*w);
  acc += s2*(nds[2*128 + lo]*(1.0f - w) + nds[2*128 + hi]*w);
  acc += s3*(nds[3*128 + lo]*(1.0f - w) + nds[3*128 + hi]*w);
  filtered[e*FLEN + t] = acc;
}

// ---------------- rooms (fallback path only) ----------------
__global__ __launch_bounds__(256) void rooms_kernel(
    const float* __restrict__ verbs, const float* __restrict__ rho,
    float* __restrict__ rooms)
{
  const int t = blockIdx.x*256 + threadIdx.x;
  const int e = blockIdx.y;
  float acc = 0.f;
  #pragma unroll
  for (int v = 0; v < 16; v++) acc += rho[e*16 + v]*verbs[(size_t)v*NS + t];
  rooms[(size_t)e*NS + t] = acc;
}

// ---------------- rare-path waveform: exact f64 replication of numpy ----------------
__device__ __noinline__ float slow_wave(int wf, int n, int i){
  const double stp = 3980.0 / 255.0;
  double fi = (i == 255) ? 4000.0 : __dadd_rn(__dmul_rn((double)i, stp), 20.0);
  double tn = (double)n / 22050.0;
  double ph = __dmul_rn(fi, tn);
  double fr = ph - trunc(ph);
  if (wf == 1) return (float)(2.0*fr - 1.0);
  if (wf == 3){ double sw = 2.0*fr - 1.0; return (float)(2.0*fabs(sw) - 1.0); }
  if (fr == 0.0 || fr == 0.5){
    if (ph == 0.0) return 0.0f;
    double sv = sin(__dmul_rn(6.283185307179586, ph));
    return (sv > 0.0) ? 1.0f : ((sv < 0.0) ? -1.0f : 0.0f);
  }
  return (fr < 0.5) ? 1.0f : -1.0f;
}

// generate 8 wave values (rows i0..i0+7, column n) and split to bf16 hi/lo
__device__ __forceinline__ void gen8(int wf, int n, int i0,
                                     unsigned m_in, unsigned stepn,
                                     U8& bh, U8& bl)
{
  unsigned m = m_in;
  #pragma unroll
  for (int j = 0; j < 8; j++){
    float fr = (float)m * (1.0f/5622750.0f);
    float val;
    bool rare;
    if (wf == 0){
      asm("v_sin_f32 %0, %1" : "=v"(val) : "v"(fr));
      rare = false;
    } else if (wf == 1){
      val = fmaf(fr, 2.0f, -1.0f);
      rare = (m == 0u);
    } else if (wf == 2){
      val = (m < GDH) ? 1.0f : -1.0f;
      rare = (m == 0u) || (m == GDH);
    } else {
      val = fmaf(fabsf(fmaf(fr, 2.0f, -1.0f)), 2.0f, -1.0f);
      rare = (m == 0u);
    }
    if (rare) val = slow_wave(wf, n, i0 + j);
    unsigned ub = __float_as_uint(val);
    unsigned th = ub & 0xFFFF0000u;
    float lres = val - __uint_as_float(th);
    bh.u[j] = (unsigned short)(ub >> 16);
    bl.u[j] = (unsigned short)(__float_as_uint(lres) >> 16);
    m += stepn;
    if (m >= GD) m -= GD;
  }
}

// ---------------- MFMA GEMM v3: 512 thr / 8 waves, one 16-col tile per wave ----
__global__ __launch_bounds__(512, 2) void gemm_dres_gen3_kernel(
    const unsigned short* __restrict__ Ahi,
    const float* __restrict__ w_small, const float* __restrict__ d_small,
    float* __restrict__ dres)
{
  __shared__ __align__(16) unsigned short Abuf[2][8192];   // 2 x 16 KB

  const int tid = threadIdx.x;
  const int l = tid & 63, w = tid >> 6;   // 8 waves
  const int g = l >> 4, c = l & 15;
  const int n = blockIdx.x*128 + w*16 + c;

  f32x4 acc[16];
  #pragma unroll
  for (int m = 0; m < 16; m++) acc[m] = (f32x4){0.f,0.f,0.f,0.f};

  const unsigned stepn = (3980u*(unsigned)n) % GD;
  const unsigned s32 = (32u*stepn) % GD;
  const unsigned K0g = 3980u*(unsigned)(g*8) + 5100u;
  const unsigned m0 = (unsigned)(((unsigned long long)(unsigned)n * K0g) % GD);
  unsigned mseg = m0;

  typedef const __attribute__((address_space(1))) void GV;
  typedef __attribute__((address_space(3))) void LV;

  #pragma unroll
  for (int q = 0; q < 2; q++){
    const unsigned short* src = Ahi + (size_t)q*4096 + (size_t)w*512 + (size_t)l*8;
    __builtin_amdgcn_global_load_lds((GV*)src, (LV*)&Abuf[0][q*4096 + w*512], 16, 0, 0);
  }
  __syncthreads();

  for (int k0 = 0; k0 < 1024; k0 += 32){
    const int cur = (k0 >> 5) & 1, nxt = cur ^ 1;
    const int wf = k0 >> 8;
    if ((k0 & 255) == 0) mseg = m0;

    if (k0 + 32 < 1024){
      const size_t slice = (size_t)((k0 + 32) >> 5) * 8192;
      #pragma unroll
      for (int q = 0; q < 2; q++){
        const unsigned short* src = Ahi + slice + (size_t)q*4096 + (size_t)w*512 + (size_t)l*8;
        __builtin_amdgcn_global_load_lds((GV*)src, (LV*)&Abuf[nxt][q*4096 + w*512], 16, 0, 0);
      }
    }

    const int i0 = (k0 & 255) + g*8;
    U8 bh, bl;
    gen8(wf, n, i0, mseg, stepn, bh, bl);
    mseg += s32; if (mseg >= GD) mseg -= GD;

    #pragma unroll
    for (int m = 0; m < 16; m++){
      U8 ah;
      ah.q = *(const uint4*)&Abuf[cur][g*2048 + (m*16 + c)*8];
      acc[m] = __builtin_amdgcn_mfma_f32_16x16x32_bf16(ah.v, bh.v, acc[m], 0, 0, 0);
      acc[m] = __builtin_amdgcn_mfma_f32_16x16x32_bf16(ah.v, bl.v, acc[m], 0, 0, 0);
    }
    __syncthreads();
  }

  const int t = n;
  float pos = (float)t * (127.0f/65535.0f);
  int lo = (int)floorf(pos);
  int hi = imin(lo + 1, 127);
  float fr = pos - (float)lo;
  #pragma unroll
  for (int m = 0; m < 16; m++){
    int e = 2*m + (g >> 1);
    float s = 0.f;
    #pragma unroll
    for (int jj = 0; jj < 4; jj++){
      int i = (g & 1)*4 + jj;
      const float* wr = w_small + (size_t)(e*8 + i)*128;
      float wi = wr[lo]*(1.0f - fr) + wr[hi]*fr;
      s += wi * acc[m][jj];
    }
    s += __shfl_xor(s, 16);
    if ((g & 1) == 0){
      float de = d_small[e*128 + lo]*(1.0f - fr) + d_small[e*128 + hi]*fr;
      dres[(size_t)e*NS + t] = de * s;
    }
  }
}

// ---------------- fallback f32 GEMM ----------------
__global__ __launch_bounds__(256) void gemm_dres_kernel(
    const float* __restrict__ P2, const float* __restrict__ waves,
    const float* __restrict__ w_small, const float* __restrict__ d_small,
    float* __restrict__ dres)
{
  __shared__ __align__(16) float At[32][256];
  __shared__ __align__(16) float Bt[32][64];
  const int tid = threadIdx.x;
  const int tx = tid & 15, ty = tid >> 4;
  const int n0 = blockIdx.x * 64;
  float acc[16][4];
  #pragma unroll
  for (int a = 0; a < 16; a++)
    #pragma unroll
    for (int b = 0; b < 4; b++) acc[a][b] = 0.f;

  for (int k0 = 0; k0 < 1024; k0 += 32){
    {
      const float4* src = (const float4*)(P2 + (size_t)tid*1024 + k0);
      #pragma unroll
      for (int q = 0; q < 8; q++){
        float4 v = src[q];
        At[q*4 + 0][tid] = v.x; At[q*4 + 1][tid] = v.y;
        At[q*4 + 2][tid] = v.z; At[q*4 + 3][tid] = v.w;
      }
    }
    {
      int c  = tid & 15;
      int kr = tid >> 4;
      *(float4*)&Bt[kr][c*4]      = *((const float4*)(waves + (size_t)(k0 + kr)*NS + n0) + c);
      *(float4*)&Bt[kr + 16][c*4] = *((const float4*)(waves + (size_t)(k0 + kr + 16)*NS + n0) + c);
    }
    __syncthreads();
    #pragma unroll 4
    for (int k = 0; k < 32; k++){
      float a[16];
      *(float4*)&a[0]  = *(const float4*)&At[k][ty*16 + 0];
      *(float4*)&a[4]  = *(const float4*)&At[k][ty*16 + 4];
      *(float4*)&a[8]  = *(const float4*)&At[k][ty*16 + 8];
      *(float4*)&a[12] = *(const float4*)&At[k][ty*16 + 12];
      float4 b = *(const float4*)&Bt[k][tx*4];
      #pragma unroll
      for (int mi = 0; mi < 16; mi++){
        acc[mi][0] += a[mi]*b.x;
        acc[mi][1] += a[mi]*b.y;
        acc[mi][2] += a[mi]*b.z;
        acc[mi][3] += a[mi]*b.w;
      }
    }
    __syncthreads();
  }

  #pragma unroll
  for (int ni = 0; ni < 4; ni++){
    int t = n0 + tx*4 + ni;
    float pos = (float)t * (127.0f/65535.0f);
    int lo = (int)floorf(pos);
    int hi = imin(lo + 1, 127);
    float w = pos - (float)lo;
    #pragma unroll
    for (int ev2 = 0; ev2 < 2; ev2++){
      int e = ty*2 + ev2;
      float de = d_small[e*128 + lo]*(1.0f - w) + d_small[e*128 + hi]*w;
      float s = 0.f;
      #pragma unroll
      for (int i = 0; i < 8; i++){
        const float* wrow = w_small + (size_t)(e*8 + i)*128;
        float wi = wrow[lo]*(1.0f - w) + wrow[hi]*w;
        s += wi * acc[ev2*8 + i][ni];
      }
      dres[(size_t)e*NS + t] = de * s;
    }
  }
}

// ================= FFT machinery (four-step, N = 131072 = 256 x 512) =================
// Spectrum layout: S[k2*256 + k1], true k = k2 + 512*k1.
// Mixed-radix Stockham: radix-2 first (512 only, twiddle-free), then radix-4.

template<int L, int Ns, int DIR>
__device__ __forceinline__ void r4_stage(const float* __restrict__ xr,
                                         const float* __restrict__ xi,
                                         float* __restrict__ yr,
                                         float* __restrict__ yi)
{
  const int tid = threadIdx.x;
  constexpr int BPR = L/4;
  #pragma unroll
  for (int q = 0; q < 4; q++){
    int bf = tid + 256*q;
    int r  = bf / BPR;
    int j  = bf % BPR;
    int sw = (r & 7) << 2;
    int jm = j & (Ns - 1);
    float2 w1 = twid((float)jm * (1.0f/(4.0f*(float)Ns)));
    if (DIR < 0) w1.y = -w1.y;
    float2 w2 = make_float2(w1.x*w1.x - w1.y*w1.y, 2.0f*w1.x*w1.y);
    float2 w3 = make_float2(w2.x*w1.x - w2.y*w1.y, w2.x*w1.y + w2.y*w1.x);
    const float* xrr = xr + r*L;
    const float* xir = xi + r*L;
    float ar  = xrr[j ^ sw],           ai  = xir[j ^ sw];
    float b0r = xrr[(j+BPR) ^ sw],     b0i = xir[(j+BPR) ^ sw];
    float c0r = xrr[(j+2*BPR) ^ sw],   c0i = xir[(j+2*BPR) ^ sw];
    float d0r = xrr[(j+3*BPR) ^ sw],   d0i = xir[(j+3*BPR) ^ sw];
    float br = b0r*w1.x - b0i*w1.y,  bi = b0r*w1.y + b0i*w1.x;
    float cr = c0r*w2.x - c0i*w2.y,  ci = c0r*w2.y + c0i*w2.x;
    float dr = d0r*w3.x - d0i*w3.y,  di = d0r*w3.y + d0i*w3.x;
    float apc_r = ar + cr, apc_i = ai + ci;
    float amc_r = ar - cr, amc_i = ai - ci;
    float bpd_r = br + dr, bpd_i = bi + di;
    float bmd_r = br - dr, bmd_i = bi - di;
    int dbase = ((j - jm) << 2) + jm;
    float* yrr = yr + r*L;
    float* yir = yi + r*L;
    yrr[dbase ^ sw]          = apc_r + bpd_r;
    yir[dbase ^ sw]          = apc_i + bpd_i;
    yrr[(dbase + 2*Ns) ^ sw] = apc_r - bpd_r;
    yir[(dbase + 2*Ns) ^ sw] = apc_i - bpd_i;
    if (DIR > 0){
      yrr[(dbase + Ns) ^ sw]   = amc_r + bmd_i;
      yir[(dbase + Ns) ^ sw]   = amc_i - bmd_r;
      yrr[(dbase + 3*Ns) ^ sw] = amc_r - bmd_i;
      yir[(dbase + 3*Ns) ^ sw] = amc_i + bmd_r;
    } else {
      yrr[(dbase + Ns) ^ sw]   = amc_r - bmd_i;
      yir[(dbase + Ns) ^ sw]   = amc_i + bmd_r;
      yrr[(dbase + 3*Ns) ^ sw] = amc_r + bmd_i;
      yir[(dbase + 3*Ns) ^ sw] = amc_i - bmd_r;
    }
  }
}

#define FFT_SWAP { float* t_; t_=ra;ra=rb;rb=t_; t_=ia;ia=ib;ib=t_; }

template<int L, int DIR>
__device__ __forceinline__ void fft_core4(float*& ra, float*& ia, float*& rb, float*& ib)
{
  const int tid = threadIdx.x;
  if (L == 512){
    __syncthreads();
    #pragma unroll
    for (int q = 0; q < 8; q++){
      int bf = tid + 256*q;
      int r = bf >> 8, j = bf & 255;
      int sw = (r & 7) << 2;
      float ar = ra[r*512 + (j ^ sw)],        ai = ia[r*512 + (j ^ sw)];
      float br = ra[r*512 + ((j+256) ^ sw)],  bi = ia[r*512 + ((j+256) ^ sw)];
      rb[r*512 + ((2*j) ^ sw)]   = ar + br;
      ib[r*512 + ((2*j) ^ sw)]   = ai + bi;
      rb[r*512 + ((2*j+1) ^ sw)] = ar - br;
      ib[r*512 + ((2*j+1) ^ sw)] = ai - bi;
    }
    FFT_SWAP
    __syncthreads(); r4_stage<512,   2, DIR>(ra, ia, rb, ib); FFT_SWAP
    __syncthreads(); r4_stage<512,   8, DIR>(ra, ia, rb, ib); FFT_SWAP
    __syncthreads(); r4_stage<512,  32, DIR>(ra, ia, rb, ib); FFT_SWAP
    __syncthreads(); r4_stage<512, 128, DIR>(ra, ia, rb, ib); FFT_SWAP
  } else {
    __syncthreads(); r4_stage<256,   1, DIR>(ra, ia, rb, ib); FFT_SWAP
    __syncthreads(); r4_stage<256,   4, DIR>(ra, ia, rb, ib); FFT_SWAP
    __syncthreads(); r4_stage<256,  16, DIR>(ra, ia, rb, ib); FFT_SWAP
    __syncthreads(); r4_stage<256,  64, DIR>(ra, ia, rb, ib); FFT_SWAP
  }
  __syncthreads();
}

// F1-merged: z=0 filtered pair, z=1 dres pair, z=2 rooms pair (inline from verbs).
__global__ __launch_bounds__(256) void fwd512_all_kernel(
    const float* __restrict__ filt, const float* __restrict__ dresv,
    const float* __restrict__ verbs, const float* __restrict__ rho,
    float2* __restrict__ Xf, float2* __restrict__ Xd, float2* __restrict__ Xr)
{
  __shared__ float reA[4096], imA[4096], reB[4096], imB[4096];
  __shared__ float srho[32];
  const int e = blockIdx.y, t1 = blockIdx.x*8, tid = threadIdx.x;
  const int z = blockIdx.z;
  if (z == 2){
    if (tid < 32) srho[tid] = rho[(2*e)*16 + tid];
    __syncthreads();
  }
  #pragma unroll
  for (int q = 0; q < 4; q++){
    int flat = tid + 256*q;
    int n2 = flat >> 1;
    int rb = (flat & 1)*4;
    int nb = t1 + rb + 256*n2;
    float4 va = make_float4(0.f,0.f,0.f,0.f);
    float4 vb = make_float4(0.f,0.f,0.f,0.f);
    if (z == 0){
      if (nb < FLEN){
        va = *(const float4*)(filt + (size_t)e*2*FLEN + nb);
        vb = *(const float4*)(filt + (size_t)e*2*FLEN + FLEN + nb);
      }
    } else if (z == 1){
      if (nb < NS){
        va = *(const float4*)(dresv + (size_t)e*2*NS + nb);
        vb = *(const float4*)(dresv + (size_t)e*2*NS + NS + nb);
      }
    } else {
      if (nb < NS){
        #pragma unroll
        for (int v = 0; v < 16; v++){
          float4 w4 = *(const float4*)(verbs + (size_t)v*NS + nb);
          float r0 = srho[v], r1 = srho[16 + v];
          va.x += r0*w4.x; va.y += r0*w4.y; va.z += r0*w4.z; va.w += r0*w4.w;
          vb.x += r1*w4.x; vb.y += r1*w4.y; vb.z += r1*w4.z; vb.w += r1*w4.w;
        }
      }
    }
    #pragma unroll
    for (int j = 0; j < 4; j++){
      int r = rb + j;
      int sw = (r & 7) << 2;
      reA[r*512 + (n2 ^ sw)] = (&va.x)[j];
      imA[r*512 + (n2 ^ sw)] = (&vb.x)[j];
    }
  }
  float *ra = reA, *ia = imA, *rb2 = reB, *ib2 = imB;
  fft_core4<512, +1>(ra, ia, rb2, ib2);
  float2* Bt = (z == 0) ? Xf : (z == 1) ? Xd : Xr;
  float2* dst = Bt + ((size_t)e << 17);
  #pragma unroll
  for (int q = 0; q < 16; q++){
    int idx = tid + 256*q;
    int r = idx & 7, k2 = idx >> 3;
    int n1 = t1 + r;
    int sw = (r & 7) << 2;
    float xr = ra[r*512 + (k2 ^ sw)];
    float xi = ia[r*512 + (k2 ^ sw)];
    float2 w = twid((float)(n1*k2) * (1.0f/131072.0f));
    dst[k2*256 + n1] = make_float2(xr*w.x - xi*w.y, xr*w.y + xi*w.x);
  }
}

// F2: in-place FFT_256 along contiguous rows. z selects spectrum (tri) or single.
__device__ __forceinline__ void fwd256_body(float2* __restrict__ S)
{
  __shared__ float reA[4096], imA[4096], reB[4096], imB[4096];
  const int e = blockIdx.y, K0 = blockIdx.x*16, tid = threadIdx.x;
  float2* base = S + ((size_t)e << 17) + (size_t)K0*256;
  #pragma unroll
  for (int q = 0; q < 16; q++){
    int idx = tid + 256*q;
    int r = idx >> 8, col = idx & 255;
    float2 v = base[r*256 + col];
    int sw = (r & 7) << 2;
    reA[r*256 + (col ^ sw)] = v.x;
    imA[r*256 + (col ^ sw)] = v.y;
  }
  float *ra = reA, *ia = imA, *rb = reB, *ib = imB;
  fft_core4<256, +1>(ra, ia, rb, ib);
  #pragma unroll
  for (int q = 0; q < 16; q++){
    int idx = tid + 256*q;
    int r = idx >> 8, col = idx & 255;
    int sw = (r & 7) << 2;
    base[r*256 + col] = make_float2(ra[r*256 + (col ^ sw)], ia[r*256 + (col ^ sw)]);
  }
}

__global__ __launch_bounds__(256) void fwd256_tri_kernel(
    float2* __restrict__ Xf, float2* __restrict__ Xd, float2* __restrict__ Xr)
{
  float2* S = (blockIdx.z == 0) ? Xf : (blockIdx.z == 1) ? Xd : Xr;
  fwd256_body(S);
}

__global__ __launch_bounds__(256) void fwd256_kernel(float2* __restrict__ S)
{
  fwd256_body(S);
}

// I1: Hermitian-unpack TWO packed spectra, per-event product, repack
// Y = P0 + i*P1, inverse FFT_256, conj twiddle, write Ut[n1*512 + k2].
__global__ __launch_bounds__(256) void inv256_mul2_kernel(
    const float2* __restrict__ ZA, const float2* __restrict__ ZB,
    float2* __restrict__ Ut)
{
  __shared__ float reA[4096], imA[4096], reB[4096], imB[4096];
  const int e = blockIdx.y, K0 = blockIdx.x*16, tid = threadIdx.x;
  const float2* Za = ZA + ((size_t)e << 17);
  const float2* Zb = ZB + ((size_t)e << 17);
  #pragma unroll
  for (int q = 0; q < 16; q++){
    int idx = tid + 256*q;
    int r = idx >> 8, col = idx & 255;
    int k2 = K0 + r;
    int k2p, k1p;
    if (k2 == 0){ k2p = 0; k1p = (256 - col) & 255; }
    else        { k2p = 512 - k2; k1p = 255 - col; }
    float2 za  = Za[(size_t)k2*256 + col];
    float2 zap = Za[(size_t)k2p*256 + k1p];
    float2 zb  = Zb[(size_t)k2*256 + col];
    float2 zbp = Zb[(size_t)k2p*256 + k1p];
    float a0r = 0.5f*(za.x + zap.x), a0i = 0.5f*(za.y - zap.y);
    float a1r = 0.5f*(za.y + zap.y), a1i = 0.5f*(zap.x - za.x);
    float b0r = 0.5f*(zb.x + zbp.x), b0i = 0.5f*(zb.y - zbp.y);
    float b1r = 0.5f*(zb.y + zbp.y), b1i = 0.5f*(zbp.x - zb.x);
    float p0r = a0r*b0r - a0i*b0i, p0i = a0r*b0i + a0i*b0r;
    float p1r = a1r*b1r - a1i*b1i, p1i = a1r*b1i + a1i*b1r;
    int sw = (r & 7) << 2;
    reA[r*256 + (col ^ sw)] = p0r - p1i;
    imA[r*256 + (col ^ sw)] = p0i + p1r;
  }
  float *ra = reA, *ia = imA, *rb = reB, *ib = imB;
  fft_core4<256, -1>(ra, ia, rb, ib);
  float2* dst = Ut + ((size_t)e << 17);
  #pragma unroll
  for (int q = 0; q < 16; q++){
    int idx = tid + 256*q;
    int r = idx & 15, n1 = idx >> 4;
    int k2 = K0 + r;
    int sw = (r & 7) << 2;
    float xr = ra[r*256 + (n1 ^ sw)];
    float xi = ia[r*256 + (n1 ^ sw)];
    float2 w = twid((float)(n1*k2) * (1.0f/131072.0f));   // conj applied
    dst[n1*512 + k2] = make_float2(xr*w.x + xi*w.y, xi*w.x - xr*w.y);
  }
}

// I2+F1 fused: inverse FFT_512 -> packed conv pair; write CONV;
// truncate (n2>=256 -> 0) and forward FFT_512 + twiddle -> Bt.
__global__ __launch_bounds__(256) void inv512_fwdpack2_kernel(
    const float2* __restrict__ Ut, float* __restrict__ conv,
    float2* __restrict__ Bt)
{
  __shared__ float reA[4096], imA[4096], reB[4096], imB[4096];
  const int e = blockIdx.y, t1 = blockIdx.x*8, tid = threadIdx.x;
  const float2* base = Ut + ((size_t)e << 17) + (size_t)t1*512;
  #pragma unroll
  for (int q = 0; q < 16; q++){
    int idx = tid + 256*q;
    int r = idx >> 9, col = idx & 511;
    float2 v = base[r*512 + col];
    int sw = (r & 7) << 2;
    reA[r*512 + (col ^ sw)] = v.x;
    imA[r*512 + (col ^ sw)] = v.y;
  }
  float *ra = reA, *ia = imA, *rb = reB, *ib = imB;
  fft_core4<512, -1>(ra, ia, rb, ib);
  const float s = 1.0f/131072.0f;
  #pragma unroll
  for (int q = 0; q < 16; q++){
    int idx = tid + 256*q;
    int r = idx & 7, n2 = idx >> 3;
    int sw = (r & 7) << 2;
    int pos = r*512 + (n2 ^ sw);
    if (n2 < 256){
      int n = (t1 + r) + 256*n2;
      float y0 = ra[pos]*s, y1 = ia[pos]*s;
      conv[(size_t)(2*e)*NS + n]     = y0;
      conv[(size_t)(2*e + 1)*NS + n] = y1;
      rb[pos] = y0; ib[pos] = y1;
    } else {
      rb[pos] = 0.f; ib[pos] = 0.f;
    }
  }
  __syncthreads();
  float *r2 = rb, *i2 = ib, *r3 = ra, *i3 = ia;
  fft_core4<512, +1>(r2, i2, r3, i3);
  float2* dst = Bt + ((size_t)e << 17);
  #pragma unroll
  for (int q = 0; q < 16; q++){
    int idx = tid + 256*q;
    int r = idx & 7, k2 = idx >> 3;
    int n1 = t1 + r;
    int sw = (r & 7) << 2;
    float xr = r2[r*512 + (k2 ^ sw)];
    float xi = i2[r*512 + (k2 ^ sw)];
    float2 w = twid((float)(n1*k2) * (1.0f/131072.0f));
    dst[k2*256 + n1] = make_float2(xr*w.x - xi*w.y, xr*w.y + xi*w.x);
  }
}

// I2-final: inverse FFT_512 -> packed wet pair; mix with conv, write out.
__global__ __launch_bounds__(256) void inv512_mix2_kernel(
    const float2* __restrict__ Ut, const float* __restrict__ conv,
    const float* __restrict__ scal, float* __restrict__ dst)
{
  __shared__ float reA[4096], imA[4096], reB[4096], imB[4096];
  const int e = blockIdx.y, t1 = blockIdx.x*8, tid = threadIdx.x;
  const float2* base = Ut + ((size_t)e << 17) + (size_t)t1*512;
  #pragma unroll
  for (int q = 0; q < 16; q++){
    int idx = tid + 256*q;
    int r = idx >> 9, col = idx & 511;
    float2 v = base[r*512 + col];
    int sw = (r & 7) << 2;
    reA[r*512 + (col ^ sw)] = v.x;
    imA[r*512 + (col ^ sw)] = v.y;
  }
  float *ra = reA, *ia = imA, *rb = reB, *ib = imB;
  fft_core4<512, -1>(ra, ia, rb, ib);
  const float s = 1.0f/131072.0f;
  const int e0 = 2*e, e1 = 2*e + 1;
  float m00 = scal[e0*4 + 0], m10 = scal[e0*4 + 1], a20 = scal[e0*4 + 2];
  float m01 = scal[e1*4 + 0], m11 = scal[e1*4 + 1], a21 = scal[e1*4 + 2];
  #pragma unroll
  for (int q = 0; q < 8; q++){
    int idx = tid + 256*q;
    int r = idx & 7, n2 = idx >> 3;
    int n = (t1 + r) + 256*n2;
    int sw = (r & 7) << 2;
    int pos = r*512 + (n2 ^ sw);
    float w0 = ra[pos]*s, w1 = ia[pos]*s;
    size_t g0 = (size_t)e0*NS + n, g1 = (size_t)e1*NS + n;
    dst[g0] = (m00*conv[g0] + m10*w0)*a20;
    dst[g1] = (m01*conv[g1] + m11*w1)*a21;
  }
}

// ---------------- fallback: direct causal conv ----------------
template<int MODE>
__global__ __launch_bounds__(256) void tconv_kernel(
    const float* __restrict__ sig, int sig_len, int sig_stride,
    const float* __restrict__ go, const float* __restrict__ scal,
    float* __restrict__ dst)
{
  __shared__ __align__(16) float cs[2048];
  __shared__ __align__(16) float rs[4104];
  const int e = blockIdx.y;
  const int t0 = blockIdx.x * 2048;
  const int tid = threadIdx.x;
  const int tb = tid * 8;
  float acc[8] = {0,0,0,0,0,0,0,0};
  const int kcap = imin(sig_len, t0 + 2048);
  for (int c0 = 0; c0 < kcap; c0 += 2048){
    __syncthreads();
    for (int idx = tid; idx < 2048; idx += 256){
      int gsi = c0 + idx;
      cs[idx] = (gsi < sig_len) ? sig[(size_t)e*sig_stride + gsi] : 0.f;
    }
    const int rb = t0 - c0 - 2056;
    for (int idx = tid; idx < 4104; idx += 256){
      int g = rb + idx;
      rs[idx] = (g >= 0 && g < NS) ? go[(size_t)e*NS + g] : 0.f;
    }
    __syncthreads();
    float W[12];
    int P = tb + 2056;
    *(float4*)&W[0] = *(const float4*)&rs[P - 4];
    *(float4*)&W[4] = *(const float4*)&rs[P];
    *(float4*)&W[8] = *(const float4*)&rs[P + 4];
    for (int u = 0; u < 512; u++){
      float4 f4 = *(const float4*)&cs[4*u];
      #pragma unroll
      for (int j = 0; j < 8; j++){
        acc[j] += f4.x*W[4 + j];
        acc[j] += f4.y*W[3 + j];
        acc[j] += f4.z*W[2 + j];
        acc[j] += f4.w*W[1 + j];
      }
      #pragma unroll
      for (int x2 = 11; x2 >= 4; x2--) W[x2] = W[x2 - 4];
      P -= 4;
      *(float4*)&W[0] = *(const float4*)&rs[P - 4];
    }
  }
  if (MODE == 0){
    #pragma unroll
    for (int j = 0; j < 8; j++) dst[(size_t)e*NS + t0 + tb + j] = acc[j];
  } else {
    float m0 = scal[e*4 + 0], m1 = scal[e*4 + 1], a2 = scal[e*4 + 2];
    #pragma unroll
    for (int j = 0; j < 8; j++){
      size_t gi = (size_t)e*NS + t0 + tb + j;
      dst[gi] = (m0*sig[gi] + m1*acc[j]) * a2;
    }
  }
}

// ---------------- launcher ----------------
extern "C" void kernel_launch(void* const* d_in, const int* in_sizes, int n_in,
                              void* d_out, int out_size, void* d_ws, size_t ws_size,
                              hipStream_t stream)
{
  (void)in_sizes; (void)n_in; (void)out_size;
  const float* res_sel     = (const float*)d_in[0];
  const float* noise_sel   = (const float*)d_in[1];
  const float* env_sel     = (const float*)d_in[2];
  const float* dec_sel     = (const float*)d_in[3];
  const float* def_sel     = (const float*)d_in[4];
  const float* ndef_sel    = (const float*)d_in[5];
  const float* mix_sel     = (const float*)d_in[6];
  const float* room_sel    = (const float*)d_in[7];
  const float* amp         = (const float*)d_in[8];
  const float* r_items     = (const float*)d_in[9];
  const float* n_items     = (const float*)d_in[10];
  const float* e_items     = (const float*)d_in[11];
  const float* d_items     = (const float*)d_in[12];
  const float* warp_items  = (const float*)d_in[13];
  const float* nwarp_items = (const float*)d_in[14];
  const float* verbs       = (const float*)d_in[15];
  const float* waves       = (const float*)d_in[16];
  float* ws  = (float*)d_ws;
  float* out = (float*)d_out;

  const bool big_ws = ws_size >= (size_t)O_END * sizeof(float);

  if (big_ws) {
    weights_kernel<<<dim3(NEV), dim3(64), 0, stream>>>(
        noise_sel, env_sel, dec_sel, def_sel, ndef_sel, mix_sel, room_sel, amp,
        d_items, ws + O_SWE, ws + O_SWN, ws + O_SWD, ws + O_SWND,
        ws + O_DSM, ws + O_SCAL, ws + O_RHO);
    lookups_kernel<<<dim3(224), dim3(256), 0, stream>>>(
        ws + O_SWE, ws + O_SWN, ws + O_SWD, ws + O_SWND,
        e_items, n_items, warp_items, nwarp_items,
        ws + O_ENV_SMALL, ws + O_NFIL, ws + O_WSM, ws + O_ND);

    unsigned short* Ahi = (unsigned short*)(ws + O_X);
    p2s_kernel<<<dim3(4, 32), dim3(256), 0, stream>>>(res_sel, r_items, Ahi);

    env_noise_kernel<<<dim3(1024), dim3(256), 0, stream>>>(ws + O_ENV_SMALL, ws + O_IMP);
    filt_kernel<<<dim3(34, NEV), dim3(256), 0, stream>>>(ws + O_NFIL, ws + O_IMP, ws + O_ND, ws + O_FILT);

    gemm_dres_gen3_kernel<<<dim3(512), dim3(512), 0, stream>>>(
        Ahi, ws + O_WSM, ws + O_DSM, ws + O_DRES);

    // ---- event-pair-packed FFT convolution ----
    float2* Xf = (float2*)(ws + O_X);
    float2* Xd = (float2*)(ws + O_X + 4194304);
    float2* Xr = (float2*)(ws + O_Y);
    float2* Uc = (float2*)(ws + O_Y + 4194304);
    float2* Xc = Xf;
    float2* Uw = Xd;

    fwd512_all_kernel<<<dim3(32, 16, 3), dim3(256), 0, stream>>>(
        ws + O_FILT, ws + O_DRES, verbs, ws + O_RHO, Xf, Xd, Xr);
    fwd256_tri_kernel<<<dim3(32, 16, 3), dim3(256), 0, stream>>>(Xf, Xd, Xr);

    inv256_mul2_kernel<<<dim3(32, 16), dim3(256), 0, stream>>>(Xf, Xd, Uc);
    inv512_fwdpack2_kernel<<<dim3(32, 16), dim3(256), 0, stream>>>(Uc, ws + O_CONV, Xc);
    fwd256_kernel<<<dim3(32, 16), dim3(256), 0, stream>>>(Xc);
    inv256_mul2_kernel<<<dim3(32, 16), dim3(256), 0, stream>>>(Xc, Xr, Uw);
    inv512_mix2_kernel<<<dim3(32, 16), dim3(256), 0, stream>>>(
        Uw, ws + O_CONV, ws + O_SCAL, out);
  } else {
    // fallback: legacy prep + f32 GEMM + direct time-domain conv
    prep_kernel<<<dim3(NEV), dim3(64), 0, stream>>>(
        noise_sel, env_sel, dec_sel, def_sel, ndef_sel, mix_sel, room_sel, amp,
        n_items, e_items, d_items, warp_items, nwarp_items,
        ws + O_ENV_SMALL, ws + O_NFIL, ws + O_ND, ws + O_WSM,
        ws + O_DSM, ws + O_SCAL, ws + O_RHO);
    p1_softmax_kernel<<<dim3(256), dim3(256), 0, stream>>>(res_sel, ws + O_P1);
    p2_kernel<<<dim3(4, 32), dim3(256), 0, stream>>>(ws + O_P1, r_items, ws + O_P2);
    env_noise_kernel<<<dim3(1024), dim3(256), 0, stream>>>(ws + O_ENV_SMALL, ws + O_IMP);
    filt_kernel<<<dim3(34, NEV), dim3(256), 0, stream>>>(ws + O_NFIL, ws + O_IMP, ws + O_ND, ws + O_FILT);
    rooms_kernel<<<dim3(256, NEV), dim3(256), 0, stream>>>(verbs, ws + O_RHO, ws + O_ROOMS);
    gemm_dres_kernel<<<dim3(1024), dim3(256), 0, stream>>>(
        ws + O_P2, waves, ws + O_WSM, ws + O_DSM, ws + O_DRES);
    tconv_kernel<0><<<dim3(32, NEV), dim3(256), 0, stream>>>(
        ws + O_FILT, FLEN, FLEN, ws + O_DRES, (const float*)nullptr, ws + O_CONV);
    tconv_kernel<1><<<dim3(32, NEV), dim3(256), 0, stream>>>(
        ws + O_CONV, NS, NS, ws + O_ROOMS, ws + O_SCAL, out);
  }
}

// Round 11
// 349.615 us; speedup vs baseline: 1.6158x; 1.0188x over previous
//
#include <hip/hip_runtime.h>
#include <math.h>

// ---------------- problem sizes ----------------
#define NEV    32      // n_events
#define NS     65536   // n_samples
#define NFFT   131072  // 2*NS
#define ENVS   128
#define ENVF   8192
#define FSAMP2 512
#define NEXP2  4
#define FLEN   8704    // filtered support (8192 + 512 - 1 -> padded to 8704)
#define GD     5622750u   // 22050*255 (phase denominator)
#define GDH    2811375u   // GD/2

// ---------------- workspace layout (float offsets) ----------------
enum : size_t {
  O_ENV_SMALL = 0,         // 32*128
  O_NFIL      = 4096,      // 32*4*512
  O_IMP       = 69632,     // 32*8192
  O_ND        = 331776,    // 32*4*128
  O_WSM       = 348160,    // 32*8*128
  O_DSM       = 380928,    // 32*128
  O_SCAL      = 385024,    // 32*4  (m0, m1, amp^2)
  O_RHO       = 385152,    // 32*16
  O_P1        = 385664,    // 256*1024 (fallback only)
  O_P2        = 647808,    // 256*1024 (fallback only)
  O_FILT      = 909952,    // 32*8704
  O_DRES      = 1188480,   // 32*65536
  O_CONV      = 3285632,   // 32*65536 (fallback path only)
  O_ROOMS     = 5382784,   // 32*65536 (fallback path only)
  O_SWE       = 7479936,   // 32*64
  O_SWN       = 7482048,   // 32*4*64
  O_SWD       = 7490304,   // 32*64
  O_SWND      = 7492416,   // 32*32
  O_X         = 7742080,   // 8,388,608 floats: Xf | Xd  (16 pair-slices each)
  O_Y         = 16130688,  // 8,388,608 floats: Xr | Uc
  O_END       = 24519296,  // *4 bytes = 98,077,184
};

typedef float f32x4 __attribute__((ext_vector_type(4)));
typedef short bf16x8 __attribute__((ext_vector_type(8)));

union U8 { uint4 q; bf16x8 v; unsigned short u[8]; };

__device__ __forceinline__ int imin(int a, int b){ return a < b ? a : b; }

__device__ __forceinline__ float wsum(float v){
  #pragma unroll
  for (int o = 32; o > 0; o >>= 1) v += __shfl_xor(v, o);
  return v;
}
__device__ __forceinline__ float wmax(float v){
  #pragma unroll
  for (int o = 32; o > 0; o >>= 1) v = fmaxf(v, __shfl_xor(v, o));
  return v;
}

__device__ __forceinline__ unsigned short f2bf(float f){
  unsigned u = __float_as_uint(f);
  unsigned r = (u + 0x7fffu + ((u >> 16) & 1u)) >> 16;
  return (unsigned short)r;
}

// e^{-2*pi*i*frac} via HW trig (input in revolutions)
__device__ __forceinline__ float2 twid(float frac){
  float c, s;
  asm("v_cos_f32 %0, %1" : "=v"(c) : "v"(frac));
  asm("v_sin_f32 %0, %1" : "=v"(s) : "v"(frac));
  return make_float2(c, -s);
}

// ---------------- JAX threefry2x32, partitionable 32-bit path ----------------
__device__ __forceinline__ unsigned tf_rotl(unsigned x, int d){ return (x << d) | (x >> (32 - d)); }

__device__ unsigned threefry_bits(unsigned chi, unsigned clo){
  const unsigned k0 = 0u, k1 = 42u, k2 = 0x1BD11BDAu ^ 0u ^ 42u;
  unsigned x0 = chi + k0;
  unsigned x1 = clo + k1;
  x0 += x1; x1 = tf_rotl(x1,13); x1 ^= x0;
  x0 += x1; x1 = tf_rotl(x1,15); x1 ^= x0;
  x0 += x1; x1 = tf_rotl(x1,26); x1 ^= x0;
  x0 += x1; x1 = tf_rotl(x1, 6); x1 ^= x0;
  x0 += k1; x1 += k2 + 1u;
  x0 += x1; x1 = tf_rotl(x1,17); x1 ^= x0;
  x0 += x1; x1 = tf_rotl(x1,29); x1 ^= x0;
  x0 += x1; x1 = tf_rotl(x1,16); x1 ^= x0;
  x0 += x1; x1 = tf_rotl(x1,24); x1 ^= x0;
  x0 += k2; x1 += k0 + 2u;
  x0 += x1; x1 = tf_rotl(x1,13); x1 ^= x0;
  x0 += x1; x1 = tf_rotl(x1,15); x1 ^= x0;
  x0 += x1; x1 = tf_rotl(x1,26); x1 ^= x0;
  x0 += x1; x1 = tf_rotl(x1, 6); x1 ^= x0;
  x0 += k0; x1 += k1 + 3u;
  x0 += x1; x1 = tf_rotl(x1,17); x1 ^= x0;
  x0 += x1; x1 = tf_rotl(x1,29); x1 ^= x0;
  x0 += x1; x1 = tf_rotl(x1,16); x1 ^= x0;
  x0 += x1; x1 = tf_rotl(x1,24); x1 ^= x0;
  x0 += k1; x1 += k2 + 4u;
  x0 += x1; x1 = tf_rotl(x1,13); x1 ^= x0;
  x0 += x1; x1 = tf_rotl(x1,15); x1 ^= x0;
  x0 += x1; x1 = tf_rotl(x1,26); x1 ^= x0;
  x0 += x1; x1 = tf_rotl(x1, 6); x1 ^= x0;
  x0 += k2; x1 += k0 + 5u;
  return x0 ^ x1;
}

// ---------------- weights: softmaxes + decay/mix/room ----------------
__global__ __launch_bounds__(64) void weights_kernel(
    const float* __restrict__ noise_sel, const float* __restrict__ env_sel,
    const float* __restrict__ dec_sel,   const float* __restrict__ def_sel,
    const float* __restrict__ ndef_sel,  const float* __restrict__ mix_sel,
    const float* __restrict__ room_sel,  const float* __restrict__ amp,
    const float* __restrict__ d_items,
    float* __restrict__ swE, float* __restrict__ swN,
    float* __restrict__ swD, float* __restrict__ swND,
    float* __restrict__ d_small, float* __restrict__ scal,
    float* __restrict__ rho)
{
  const int e = blockIdx.x;
  const int l = threadIdx.x;

  {
    float x = env_sel[e*64 + l];
    float mx = wmax(x);
    float ex = expf(x - mx);
    float sm = wsum(ex);
    swE[e*64 + l] = ex / sm;
  }
  #pragma unroll
  for (int x4 = 0; x4 < NEXP2; x4++){
    float v = noise_sel[(e*NEXP2 + x4)*64 + l];
    float mxv = wmax(v);
    float exv = expf(v - mxv);
    float smv = wsum(exv);
    swN[(e*NEXP2 + x4)*64 + l] = exv / smv;
  }
  {
    float x = def_sel[e*64 + l];
    float mx = wmax(x);
    float ex = expf(x - mx);
    float sm = wsum(ex);
    swD[e*64 + l] = ex / sm;
  }
  {
    float x = (l < 32) ? ndef_sel[e*32 + l] : -1e30f;
    float mx = wmax(x);
    float ex = (l < 32) ? expf(x - mx) : 0.f;
    float sm = wsum(ex);
    if (l < 32) swND[e*32 + l] = ex / sm;
  }
  {
    float x = dec_sel[e*64 + l];
    float mx = wmax(x);
    float ex = expf(x - mx);
    float sm = wsum(ex);
    float wgt = ex / sm;
    float di = d_items[l];
    float dp = 0.5f + 0.5f*(1.0f/(1.0f + expf(-di)));
    float d0 = wsum(wgt*dp);
    float ld = logf(d0 + 1e-12f);
    #pragma unroll
    for (int c = 0; c < 2; c++){
      int f = l + 64*c;
      d_small[e*128 + f] = expf((float)(f+1)*ld);
    }
  }
  if (l == 0){
    float a = mix_sel[e*2 + 0], b = mix_sel[e*2 + 1];
    float mm = fmaxf(a, b);
    float ea = expf(a - mm), eb = expf(b - mm);
    float ss = ea + eb;
    scal[e*4 + 0] = ea/ss;
    scal[e*4 + 1] = eb/ss;
    float am = amp[e];
    scal[e*4 + 2] = am*am;
  }
  {
    float x = (l < 16) ? room_sel[e*16 + l] : -1e30f;
    float mx = wmax(x);
    float ex = (l < 16) ? expf(x - mx) : 0.f;
    float sm = wsum(ex);
    if (l < 16) rho[e*16 + l] = ex/sm;
  }
}

// ---------------- fused output-parallel lookups (envs | nfil | warp | nwarp) ----
__global__ __launch_bounds__(256) void lookups_kernel(
    const float* __restrict__ swE,  const float* __restrict__ swN,
    const float* __restrict__ swD,  const float* __restrict__ swND,
    const float* __restrict__ e_items, const float* __restrict__ n_items,
    const float* __restrict__ warp_items, const float* __restrict__ nwarp_items,
    float* __restrict__ env_small, float* __restrict__ nfil,
    float* __restrict__ w_small,   float* __restrict__ nd_small)
{
  __shared__ float sw[64];
  const int b = blockIdx.x;
  const int tid = threadIdx.x;

  if (b < 32){                                 // envs
    const int e = b, j = tid;
    if (j < 64) sw[j] = swE[e*64 + j];
    __syncthreads();
    if (j < 128){
      float acc = 0.f;
      #pragma unroll 8
      for (int k = 0; k < 64; k++){ float it = e_items[k*ENVS + j]; acc += sw[k]*(it*it); }
      env_small[e*ENVS + j] = acc;
    }
  } else if (b < 160){                         // nfil
    const int bb = b - 32;
    if (tid < 64) sw[tid] = swN[bb*64 + tid];
    __syncthreads();
    #pragma unroll
    for (int c = 0; c < 2; c++){
      int tau = tid + 256*c;
      float acc = 0.f;
      #pragma unroll 8
      for (int f = 0; f < 64; f++) acc += sw[f]*n_items[f*FSAMP2 + tau];
      float ham = 0.54f - 0.46f*cosf((6.2831853071795864769f * (float)tau) / 511.0f);
      nfil[bb*FSAMP2 + tau] = acc*ham;
    }
  } else if (b < 192){                         // warp
    const int e = b - 160, f = tid;
    if (f < 64) sw[f] = swD[e*64 + f];
    __syncthreads();
    if (f < 128){
      float acc[8] = {0,0,0,0,0,0,0,0};
      for (int k = 0; k < 64; k++){
        float wk = sw[k];
        const float* row = warp_items + (size_t)k*1024 + f;
        #pragma unroll
        for (int i = 0; i < 8; i++) acc[i] += wk*row[i*128];
      }
      float mx = -1e30f;
      #pragma unroll
      for (int i = 0; i < 8; i++) mx = fmaxf(mx, acc[i]);
      float ev[8]; float s = 0.f;
      #pragma unroll
      for (int i = 0; i < 8; i++){ ev[i] = expf(acc[i] - mx); s += ev[i]; }
      #pragma unroll
      for (int i = 0; i < 8; i++) w_small[(e*8 + i)*128 + f] = ev[i]/s;
    }
  } else {                                     // nwarp
    const int e = b - 192, f = tid;
    if (f < 32) sw[f] = swND[e*32 + f];
    __syncthreads();
    if (f < 128){
      float acc[4] = {0,0,0,0};
      for (int k = 0; k < 32; k++){
        float wk = sw[k];
        const float* row = nwarp_items + (size_t)k*512 + f;
        #pragma unroll
        for (int x = 0; x < 4; x++) acc[x] += wk*row[x*128];
      }
      float mx = -1e30f;
      #pragma unroll
      for (int x = 0; x < 4; x++) mx = fmaxf(mx, acc[x]);
      float ev[4]; float s = 0.f;
      #pragma unroll
      for (int x = 0; x < 4; x++){ ev[x] = expf(acc[x] - mx); s += ev[x]; }
      #pragma unroll
      for (int x = 0; x < 4; x++) nd_small[(e*4 + x)*128 + f] = ev[x]/s;
    }
  }
}

// ---------------- fused p1+p2+split: softmax(res_sel) @ r_items -> Ahi (bf16) ----
__global__ __launch_bounds__(256) void p2s_kernel(
    const float* __restrict__ res_sel, const float* __restrict__ r_items,
    unsigned short* __restrict__ Ahi)
{
  __shared__ __align__(16) float sp1[8][1024];
  const int bx = blockIdx.x;
  const int mg = blockIdx.y;
  const int tid = threadIdx.x;
  for (int idx = tid; idx < 2048; idx += 256)
    ((float4*)&sp1[0][0])[idx] = ((const float4*)(res_sel + (size_t)mg*8*1024))[idx];
  __syncthreads();
  {
    const int r = tid >> 5, lr = tid & 31;
    float mx = -1e30f;
    #pragma unroll 8
    for (int k = 0; k < 32; k++) mx = fmaxf(mx, sp1[r][lr + 32*k]);
    #pragma unroll
    for (int o = 16; o > 0; o >>= 1) mx = fmaxf(mx, __shfl_xor(mx, o));
    float sm = 0.f;
    float ev[32];
    #pragma unroll 8
    for (int k = 0; k < 32; k++){ ev[k] = expf(sp1[r][lr + 32*k] - mx); sm += ev[k]; }
    #pragma unroll
    for (int o = 16; o > 0; o >>= 1) sm += __shfl_xor(sm, o);
    float inv = 1.0f/sm;
    #pragma unroll 8
    for (int k = 0; k < 32; k++) sp1[r][lr + 32*k] = ev[k]*inv;
  }
  __syncthreads();
  const int n = bx*256 + tid;
  float acc[8] = {0,0,0,0,0,0,0,0};
  for (int k = 0; k < 1024; k++){
    float wv = r_items[(size_t)k*1024 + n];
    #pragma unroll
    for (int r = 0; r < 8; r++) acc[r] += sp1[r][k]*wv;
  }
  const size_t base = (size_t)(n >> 3)*2048 + (size_t)(n & 7);
  #pragma unroll
  for (int r = 0; r < 8; r++)
    Ahi[base + (size_t)(mg*8 + r)*8] = f2bf(acc[r]);
}

// ---------------- legacy prep (fallback path only) ----------------
__global__ __launch_bounds__(64) void prep_kernel(
    const float* __restrict__ noise_sel, const float* __restrict__ env_sel,
    const float* __restrict__ dec_sel,   const float* __restrict__ def_sel,
    const float* __restrict__ ndef_sel,  const float* __restrict__ mix_sel,
    const float* __restrict__ room_sel,  const float* __restrict__ amp,
    const float* __restrict__ n_items,   const float* __restrict__ e_items,
    const float* __restrict__ d_items,   const float* __restrict__ warp_items,
    const float* __restrict__ nwarp_items,
    float* __restrict__ env_small, float* __restrict__ nfil,
    float* __restrict__ nd_small,  float* __restrict__ w_small,
    float* __restrict__ d_small,   float* __restrict__ scal,
    float* __restrict__ rho)
{
  const int e = blockIdx.x;
  const int l = threadIdx.x;
  __shared__ float sw[64];
  __shared__ float buf[1024];

  {
    float x = env_sel[e*64 + l];
    float mx = wmax(x);
    float ex = expf(x - mx);
    float sm = wsum(ex);
    sw[l] = ex / sm;
  }
  __syncthreads();
  #pragma unroll
  for (int c = 0; c < 2; c++){
    int j = l + 64*c;
    float acc = 0.f;
    for (int k = 0; k < 64; k++){ float it = e_items[k*ENVS + j]; acc += sw[k]*(it*it); }
    env_small[e*ENVS + j] = acc;
  }
  __syncthreads();

  for (int x = 0; x < NEXP2; x++){
    float v = noise_sel[(e*NEXP2 + x)*64 + l];
    float mxv = wmax(v);
    float exv = expf(v - mxv);
    float smv = wsum(exv);
    sw[l] = exv / smv;
    __syncthreads();
    for (int c = 0; c < 8; c++){
      int tau = l + 64*c;
      float acc = 0.f;
      for (int f = 0; f < 64; f++) acc += sw[f]*n_items[f*FSAMP2 + tau];
      float ham = 0.54f - 0.46f*cosf((6.2831853071795864769f * (float)tau) / 511.0f);
      nfil[(e*NEXP2 + x)*FSAMP2 + tau] = acc*ham;
    }
    __syncthreads();
  }

  {
    float x = def_sel[e*64 + l];
    float mx = wmax(x);
    float ex = expf(x - mx);
    float sm = wsum(ex);
    sw[l] = ex / sm;
  }
  __syncthreads();
  for (int c = 0; c < 16; c++){
    int idx = l + 64*c;
    float acc = 0.f;
    for (int k = 0; k < 64; k++) acc += sw[k]*warp_items[k*1024 + idx];
    buf[idx] = acc;
  }
  __syncthreads();
  #pragma unroll
  for (int c = 0; c < 2; c++){
    int f = l + 64*c;
    float mx = -1e30f;
    for (int i = 0; i < 8; i++) mx = fmaxf(mx, buf[i*128 + f]);
    float ev[8]; float s = 0.f;
    for (int i = 0; i < 8; i++){ ev[i] = expf(buf[i*128 + f] - mx); s += ev[i]; }
    for (int i = 0; i < 8; i++) w_small[(e*8 + i)*128 + f] = ev[i]/s;
  }
  __syncthreads();

  {
    float x = (l < 32) ? ndef_sel[e*32 + l] : -1e30f;
    float mx = wmax(x);
    float ex = (l < 32) ? expf(x - mx) : 0.f;
    float sm = wsum(ex);
    sw[l] = (l < 32) ? ex/sm : 0.f;
  }
  __syncthreads();
  for (int c = 0; c < 8; c++){
    int idx = l + 64*c;
    float acc = 0.f;
    for (int k = 0; k < 32; k++) acc += sw[k]*nwarp_items[k*512 + idx];
    buf[idx] = acc;
  }
  __syncthreads();
  #pragma unroll
  for (int c = 0; c < 2; c++){
    int j = l + 64*c;
    float mx = -1e30f;
    for (int x = 0; x < 4; x++) mx = fmaxf(mx, buf[x*128 + j]);
    float ev[4]; float s = 0.f;
    for (int x = 0; x < 4; x++){ ev[x] = expf(buf[x*128 + j] - mx); s += ev[x]; }
    for (int x = 0; x < 4; x++) nd_small[(e*4 + x)*128 + j] = ev[x]/s;
  }
  __syncthreads();

  {
    float x = dec_sel[e*64 + l];
    float mx = wmax(x);
    float ex = expf(x - mx);
    float sm = wsum(ex);
    float wgt = ex / sm;
    float di = d_items[l];
    float dp = 0.5f + 0.5f*(1.0f/(1.0f + expf(-di)));
    float d0 = wsum(wgt*dp);
    float ld = logf(d0 + 1e-12f);
    #pragma unroll
    for (int c = 0; c < 2; c++){
      int f = l + 64*c;
      d_small[e*128 + f] = expf((float)(f+1)*ld);
    }
  }
  if (l == 0){
    float a = mix_sel[e*2 + 0], b = mix_sel[e*2 + 1];
    float mm = fmaxf(a, b);
    float ea = expf(a - mm), eb = expf(b - mm);
    float ss = ea + eb;
    scal[e*4 + 0] = ea/ss;
    scal[e*4 + 1] = eb/ss;
    float am = amp[e];
    scal[e*4 + 2] = am*am;
  }
  {
    float x = (l < 16) ? room_sel[e*16 + l] : -1e30f;
    float mx = wmax(x);
    float ex = (l < 16) ? expf(x - mx) : 0.f;
    float sm = wsum(ex);
    if (l < 16) rho[e*16 + l] = ex/sm;
  }
}

// ---------------- P1 = softmax(res_sel)  (fallback only) ----------------
__global__ __launch_bounds__(256) void p1_softmax_kernel(
    const float* __restrict__ res_sel, float* __restrict__ P1)
{
  const int m = blockIdx.x;
  const int tid = threadIdx.x;
  __shared__ float red[4], red2[4];
  const float* row = res_sel + (size_t)m*1024;
  float4 v = ((const float4*)row)[tid];
  float mx = fmaxf(fmaxf(v.x, v.y), fmaxf(v.z, v.w));
  #pragma unroll
  for (int o = 32; o > 0; o >>= 1) mx = fmaxf(mx, __shfl_xor(mx, o));
  if ((tid & 63) == 0) red[tid >> 6] = mx;
  __syncthreads();
  mx = fmaxf(fmaxf(red[0], red[1]), fmaxf(red[2], red[3]));
  float e0 = expf(v.x - mx), e1 = expf(v.y - mx), e2 = expf(v.z - mx), e3 = expf(v.w - mx);
  float s = e0 + e1 + e2 + e3;
  #pragma unroll
  for (int o = 32; o > 0; o >>= 1) s += __shfl_xor(s, o);
  if ((tid & 63) == 0) red2[tid >> 6] = s;
  __syncthreads();
  s = red2[0] + red2[1] + red2[2] + red2[3];
  float inv = 1.0f/s;
  ((float4*)(P1 + (size_t)m*1024))[tid] = make_float4(e0*inv, e1*inv, e2*inv, e3*inv);
}

// ---------------- P2 = P1 @ r_items  (fallback only) ----------------
__global__ __launch_bounds__(256) void p2_kernel(
    const float* __restrict__ P1, const float* __restrict__ r_items,
    float* __restrict__ P2)
{
  __shared__ __align__(16) float sp1[8][1024];
  const int bx = blockIdx.x;
  const int mg = blockIdx.y;
  const int tid = threadIdx.x;
  for (int idx = tid; idx < 2048; idx += 256)
    ((float4*)&sp1[0][0])[idx] = ((const float4*)(P1 + (size_t)mg*8*1024))[idx];
  __syncthreads();
  const int n = bx*256 + tid;
  float acc[8] = {0,0,0,0,0,0,0,0};
  for (int k = 0; k < 1024; k++){
    float wv = r_items[(size_t)k*1024 + n];
    #pragma unroll
    for (int r = 0; r < 8; r++) acc[r] += sp1[r][k]*wv;
  }
  #pragma unroll
  for (int r = 0; r < 8; r++) P2[(size_t)(mg*8 + r)*1024 + n] = acc[r];
}

// ---------------- impulses = interp(env_small,8192) * uniform_noise ----------------
__global__ __launch_bounds__(256) void env_noise_kernel(
    const float* __restrict__ env_small, float* __restrict__ impulses)
{
  const int flat = blockIdx.x*256 + threadIdx.x;
  const int e = flat >> 13, i = flat & 8191;
  unsigned bits = threefry_bits(0u, (unsigned)flat);
  float u01 = __uint_as_float((bits >> 9) | 0x3f800000u) - 1.0f;
  float nz  = fmaxf(-1.0f, u01*2.0f - 1.0f);
  float pos = (float)i * (127.0f/8191.0f);
  int lo = (int)floorf(pos);
  int hi = imin(lo + 1, 127);
  float w = pos - (float)lo;
  const float* es = env_small + e*ENVS;
  float v = es[lo]*(1.0f - w) + es[hi]*w;
  impulses[flat] = v*nz;
}

// ---------------- filtered: 512-tap FIR + nd combine ----------------
__global__ __launch_bounds__(256) void filt_kernel(
    const float* __restrict__ nfil, const float* __restrict__ impulses,
    const float* __restrict__ nd_small, float* __restrict__ filtered)
{
  __shared__ float nf[4*512];
  __shared__ float imp[768];
  const int e = blockIdx.y, t0 = blockIdx.x*256, tid = threadIdx.x;
  for (int idx = tid; idx < 2048; idx += 256) nf[idx] = nfil[e*2048 + idx];
  for (int idx = tid; idx < 768; idx += 256){
    int g = t0 - 512 + idx;
    imp[idx] = (g >= 0 && g < ENVF) ? impulses[e*ENVF + g] : 0.f;
  }
  __syncthreads();
  const int t = t0 + tid;
  float s0 = 0.f, s1 = 0.f, s2 = 0.f, s3 = 0.f;
  for (int tau = 0; tau < 512; tau++){
    float iv = imp[512 + tid - tau];
    s0 += nf[0*512 + tau]*iv;
    s1 += nf[1*512 + tau]*iv;
    s2 += nf[2*512 + tau]*iv;
    s3 += nf[3*512 + tau]*iv;
  }
  float pos = (float)t * (127.0f/65535.0f);
  int lo = (int)floorf(pos);
  int hi = imin(lo + 1, 127);
  float w = pos - (float)lo;
  const float* nds = nd_small + e*512;
  float acc = 0.f;
  acc += s0*(nds[0*128 + lo]*(1.0f - w) + nds[0*128 + hi]*w);
  acc += s1*(nds[1*128 + lo]*(1.0f - w) + nds[1*128 + hi]*w);
  acc += s2*(nds[2*128 + lo]*(1.0f - w) + nds[2*128 + hi]*w);
  acc += s3*(nds[3*128 + lo]*(1.0f - w) + nds[3*128 + hi]*w);
  filtered[e*FLEN + t] = acc;
}

// ---------------- rooms (fallback path only) ----------------
__global__ __launch_bounds__(256) void rooms_kernel(
    const float* __restrict__ verbs, const float* __restrict__ rho,
    float* __restrict__ rooms)
{
  const int t = blockIdx.x*256 + threadIdx.x;
  const int e = blockIdx.y;
  float acc = 0.f;
  #pragma unroll
  for (int v = 0; v < 16; v++) acc += rho[e*16 + v]*verbs[(size_t)v*NS + t];
  rooms[(size_t)e*NS + t] = acc;
}

// ---------------- rare-path waveform: exact f64 replication of numpy ----------------
__device__ __noinline__ float slow_wave(int wf, int n, int i){
  const double stp = 3980.0 / 255.0;
  double fi = (i == 255) ? 4000.0 : __dadd_rn(__dmul_rn((double)i, stp), 20.0);
  double tn = (double)n / 22050.0;
  double ph = __dmul_rn(fi, tn);
  double fr = ph - trunc(ph);
  if (wf == 1) return (float)(2.0*fr - 1.0);
  if (wf == 3){ double sw = 2.0*fr - 1.0; return (float)(2.0*fabs(sw) - 1.0); }
  if (fr == 0.0 || fr == 0.5){
    if (ph == 0.0) return 0.0f;
    double sv = sin(__dmul_rn(6.283185307179586, ph));
    return (sv > 0.0) ? 1.0f : ((sv < 0.0) ? -1.0f : 0.0f);
  }
  return (fr < 0.5) ? 1.0f : -1.0f;
}

// generate 8 wave values (rows i0..i0+7, column n) and split to bf16 hi/lo
__device__ __forceinline__ void gen8(int wf, int n, int i0,
                                     unsigned m_in, unsigned stepn,
                                     U8& bh, U8& bl)
{
  unsigned m = m_in;
  #pragma unroll
  for (int j = 0; j < 8; j++){
    float fr = (float)m * (1.0f/5622750.0f);
    float val;
    bool rare;
    if (wf == 0){
      asm("v_sin_f32 %0, %1" : "=v"(val) : "v"(fr));
      rare = false;
    } else if (wf == 1){
      val = fmaf(fr, 2.0f, -1.0f);
      rare = (m == 0u);
    } else if (wf == 2){
      val = (m < GDH) ? 1.0f : -1.0f;
      rare = (m == 0u) || (m == GDH);
    } else {
      val = fmaf(fabsf(fmaf(fr, 2.0f, -1.0f)), 2.0f, -1.0f);
      rare = (m == 0u);
    }
    if (rare) val = slow_wave(wf, n, i0 + j);
    unsigned ub = __float_as_uint(val);
    unsigned th = ub & 0xFFFF0000u;
    float lres = val - __uint_as_float(th);
    bh.u[j] = (unsigned short)(ub >> 16);
    bl.u[j] = (unsigned short)(__float_as_uint(lres) >> 16);
    m += stepn;
    if (m >= GD) m -= GD;
  }
}

// ---------------- MFMA GEMM v4: BK=64, half the barriers of v3 ----------------
// M=256, N=65536, K=1024. Grid 512 blocks x 512 thr (8 waves). Wave w owns cols
// [n0+16w, +16). A: 2 x 32 KB LDS double-buffer (two 32-k slices per step).
__global__ __launch_bounds__(512, 2) void gemm_dres_gen4_kernel(
    const unsigned short* __restrict__ Ahi,
    const float* __restrict__ w_small, const float* __restrict__ d_small,
    float* __restrict__ dres)
{
  __shared__ __align__(16) unsigned short Abuf[2][16384];   // 2 x 32 KB

  const int tid = threadIdx.x;
  const int l = tid & 63, w = tid >> 6;   // 8 waves
  const int g = l >> 4, c = l & 15;
  const int n = blockIdx.x*128 + w*16 + c;

  f32x4 acc[16];
  #pragma unroll
  for (int m = 0; m < 16; m++) acc[m] = (f32x4){0.f,0.f,0.f,0.f};

  const unsigned stepn = (3980u*(unsigned)n) % GD;
  const unsigned s32 = (32u*stepn) % GD;
  const unsigned K0g = 3980u*(unsigned)(g*8) + 5100u;
  const unsigned m0 = (unsigned)(((unsigned long long)(unsigned)n * K0g) % GD);
  unsigned mseg = m0;

  typedef const __attribute__((address_space(1))) void GV;
  typedef __attribute__((address_space(3))) void LV;

  // prologue: stage k = [0, 64) (16384 ushorts) into buf 0
  #pragma unroll
  for (int q = 0; q < 4; q++){
    const unsigned short* src = Ahi + (size_t)q*4096 + (size_t)w*512 + (size_t)l*8;
    __builtin_amdgcn_global_load_lds((GV*)src, (LV*)&Abuf[0][q*4096 + w*512], 16, 0, 0);
  }
  __syncthreads();

  for (int k0 = 0; k0 < 1024; k0 += 64){
    const int cur = (k0 >> 6) & 1, nxt = cur ^ 1;
    const int wf = k0 >> 8;
    if ((k0 & 255) == 0) mseg = m0;

    if (k0 + 64 < 1024){
      const size_t sb = (size_t)((k0 + 64) >> 5) * 8192;
      #pragma unroll
      for (int q = 0; q < 4; q++){
        const unsigned short* src = Ahi + sb + (size_t)q*4096 + (size_t)w*512 + (size_t)l*8;
        __builtin_amdgcn_global_load_lds((GV*)src, (LV*)&Abuf[nxt][q*4096 + w*512], 16, 0, 0);
      }
    }

    #pragma unroll
    for (int ks = 0; ks < 2; ks++){
      const int i0 = (k0 & 255) + 32*ks + g*8;
      U8 bh, bl;
      gen8(wf, n, i0, mseg, stepn, bh, bl);
      mseg += s32; if (mseg >= GD) mseg -= GD;
      const int abase = ks*8192 + g*2048;
      #pragma unroll
      for (int m = 0; m < 16; m++){
        U8 ah;
        ah.q = *(const uint4*)&Abuf[cur][abase + (m*16 + c)*8];
        acc[m] = __builtin_amdgcn_mfma_f32_16x16x32_bf16(ah.v, bh.v, acc[m], 0, 0, 0);
        acc[m] = __builtin_amdgcn_mfma_f32_16x16x32_bf16(ah.v, bl.v, acc[m], 0, 0, 0);
      }
    }
    __syncthreads();   // drains stage vmcnt + protects buffer swap
  }

  const int t = n;
  float pos = (float)t * (127.0f/65535.0f);
  int lo = (int)floorf(pos);
  int hi = imin(lo + 1, 127);
  float fr = pos - (float)lo;
  #pragma unroll
  for (int m = 0; m < 16; m++){
    int e = 2*m + (g >> 1);
    float s = 0.f;
    #pragma unroll
    for (int jj = 0; jj < 4; jj++){
      int i = (g & 1)*4 + jj;
      const float* wr = w_small + (size_t)(e*8 + i)*128;
      float wi = wr[lo]*(1.0f - fr) + wr[hi]*fr;
      s += wi * acc[m][jj];
    }
    s += __shfl_xor(s, 16);
    if ((g & 1) == 0){
      float de = d_small[e*128 + lo]*(1.0f - fr) + d_small[e*128 + hi]*fr;
      dres[(size_t)e*NS + t] = de * s;
    }
  }
}

// ---------------- fallback f32 GEMM ----------------
__global__ __launch_bounds__(256) void gemm_dres_kernel(
    const float* __restrict__ P2, const float* __restrict__ waves,
    const float* __restrict__ w_small, const float* __restrict__ d_small,
    float* __restrict__ dres)
{
  __shared__ __align__(16) float At[32][256];
  __shared__ __align__(16) float Bt[32][64];
  const int tid = threadIdx.x;
  const int tx = tid & 15, ty = tid >> 4;
  const int n0 = blockIdx.x * 64;
  float acc[16][4];
  #pragma unroll
  for (int a = 0; a < 16; a++)
    #pragma unroll
    for (int b = 0; b < 4; b++) acc[a][b] = 0.f;

  for (int k0 = 0; k0 < 1024; k0 += 32){
    {
      const float4* src = (const float4*)(P2 + (size_t)tid*1024 + k0);
      #pragma unroll
      for (int q = 0; q < 8; q++){
        float4 v = src[q];
        At[q*4 + 0][tid] = v.x; At[q*4 + 1][tid] = v.y;
        At[q*4 + 2][tid] = v.z; At[q*4 + 3][tid] = v.w;
      }
    }
    {
      int c  = tid & 15;
      int kr = tid >> 4;
      *(float4*)&Bt[kr][c*4]      = *((const float4*)(waves + (size_t)(k0 + kr)*NS + n0) + c);
      *(float4*)&Bt[kr + 16][c*4] = *((const float4*)(waves + (size_t)(k0 + kr + 16)*NS + n0) + c);
    }
    __syncthreads();
    #pragma unroll 4
    for (int k = 0; k < 32; k++){
      float a[16];
      *(float4*)&a[0]  = *(const float4*)&At[k][ty*16 + 0];
      *(float4*)&a[4]  = *(const float4*)&At[k][ty*16 + 4];
      *(float4*)&a[8]  = *(const float4*)&At[k][ty*16 + 8];
      *(float4*)&a[12] = *(const float4*)&At[k][ty*16 + 12];
      float4 b = *(const float4*)&Bt[k][tx*4];
      #pragma unroll
      for (int mi = 0; mi < 16; mi++){
        acc[mi][0] += a[mi]*b.x;
        acc[mi][1] += a[mi]*b.y;
        acc[mi][2] += a[mi]*b.z;
        acc[mi][3] += a[mi]*b.w;
      }
    }
    __syncthreads();
  }

  #pragma unroll
  for (int ni = 0; ni < 4; ni++){
    int t = n0 + tx*4 + ni;
    float pos = (float)t * (127.0f/65535.0f);
    int lo = (int)floorf(pos);
    int hi = imin(lo + 1, 127);
    float w = pos - (float)lo;
    #pragma unroll
    for (int ev2 = 0; ev2 < 2; ev2++){
      int e = ty*2 + ev2;
      float de = d_small[e*128 + lo]*(1.0f - w) + d_small[e*128 + hi]*w;
      float s = 0.f;
      #pragma unroll
      for (int i = 0; i < 8; i++){
        const float* wrow = w_small + (size_t)(e*8 + i)*128;
        float wi = wrow[lo]*(1.0f - w) + wrow[hi]*w;
        s += wi * acc[ev2*8 + i][ni];
      }
      dres[(size_t)e*NS + t] = de * s;
    }
  }
}

// ================= FFT machinery (four-step, N = 131072 = 256 x 512) =================
// Spectrum layout: S[k2*256 + k1], true k = k2 + 512*k1.
// Mixed-radix Stockham: radix-2 first (512 only, twiddle-free), then radix-4.

template<int L, int Ns, int DIR>
__device__ __forceinline__ void r4_stage(const float* __restrict__ xr,
                                         const float* __restrict__ xi,
                                         float* __restrict__ yr,
                                         float* __restrict__ yi)
{
  const int tid = threadIdx.x;
  constexpr int BPR = L/4;
  #pragma unroll
  for (int q = 0; q < 4; q++){
    int bf = tid + 256*q;
    int r  = bf / BPR;
    int j  = bf % BPR;
    int sw = (r & 7) << 2;
    int jm = j & (Ns - 1);
    float2 w1 = twid((float)jm * (1.0f/(4.0f*(float)Ns)));
    if (DIR < 0) w1.y = -w1.y;
    float2 w2 = make_float2(w1.x*w1.x - w1.y*w1.y, 2.0f*w1.x*w1.y);
    float2 w3 = make_float2(w2.x*w1.x - w2.y*w1.y, w2.x*w1.y + w2.y*w1.x);
    const float* xrr = xr + r*L;
    const float* xir = xi + r*L;
    float ar  = xrr[j ^ sw],           ai  = xir[j ^ sw];
    float b0r = xrr[(j+BPR) ^ sw],     b0i = xir[(j+BPR) ^ sw];
    float c0r = xrr[(j+2*BPR) ^ sw],   c0i = xir[(j+2*BPR) ^ sw];
    float d0r = xrr[(j+3*BPR) ^ sw],   d0i = xir[(j+3*BPR) ^ sw];
    float br = b0r*w1.x - b0i*w1.y,  bi = b0r*w1.y + b0i*w1.x;
    float cr = c0r*w2.x - c0i*w2.y,  ci = c0r*w2.y + c0i*w2.x;
    float dr = d0r*w3.x - d0i*w3.y,  di = d0r*w3.y + d0i*w3.x;
    float apc_r = ar + cr, apc_i = ai + ci;
    float amc_r = ar - cr, amc_i = ai - ci;
    float bpd_r = br + dr, bpd_i = bi + di;
    float bmd_r = br - dr, bmd_i = bi - di;
    int dbase = ((j - jm) << 2) + jm;
    float* yrr = yr + r*L;
    float* yir = yi + r*L;
    yrr[dbase ^ sw]          = apc_r + bpd_r;
    yir[dbase ^ sw]          = apc_i + bpd_i;
    yrr[(dbase + 2*Ns) ^ sw] = apc_r - bpd_r;
    yir[(dbase + 2*Ns) ^ sw] = apc_i - bpd_i;
    if (DIR > 0){
      yrr[(dbase + Ns) ^ sw]   = amc_r + bmd_i;
      yir[(dbase + Ns) ^ sw]   = amc_i - bmd_r;
      yrr[(dbase + 3*Ns) ^ sw] = amc_r - bmd_i;
      yir[(dbase + 3*Ns) ^ sw] = amc_i + bmd_r;
    } else {
      yrr[(dbase + Ns) ^ sw]   = amc_r - bmd_i;
      yir[(dbase + Ns) ^ sw]   = amc_i + bmd_r;
      yrr[(dbase + 3*Ns) ^ sw] = amc_r + bmd_i;
      yir[(dbase + 3*Ns) ^ sw] = amc_i - bmd_r;
    }
  }
}

#define FFT_SWAP { float* t_; t_=ra;ra=rb;rb=t_; t_=ia;ia=ib;ib=t_; }

template<int L, int DIR>
__device__ __forceinline__ void fft_core4(float*& ra, float*& ia, float*& rb, float*& ib)
{
  const int tid = threadIdx.x;
  if (L == 512){
    __syncthreads();
    #pragma unroll
    for (int q = 0; q < 8; q++){
      int bf = tid + 256*q;
      int r = bf >> 8, j = bf & 255;
      int sw = (r & 7) << 2;
      float ar = ra[r*512 + (j ^ sw)],        ai = ia[r*512 + (j ^ sw)];
      float br = ra[r*512 + ((j+256) ^ sw)],  bi = ia[r*512 + ((j+256) ^ sw)];
      rb[r*512 + ((2*j) ^ sw)]   = ar + br;
      ib[r*512 + ((2*j) ^ sw)]   = ai + bi;
      rb[r*512 + ((2*j+1) ^ sw)] = ar - br;
      ib[r*512 + ((2*j+1) ^ sw)] = ai - bi;
    }
    FFT_SWAP
    __syncthreads(); r4_stage<512,   2, DIR>(ra, ia, rb, ib); FFT_SWAP
    __syncthreads(); r4_stage<512,   8, DIR>(ra, ia, rb, ib); FFT_SWAP
    __syncthreads(); r4_stage<512,  32, DIR>(ra, ia, rb, ib); FFT_SWAP
    __syncthreads(); r4_stage<512, 128, DIR>(ra, ia, rb, ib); FFT_SWAP
  } else {
    __syncthreads(); r4_stage<256,   1, DIR>(ra, ia, rb, ib); FFT_SWAP
    __syncthreads(); r4_stage<256,   4, DIR>(ra, ia, rb, ib); FFT_SWAP
    __syncthreads(); r4_stage<256,  16, DIR>(ra, ia, rb, ib); FFT_SWAP
    __syncthreads(); r4_stage<256,  64, DIR>(ra, ia, rb, ib); FFT_SWAP
  }
  __syncthreads();
}

// F1-merged: z=0 filtered pair, z=1 dres pair, z=2 rooms pair (inline from verbs).
__global__ __launch_bounds__(256) void fwd512_all_kernel(
    const float* __restrict__ filt, const float* __restrict__ dresv,
    const float* __restrict__ verbs, const float* __restrict__ rho,
    float2* __restrict__ Xf, float2* __restrict__ Xd, float2* __restrict__ Xr)
{
  __shared__ float reA[4096], imA[4096], reB[4096], imB[4096];
  __shared__ float srho[32];
  const int e = blockIdx.y, t1 = blockIdx.x*8, tid = threadIdx.x;
  const int z = blockIdx.z;
  if (z == 2){
    if (tid < 32) srho[tid] = rho[(2*e)*16 + tid];
    __syncthreads();
  }
  #pragma unroll
  for (int q = 0; q < 4; q++){
    int flat = tid + 256*q;
    int n2 = flat >> 1;
    int rb = (flat & 1)*4;
    int nb = t1 + rb + 256*n2;
    float4 va = make_float4(0.f,0.f,0.f,0.f);
    float4 vb = make_float4(0.f,0.f,0.f,0.f);
    if (z == 0){
      if (nb < FLEN){
        va = *(const float4*)(filt + (size_t)e*2*FLEN + nb);
        vb = *(const float4*)(filt + (size_t)e*2*FLEN + FLEN + nb);
      }
    } else if (z == 1){
      if (nb < NS){
        va = *(const float4*)(dresv + (size_t)e*2*NS + nb);
        vb = *(const float4*)(dresv + (size_t)e*2*NS + NS + nb);
      }
    } else {
      if (nb < NS){
        #pragma unroll
        for (int v = 0; v < 16; v++){
          float4 w4 = *(const float4*)(verbs + (size_t)v*NS + nb);
          float r0 = srho[v], r1 = srho[16 + v];
          va.x += r0*w4.x; va.y += r0*w4.y; va.z += r0*w4.z; va.w += r0*w4.w;
          vb.x += r1*w4.x; vb.y += r1*w4.y; vb.z += r1*w4.z; vb.w += r1*w4.w;
        }
      }
    }
    #pragma unroll
    for (int j = 0; j < 4; j++){
      int r = rb + j;
      int sw = (r & 7) << 2;
      reA[r*512 + (n2 ^ sw)] = (&va.x)[j];
      imA[r*512 + (n2 ^ sw)] = (&vb.x)[j];
    }
  }
  float *ra = reA, *ia = imA, *rb2 = reB, *ib2 = imB;
  fft_core4<512, +1>(ra, ia, rb2, ib2);
  float2* Bt = (z == 0) ? Xf : (z == 1) ? Xd : Xr;
  float2* dst = Bt + ((size_t)e << 17);
  #pragma unroll
  for (int q = 0; q < 16; q++){
    int idx = tid + 256*q;
    int r = idx & 7, k2 = idx >> 3;
    int n1 = t1 + r;
    int sw = (r & 7) << 2;
    float xr = ra[r*512 + (k2 ^ sw)];
    float xi = ia[r*512 + (k2 ^ sw)];
    float2 w = twid((float)(n1*k2) * (1.0f/131072.0f));
    dst[k2*256 + n1] = make_float2(xr*w.x - xi*w.y, xr*w.y + xi*w.x);
  }
}

// F2: in-place FFT_256 along contiguous rows.
__device__ __forceinline__ void fwd256_body(float2* __restrict__ S)
{
  __shared__ float reA[4096], imA[4096], reB[4096], imB[4096];
  const int e = blockIdx.y, K0 = blockIdx.x*16, tid = threadIdx.x;
  float2* base = S + ((size_t)e << 17) + (size_t)K0*256;
  #pragma unroll
  for (int q = 0; q < 16; q++){
    int idx = tid + 256*q;
    int r = idx >> 8, col = idx & 255;
    float2 v = base[r*256 + col];
    int sw = (r & 7) << 2;
    reA[r*256 + (col ^ sw)] = v.x;
    imA[r*256 + (col ^ sw)] = v.y;
  }
  float *ra = reA, *ia = imA, *rb = reB, *ib = imB;
  fft_core4<256, +1>(ra, ia, rb, ib);
  #pragma unroll
  for (int q = 0; q < 16; q++){
    int idx = tid + 256*q;
    int r = idx >> 8, col = idx & 255;
    int sw = (r & 7) << 2;
    base[r*256 + col] = make_float2(ra[r*256 + (col ^ sw)], ia[r*256 + (col ^ sw)]);
  }
}

__global__ __launch_bounds__(256) void fwd256_tri_kernel(
    float2* __restrict__ Xf, float2* __restrict__ Xd, float2* __restrict__ Xr)
{
  float2* S = (blockIdx.z == 0) ? Xf : (blockIdx.z == 1) ? Xd : Xr;
  fwd256_body(S);
}

__global__ __launch_bounds__(256) void fwd256_kernel(float2* __restrict__ S)
{
  fwd256_body(S);
}

// I1: Hermitian-unpack TWO packed spectra, per-event product, repack
// Y = P0 + i*P1, inverse FFT_256, conj twiddle, write Ut[n1*512 + k2].
__global__ __launch_bounds__(256) void inv256_mul2_kernel(
    const float2* __restrict__ ZA, const float2* __restrict__ ZB,
    float2* __restrict__ Ut)
{
  __shared__ float reA[4096], imA[4096], reB[4096], imB[4096];
  const int e = blockIdx.y, K0 = blockIdx.x*16, tid = threadIdx.x;
  const float2* Za = ZA + ((size_t)e << 17);
  const float2* Zb = ZB + ((size_t)e << 17);
  #pragma unroll
  for (int q = 0; q < 16; q++){
    int idx = tid + 256*q;
    int r = idx >> 8, col = idx & 255;
    int k2 = K0 + r;
    int k2p, k1p;
    if (k2 == 0){ k2p = 0; k1p = (256 - col) & 255; }
    else        { k2p = 512 - k2; k1p = 255 - col; }
    float2 za  = Za[(size_t)k2*256 + col];
    float2 zap = Za[(size_t)k2p*256 + k1p];
    float2 zb  = Zb[(size_t)k2*256 + col];
    float2 zbp = Zb[(size_t)k2p*256 + k1p];
    float a0r = 0.5f*(za.x + zap.x), a0i = 0.5f*(za.y - zap.y);
    float a1r = 0.5f*(za.y + zap.y), a1i = 0.5f*(zap.x - za.x);
    float b0r = 0.5f*(zb.x + zbp.x), b0i = 0.5f*(zb.y - zbp.y);
    float b1r = 0.5f*(zb.y + zbp.y), b1i = 0.5f*(zbp.x - zb.x);
    float p0r = a0r*b0r - a0i*b0i, p0i = a0r*b0i + a0i*b0r;
    float p1r = a1r*b1r - a1i*b1i, p1i = a1r*b1i + a1i*b1r;
    int sw = (r & 7) << 2;
    reA[r*256 + (col ^ sw)] = p0r - p1i;
    imA[r*256 + (col ^ sw)] = p0i + p1r;
  }
  float *ra = reA, *ia = imA, *rb = reB, *ib = imB;
  fft_core4<256, -1>(ra, ia, rb, ib);
  float2* dst = Ut + ((size_t)e << 17);
  #pragma unroll
  for (int q = 0; q < 16; q++){
    int idx = tid + 256*q;
    int r = idx & 15, n1 = idx >> 4;
    int k2 = K0 + r;
    int sw = (r & 7) << 2;
    float xr = ra[r*256 + (n1 ^ sw)];
    float xi = ia[r*256 + (n1 ^ sw)];
    float2 w = twid((float)(n1*k2) * (1.0f/131072.0f));   // conj applied
    dst[n1*512 + k2] = make_float2(xr*w.x + xi*w.y, xi*w.x - xr*w.y);
  }
}

// I1-mix: same as inv256_mul2 but per-event B' = m0 + m1*R (frequency-domain mix).
__global__ __launch_bounds__(256) void inv256_mulmix_kernel(
    const float2* __restrict__ ZA, const float2* __restrict__ ZB,
    const float* __restrict__ scal, float2* __restrict__ Ut)
{
  __shared__ float reA[4096], imA[4096], reB[4096], imB[4096];
  const int e = blockIdx.y, K0 = blockIdx.x*16, tid = threadIdx.x;
  const float2* Za = ZA + ((size_t)e << 17);
  const float2* Zb = ZB + ((size_t)e << 17);
  const float m00 = scal[(2*e)*4 + 0], m10 = scal[(2*e)*4 + 1];
  const float m01 = scal[(2*e+1)*4 + 0], m11 = scal[(2*e+1)*4 + 1];
  #pragma unroll
  for (int q = 0; q < 16; q++){
    int idx = tid + 256*q;
    int r = idx >> 8, col = idx & 255;
    int k2 = K0 + r;
    int k2p, k1p;
    if (k2 == 0){ k2p = 0; k1p = (256 - col) & 255; }
    else        { k2p = 512 - k2; k1p = 255 - col; }
    float2 za  = Za[(size_t)k2*256 + col];
    float2 zap = Za[(size_t)k2p*256 + k1p];
    float2 zb  = Zb[(size_t)k2*256 + col];
    float2 zbp = Zb[(size_t)k2p*256 + k1p];
    float a0r = 0.5f*(za.x + zap.x), a0i = 0.5f*(za.y - zap.y);
    float a1r = 0.5f*(za.y + zap.y), a1i = 0.5f*(zap.x - za.x);
    float b0r = 0.5f*(zb.x + zbp.x), b0i = 0.5f*(zb.y - zbp.y);
    float b1r = 0.5f*(zb.y + zbp.y), b1i = 0.5f*(zbp.x - zb.x);
    // B' = m0 + m1*R  (per event)
    float B0r = m00 + m10*b0r, B0i = m10*b0i;
    float B1r = m01 + m11*b1r, B1i = m11*b1i;
    float p0r = a0r*B0r - a0i*B0i, p0i = a0r*B0i + a0i*B0r;
    float p1r = a1r*B1r - a1i*B1i, p1i = a1r*B1i + a1i*B1r;
    int sw = (r & 7) << 2;
    reA[r*256 + (col ^ sw)] = p0r - p1i;
    imA[r*256 + (col ^ sw)] = p0i + p1r;
  }
  float *ra = reA, *ia = imA, *rb = reB, *ib = imB;
  fft_core4<256, -1>(ra, ia, rb, ib);
  float2* dst = Ut + ((size_t)e << 17);
  #pragma unroll
  for (int q = 0; q < 16; q++){
    int idx = tid + 256*q;
    int r = idx & 15, n1 = idx >> 4;
    int k2 = K0 + r;
    int sw = (r & 7) << 2;
    float xr = ra[r*256 + (n1 ^ sw)];
    float xi = ia[r*256 + (n1 ^ sw)];
    float2 w = twid((float)(n1*k2) * (1.0f/131072.0f));   // conj applied
    dst[n1*512 + k2] = make_float2(xr*w.x + xi*w.y, xi*w.x - xr*w.y);
  }
}

// I2+F1 fused: inverse FFT_512 -> packed conv pair (kept in LDS only);
// truncate (n2>=256 -> 0) and forward FFT_512 + twiddle -> Bt.
__global__ __launch_bounds__(256) void inv512_fwdpack2_kernel(
    const float2* __restrict__ Ut, float2* __restrict__ Bt)
{
  __shared__ float reA[4096], imA[4096], reB[4096], imB[4096];
  const int e = blockIdx.y, t1 = blockIdx.x*8, tid = threadIdx.x;
  const float2* base = Ut + ((size_t)e << 17) + (size_t)t1*512;
  #pragma unroll
  for (int q = 0; q < 16; q++){
    int idx = tid + 256*q;
    int r = idx >> 9, col = idx & 511;
    float2 v = base[r*512 + col];
    int sw = (r & 7) << 2;
    reA[r*512 + (col ^ sw)] = v.x;
    imA[r*512 + (col ^ sw)] = v.y;
  }
  float *ra = reA, *ia = imA, *rb = reB, *ib = imB;
  fft_core4<512, -1>(ra, ia, rb, ib);
  const float s = 1.0f/131072.0f;
  #pragma unroll
  for (int q = 0; q < 16; q++){
    int idx = tid + 256*q;
    int r = idx & 7, n2 = idx >> 3;
    int sw = (r & 7) << 2;
    int pos = r*512 + (n2 ^ sw);
    if (n2 < 256){
      rb[pos] = ra[pos]*s; ib[pos] = ia[pos]*s;
    } else {
      rb[pos] = 0.f; ib[pos] = 0.f;
    }
  }
  __syncthreads();
  float *r2 = rb, *i2 = ib, *r3 = ra, *i3 = ia;
  fft_core4<512, +1>(r2, i2, r3, i3);
  float2* dst = Bt + ((size_t)e << 17);
  #pragma unroll
  for (int q = 0; q < 16; q++){
    int idx = tid + 256*q;
    int r = idx & 7, k2 = idx >> 3;
    int n1 = t1 + r;
    int sw = (r & 7) << 2;
    float xr = r2[r*512 + (k2 ^ sw)];
    float xi = i2[r*512 + (k2 ^ sw)];
    float2 w = twid((float)(n1*k2) * (1.0f/131072.0f));
    dst[k2*256 + n1] = make_float2(xr*w.x - xi*w.y, xr*w.y + xi*w.x);
  }
}

// I2-final: inverse FFT_512 -> mixed pair already (freq-domain mix); scale by amp^2.
__global__ __launch_bounds__(256) void inv512_out_kernel(
    const float2* __restrict__ Ut, const float* __restrict__ scal,
    float* __restrict__ dst)
{
  __shared__ float reA[4096], imA[4096], reB[4096], imB[4096];
  const int e = blockIdx.y, t1 = blockIdx.x*8, tid = threadIdx.x;
  const float2* base = Ut + ((size_t)e << 17) + (size_t)t1*512;
  #pragma unroll
  for (int q = 0; q < 16; q++){
    int idx = tid + 256*q;
    int r = idx >> 9, col = idx & 511;
    float2 v = base[r*512 + col];
    int sw = (r & 7) << 2;
    reA[r*512 + (col ^ sw)] = v.x;
    imA[r*512 + (col ^ sw)] = v.y;
  }
  float *ra = reA, *ia = imA, *rb = reB, *ib = imB;
  fft_core4<512, -1>(ra, ia, rb, ib);
  const float s = 1.0f/131072.0f;
  const int e0 = 2*e, e1 = 2*e + 1;
  const float a20 = scal[e0*4 + 2]*s, a21 = scal[e1*4 + 2]*s;
  #pragma unroll
  for (int q = 0; q < 8; q++){
    int idx = tid + 256*q;
    int r = idx & 7, n2 = idx >> 3;
    int n = (t1 + r) + 256*n2;
    int sw = (r & 7) << 2;
    int pos = r*512 + (n2 ^ sw);
    dst[(size_t)e0*NS + n] = ra[pos]*a20;
    dst[(size_t)e1*NS + n] = ia[pos]*a21;
  }
}

// ---------------- fallback: direct causal conv ----------------
template<int MODE>
__global__ __launch_bounds__(256) void tconv_kernel(
    const float* __restrict__ sig, int sig_len, int sig_stride,
    const float* __restrict__ go, const float* __restrict__ scal,
    float* __restrict__ dst)
{
  __shared__ __align__(16) float cs[2048];
  __shared__ __align__(16) float rs[4104];
  const int e = blockIdx.y;
  const int t0 = blockIdx.x * 2048;
  const int tid = threadIdx.x;
  const int tb = tid * 8;
  float acc[8] = {0,0,0,0,0,0,0,0};
  const int kcap = imin(sig_len, t0 + 2048);
  for (int c0 = 0; c0 < kcap; c0 += 2048){
    __syncthreads();
    for (int idx = tid; idx < 2048; idx += 256){
      int gsi = c0 + idx;
      cs[idx] = (gsi < sig_len) ? sig[(size_t)e*sig_stride + gsi] : 0.f;
    }
    const int rb = t0 - c0 - 2056;
    for (int idx = tid; idx < 4104; idx += 256){
      int g = rb + idx;
      rs[idx] = (g >= 0 && g < NS) ? go[(size_t)e*NS + g] : 0.f;
    }
    __syncthreads();
    float W[12];
    int P = tb + 2056;
    *(float4*)&W[0] = *(const float4*)&rs[P - 4];
    *(float4*)&W[4] = *(const float4*)&rs[P];
    *(float4*)&W[8] = *(const float4*)&rs[P + 4];
    for (int u = 0; u < 512; u++){
      float4 f4 = *(const float4*)&cs[4*u];
      #pragma unroll
      for (int j = 0; j < 8; j++){
        acc[j] += f4.x*W[4 + j];
        acc[j] += f4.y*W[3 + j];
        acc[j] += f4.z*W[2 + j];
        acc[j] += f4.w*W[1 + j];
      }
      #pragma unroll
      for (int x2 = 11; x2 >= 4; x2--) W[x2] = W[x2 - 4];
      P -= 4;
      *(float4*)&W[0] = *(const float4*)&rs[P - 4];
    }
  }
  if (MODE == 0){
    #pragma unroll
    for (int j = 0; j < 8; j++) dst[(size_t)e*NS + t0 + tb + j] = acc[j];
  } else {
    float m0 = scal[e*4 + 0], m1 = scal[e*4 + 1], a2 = scal[e*4 + 2];
    #pragma unroll
    for (int j = 0; j < 8; j++){
      size_t gi = (size_t)e*NS + t0 + tb + j;
      dst[gi] = (m0*sig[gi] + m1*acc[j]) * a2;
    }
  }
}

// ---------------- launcher ----------------
extern "C" void kernel_launch(void* const* d_in, const int* in_sizes, int n_in,
                              void* d_out, int out_size, void* d_ws, size_t ws_size,
                              hipStream_t stream)
{
  (void)in_sizes; (void)n_in; (void)out_size;
  const float* res_sel     = (const float*)d_in[0];
  const float* noise_sel   = (const float*)d_in[1];
  const float* env_sel     = (const float*)d_in[2];
  const float* dec_sel     = (const float*)d_in[3];
  const float* def_sel     = (const float*)d_in[4];
  const float* ndef_sel    = (const float*)d_in[5];
  const float* mix_sel     = (const float*)d_in[6];
  const float* room_sel    = (const float*)d_in[7];
  const float* amp         = (const float*)d_in[8];
  const float* r_items     = (const float*)d_in[9];
  const float* n_items     = (const float*)d_in[10];
  const float* e_items     = (const float*)d_in[11];
  const float* d_items     = (const float*)d_in[12];
  const float* warp_items  = (const float*)d_in[13];
  const float* nwarp_items = (const float*)d_in[14];
  const float* verbs       = (const float*)d_in[15];
  const float* waves       = (const float*)d_in[16];
  float* ws  = (float*)d_ws;
  float* out = (float*)d_out;

  const bool big_ws = ws_size >= (size_t)O_END * sizeof(float);

  if (big_ws) {
    weights_kernel<<<dim3(NEV), dim3(64), 0, stream>>>(
        noise_sel, env_sel, dec_sel, def_sel, ndef_sel, mix_sel, room_sel, amp,
        d_items, ws + O_SWE, ws + O_SWN, ws + O_SWD, ws + O_SWND,
        ws + O_DSM, ws + O_SCAL, ws + O_RHO);
    lookups_kernel<<<dim3(224), dim3(256), 0, stream>>>(
        ws + O_SWE, ws + O_SWN, ws + O_SWD, ws + O_SWND,
        e_items, n_items, warp_items, nwarp_items,
        ws + O_ENV_SMALL, ws + O_NFIL, ws + O_WSM, ws + O_ND);

    unsigned short* Ahi = (unsigned short*)(ws + O_X);
    p2s_kernel<<<dim3(4, 32), dim3(256), 0, stream>>>(res_sel, r_items, Ahi);

    env_noise_kernel<<<dim3(1024), dim3(256), 0, stream>>>(ws + O_ENV_SMALL, ws + O_IMP);
    filt_kernel<<<dim3(34, NEV), dim3(256), 0, stream>>>(ws + O_NFIL, ws + O_IMP, ws + O_ND, ws + O_FILT);

    gemm_dres_gen4_kernel<<<dim3(512), dim3(512), 0, stream>>>(
        Ahi, ws + O_WSM, ws + O_DSM, ws + O_DRES);

    // ---- event-pair-packed FFT convolution ----
    float2* Xf = (float2*)(ws + O_X);
    float2* Xd = (float2*)(ws + O_X + 4194304);
    float2* Xr = (float2*)(ws + O_Y);
    float2* Uc = (float2*)(ws + O_Y + 4194304);
    float2* Xc = Xf;
    float2* Uw = Xd;

    fwd512_all_kernel<<<dim3(32, 16, 3), dim3(256), 0, stream>>>(
        ws + O_FILT, ws + O_DRES, verbs, ws + O_RHO, Xf, Xd, Xr);
    fwd256_tri_kernel<<<dim3(32, 16, 3), dim3(256), 0, stream>>>(Xf, Xd, Xr);

    inv256_mul2_kernel<<<dim3(32, 16), dim3(256), 0, stream>>>(Xf, Xd, Uc);
    inv512_fwdpack2_kernel<<<dim3(32, 16), dim3(256), 0, stream>>>(Uc, Xc);
    fwd256_kernel<<<dim3(32, 16), dim3(256), 0, stream>>>(Xc);
    inv256_mulmix_kernel<<<dim3(32, 16), dim3(256), 0, stream>>>(Xc, Xr, ws + O_SCAL, Uw);
    inv512_out_kernel<<<dim3(32, 16), dim3(256), 0, stream>>>(Uw, ws + O_SCAL, out);
  } else {
    // fallback: legacy prep + f32 GEMM + direct time-domain conv
    prep_kernel<<<dim3(NEV), dim3(64), 0, stream>>>(
        noise_sel, env_sel, dec_sel, def_sel, ndef_sel, mix_sel, room_sel, amp,
        n_items, e_items, d_items, warp_items, nwarp_items,
        ws + O_ENV_SMALL, ws + O_NFIL, ws + O_ND, ws + O_WSM,
        ws + O_DSM, ws + O_SCAL, ws + O_RHO);
    p1_softmax_kernel<<<dim3(256), dim3(256), 0, stream>>>(res_sel, ws + O_P1);
    p2_kernel<<<dim3(4, 32), dim3(256), 0, stream>>>(ws + O_P1, r_items, ws + O_P2);
    env_noise_kernel<<<dim3(1024), dim3(256), 0, stream>>>(ws + O_ENV_SMALL, ws + O_IMP);
    filt_kernel<<<dim3(34, NEV), dim3(256), 0, stream>>>(ws + O_NFIL, ws + O_IMP, ws + O_ND, ws + O_FILT);
    rooms_kernel<<<dim3(256, NEV), dim3(256), 0, stream>>>(verbs, ws + O_RHO, ws + O_ROOMS);
    gemm_dres_kernel<<<dim3(1024), dim3(256), 0, stream>>>(
        ws + O_P2, waves, ws + O_WSM, ws + O_DSM, ws + O_DRES);
    tconv_kernel<0><<<dim3(32, NEV), dim3(256), 0, stream>>>(
        ws + O_FILT, FLEN, FLEN, ws + O_DRES, (const float*)nullptr, ws + O_CONV);
    tconv_kernel<1><<<dim3(32, NEV), dim3(256), 0, stream>>>(
        ws + O_CONV, NS, NS, ws + O_ROOMS, ws + O_SCAL, out);
  }
}